// Round 12
// baseline (628.129 us; speedup 1.0000x reference)
//
#include <hip/hip_runtime.h>
#include <math.h>

#define DD 128
#define SCHUNK 2048

typedef __attribute__((ext_vector_type(8))) short short8;
typedef __attribute__((ext_vector_type(4))) float f32x4;
typedef __attribute__((ext_vector_type(4))) unsigned short us4;

__device__ __forceinline__ unsigned short f2bf(float f) {
  unsigned int u = __builtin_bit_cast(unsigned int, f);
  u = (u + 0x7FFFu + ((u >> 16) & 1u)) >> 16;   // RNE (finite inputs)
  return (unsigned short)u;
}

__device__ __forceinline__ float b2f(unsigned short u) {
  return __builtin_bit_cast(float, ((unsigned)u) << 16);
}

// ---------------------------------------------------------------------------
// Row conversion f32 -> bf16: [A | B] into one table.
// ---------------------------------------------------------------------------
__global__ __launch_bounds__(256) void rowconv_kernel(
    const float* __restrict__ A, const float* __restrict__ B,
    unsigned short* __restrict__ dst, int nA4, int ntot4)
{
  int stride = gridDim.x * 256;
  for (int i = blockIdx.x * 256 + threadIdx.x; i < ntot4; i += stride) {
    float4 v = (i < nA4) ? ((const float4*)A)[i] : ((const float4*)B)[i - nA4];
    us4 o;
    o[0] = f2bf(v.x); o[1] = f2bf(v.y); o[2] = f2bf(v.z); o[3] = f2bf(v.w);
    ((us4*)dst)[i] = o;
  }
}

// ---------------------------------------------------------------------------
// Weight conversion f32 -> bf16: [Wrev | Wfwd | Wg1] (Wg1 = W_gate[:, :128])
// ---------------------------------------------------------------------------
__global__ __launch_bounds__(256) void wconv_kernel(
    const float* __restrict__ Wrev, const float* __restrict__ Wfwd,
    const float* __restrict__ Wgate, unsigned short* __restrict__ dst)
{
  int i = blockIdx.x * 256 + threadIdx.x;   // 49152 total
  float v;
  if (i < 16384) v = Wrev[i];
  else if (i < 32768) v = Wfwd[i - 16384];
  else {
    int j = (i - 32768) >> 7, k = (i - 32768) & 127;
    v = Wgate[j * 256 + k];                 // first half of each gate row
  }
  dst[i] = f2bf(v);
}

// ---------------------------------------------------------------------------
// Wc[j][k] = sum_m Wg2[j][m] * Wr[m][k], v[j] = sum_m Wg2[j][m] * br[m]
// (Wg2 = W_gate[:, 128:]) — computed in f32 from original weights, then bf16.
// Grid: 128 blocks (j), 128 threads (k).
// ---------------------------------------------------------------------------
__global__ __launch_bounds__(128) void wc_kernel(
    const float* __restrict__ Wgate, const float* __restrict__ Wr,
    const float* __restrict__ br, unsigned short* __restrict__ Wc_bf,
    float* __restrict__ v)
{
  int j = blockIdx.x, k = threadIdx.x;
  const float* g2 = Wgate + (size_t)j * 256 + 128;
  float acc = 0.f;
  for (int m = 0; m < 128; ++m) acc += g2[m] * Wr[m * 128 + k];
  Wc_bf[j * 128 + k] = f2bf(acc);
  if (k == 0) {
    float a = 0.f;
    for (int m = 0; m < 128; ++m) a += g2[m] * br[m];
    v[j] = a;
  }
}

// ---------------------------------------------------------------------------
// Phase 1: degree histogram (per-row counts)
// ---------------------------------------------------------------------------
__global__ __launch_bounds__(256) void hist_kernel(
    const int* __restrict__ src, const int* __restrict__ dst,
    int* __restrict__ cnt, int n_a, int E)
{
  int e = blockIdx.x * 256 + threadIdx.x;
  if (e >= E) return;
  atomicAdd(&cnt[src[e]], 1);
  atomicAdd(&cnt[n_a + dst[e]], 1);
}

// ---------------------------------------------------------------------------
// Phase 2: exclusive scan over row counts (3 kernels)
// ---------------------------------------------------------------------------
__global__ __launch_bounds__(256) void scan1_kernel(
    const int* __restrict__ cnt, int n, int* __restrict__ partials)
{
  __shared__ int sd[256];
  int t = threadIdx.x;
  int base = blockIdx.x * SCHUNK;
  int s = 0;
  #pragma unroll
  for (int k = 0; k < 8; ++k) {
    int i = base + t * 8 + k;
    s += (i < n) ? cnt[i] : 0;
  }
  sd[t] = s;
  __syncthreads();
  for (int off = 128; off > 0; off >>= 1) {
    if (t < off) sd[t] += sd[t + off];
    __syncthreads();
  }
  if (t == 0) partials[blockIdx.x] = sd[0];
}

__global__ __launch_bounds__(256) void scan2_kernel(int* __restrict__ partials, int nch)
{
  __shared__ int buf[256];
  int t = threadIdx.x;
  int v = (t < nch) ? partials[t] : 0;
  buf[t] = v;
  __syncthreads();
  for (int off = 1; off < 256; off <<= 1) {
    int x = (t >= off) ? buf[t - off] : 0;
    __syncthreads();
    buf[t] += x;
    __syncthreads();
  }
  if (t < nch) partials[t] = buf[t] - v;   // exclusive
}

__global__ __launch_bounds__(256) void scan3_kernel(
    const int* __restrict__ cnt, int n, const int* __restrict__ partials,
    int* __restrict__ start, int* __restrict__ cursor)
{
  __shared__ int sd[256];
  int t = threadIdx.x;
  int base = blockIdx.x * SCHUNK;
  int loc[8];
  int s = 0;
  #pragma unroll
  for (int k = 0; k < 8; ++k) {
    int i = base + t * 8 + k;
    loc[k] = (i < n) ? cnt[i] : 0;
    s += loc[k];
  }
  sd[t] = s;
  __syncthreads();
  for (int off = 1; off < 256; off <<= 1) {
    int x = (t >= off) ? sd[t - off] : 0;
    __syncthreads();
    sd[t] += x;
    __syncthreads();
  }
  int off = partials[blockIdx.x] + sd[t] - s;
  #pragma unroll
  for (int k = 0; k < 8; ++k) {
    int i = base + t * 8 + k;
    if (i < n) { start[i] = off; cursor[i] = off; }
    off += loc[k];
  }
}

// ---------------------------------------------------------------------------
// Phase 3a: bin histogram. A rows: 1024-row bins; B rows: 256-row bins.
// ---------------------------------------------------------------------------
__global__ __launch_bounds__(256) void binhist_kernel(
    const int* __restrict__ src, const int* __restrict__ dst,
    int* __restrict__ binraw, int na_bins, int nbins, int E)
{
  __shared__ int h[1024];
  int t = threadIdx.x;
  for (int i = t; i < 1024; i += 256) h[i] = 0;
  __syncthreads();
  int stride = gridDim.x * 256;
  for (int e = blockIdx.x * 256 + t; e < E; e += stride) {
    int s = src[e], d = dst[e];
    atomicAdd(&h[s >> 10], 1);
    atomicAdd(&h[na_bins + (d >> 8)], 1);
  }
  __syncthreads();
  for (int i = t; i < nbins; i += 256)
    if (h[i]) atomicAdd(&binraw[i], h[i]);
}

// ---------------------------------------------------------------------------
// Phase 3b: exclusive scan over bin counts (single block, nbins <= 512)
// ---------------------------------------------------------------------------
__global__ __launch_bounds__(512) void binscan_kernel(
    const int* __restrict__ binraw, int nbins,
    int* __restrict__ binstart, int* __restrict__ bincur)
{
  __shared__ int buf[512];
  int t = threadIdx.x;
  int v = (t < nbins) ? binraw[t] : 0;
  buf[t] = v;
  __syncthreads();
  for (int off = 1; off < 512; off <<= 1) {
    int x = (t >= off) ? buf[t - off] : 0;
    __syncthreads();
    buf[t] += x;
    __syncthreads();
  }
  if (t < nbins) {
    int excl = buf[t] - v;
    binstart[t] = excl;
    bincur[t] = excl;
  }
}

// ---------------------------------------------------------------------------
// Phase 3c: binfill — rank 8192 records per-bin in LDS, reserve dense runs,
// write (key=row, val=partner) as per-CU dense runs.
// ---------------------------------------------------------------------------
__global__ __launch_bounds__(512) void binfill_kernel(
    const int* __restrict__ src, const int* __restrict__ dst,
    int* __restrict__ bincur, uint2* __restrict__ binrec,
    int n_a, int na_bins, int nbins, int E)
{
  __shared__ int lcnt[1024];
  __shared__ int goff[1024];
  const int t = threadIdx.x;
  const int base = blockIdx.x * 4096;
  for (int i = t; i < 1024; i += 512) lcnt[i] = 0;
  __syncthreads();

  int bins[16], ranks[16];
  unsigned keys[16], vals[16];
  #pragma unroll
  for (int j = 0; j < 8; ++j) {
    int e = base + j * 512 + t;
    int i0 = 2 * j, i1 = 2 * j + 1;
    if (e < E) {
      int s = src[e], d = dst[e];
      bins[i0] = s >> 10;               keys[i0] = (unsigned)s;       vals[i0] = (unsigned)d;
      bins[i1] = na_bins + (d >> 8);    keys[i1] = (unsigned)(n_a + d); vals[i1] = (unsigned)s;
      ranks[i0] = atomicAdd(&lcnt[bins[i0]], 1);
      ranks[i1] = atomicAdd(&lcnt[bins[i1]], 1);
    } else {
      bins[i0] = -1; bins[i1] = -1;
      ranks[i0] = 0;  ranks[i1] = 0;
      keys[i0] = 0;   keys[i1] = 0;
      vals[i0] = 0;   vals[i1] = 0;
    }
  }
  __syncthreads();
  for (int b = t; b < nbins; b += 512)
    if (lcnt[b]) goff[b] = atomicAdd(&bincur[b], lcnt[b]);
  __syncthreads();
  #pragma unroll
  for (int i = 0; i < 16; ++i) {
    if (bins[i] >= 0) {
      int p = goff[bins[i]] + ranks[i];
      binrec[p] = make_uint2(keys[i], vals[i]);
    }
  }
}

// ---------------------------------------------------------------------------
// Phase 3d: fine scatter, one block per bin (exclusively-owned L2-local bin).
// ---------------------------------------------------------------------------
__global__ __launch_bounds__(256) void binscatter_kernel(
    const uint2* __restrict__ binrec, const int* __restrict__ binstart,
    const int* __restrict__ binend, int* __restrict__ cursor,
    int* __restrict__ partner)
{
  int b = blockIdx.x;
  int s0 = binstart[b], e0 = binend[b];
  for (int i = s0 + threadIdx.x; i < e0; i += 256) {
    uint2 r = binrec[i];
    int pos = atomicAdd(&cursor[r.x], 1);
    partner[pos] = (int)r.y;
  }
}

// ---------------------------------------------------------------------------
// Phase 4: one wave per row; 32 lanes x 8B cover a 256B bf16 row, half-waves
// take even/odd edges; combine with shfl_xor(32).
// ---------------------------------------------------------------------------
__global__ __launch_bounds__(256) void aggregate_mean_bf16_kernel(
    const unsigned short* __restrict__ A_bf,
    const unsigned short* __restrict__ B_bf,
    const int* __restrict__ partner, const int* __restrict__ start,
    const int* __restrict__ cnt, unsigned short* __restrict__ mean_bf,
    int n_a, int n_total)
{
  int wid = (blockIdx.x * 256 + threadIdx.x) >> 6;
  if (wid >= n_total) return;
  int lane = threadIdx.x & 63;
  int c2 = lane & 31;
  int h  = lane >> 5;
  int s0 = start[wid], c = cnt[wid];
  const unsigned short* tbl = (wid < n_a) ? B_bf : A_bf;
  float a0 = 0.f, a1 = 0.f, a2 = 0.f, a3 = 0.f;
  int k = 0;
  for (; k + 8 <= c; k += 8) {
    int p0 = partner[s0 + k + 0 + h];
    int p1 = partner[s0 + k + 2 + h];
    int p2 = partner[s0 + k + 4 + h];
    int p3 = partner[s0 + k + 6 + h];
    us4 v0 = *(const us4*)(tbl + (size_t)p0 * DD + 4 * c2);
    us4 v1 = *(const us4*)(tbl + (size_t)p1 * DD + 4 * c2);
    us4 v2 = *(const us4*)(tbl + (size_t)p2 * DD + 4 * c2);
    us4 v3 = *(const us4*)(tbl + (size_t)p3 * DD + 4 * c2);
    a0 += b2f(v0[0]) + b2f(v1[0]) + b2f(v2[0]) + b2f(v3[0]);
    a1 += b2f(v0[1]) + b2f(v1[1]) + b2f(v2[1]) + b2f(v3[1]);
    a2 += b2f(v0[2]) + b2f(v1[2]) + b2f(v2[2]) + b2f(v3[2]);
    a3 += b2f(v0[3]) + b2f(v1[3]) + b2f(v2[3]) + b2f(v3[3]);
  }
  for (; k < c; k += 2) {
    int i = k + h;
    if (i < c) {
      int p = partner[s0 + i];
      us4 v = *(const us4*)(tbl + (size_t)p * DD + 4 * c2);
      a0 += b2f(v[0]); a1 += b2f(v[1]); a2 += b2f(v[2]); a3 += b2f(v[3]);
    }
  }
  a0 += __shfl_xor(a0, 32);
  a1 += __shfl_xor(a1, 32);
  a2 += __shfl_xor(a2, 32);
  a3 += __shfl_xor(a3, 32);
  if (lane < 32) {
    float inv = (c > 0) ? (1.f / (float)c) : 0.f;
    us4 o;
    o[0] = f2bf(a0 * inv); o[1] = f2bf(a1 * inv);
    o[2] = f2bf(a2 * inv); o[3] = f2bf(a3 * inv);
    *(us4*)&mean_bf[(size_t)wid * DD + 4 * c2] = o;
  }
}

// ---------------------------------------------------------------------------
// Phase 5+6 fused v2 (MFMA, swapped operands, Wc trick, persistent blocks):
//   t = (cnt>0) ? mean @ Wr^T + br : 0
//   u = row @ Wg1^T + mean @ Wc^T + (cnt>0 ? bg+v : bg)   [v = Wg2@br]
//   out = sigmoid(u)*row + (1-sigmoid(u))*t
// mfma(W_frag, x_frag): D[j][m] -> lane holds 4 consecutive output dims j for
// ONE row m = m0+(lane&15): per-lane-uniform cnt mask, float4 bias + store.
// No LDS writes in the loop -> grid-stride reuse is hazard-free.
// A and B ranges merged: blocks [0,gA) -> A, [gA,grid) -> B.
// ---------------------------------------------------------------------------
__global__ __launch_bounds__(512, 1) void fused_post2_kernel(
    const unsigned short* __restrict__ rows_bf,  // [n_total][128] bf16
    const unsigned short* __restrict__ mean_bf,  // [n_total][128] bf16
    const int* __restrict__ cnt,                 // [n_total]
    const unsigned short* __restrict__ wbf,      // [Wrev|Wfwd|Wg1|WcA|WcB]
    const float* __restrict__ vab,               // [vA(128) | vB(128)]
    const float* __restrict__ b_rev, const float* __restrict__ b_fwd,
    const float* __restrict__ bg,
    float* __restrict__ out, int n_a, int n_b, int gA)
{
  __shared__ unsigned short Wr_l[128 * 128];   // 32 KB
  __shared__ unsigned short Wg1_l[128 * 128];  // 32 KB
  __shared__ unsigned short Wc_l[128 * 128];   // 32 KB
  __shared__ __align__(16) float br_l[128];
  __shared__ __align__(16) float bg_l[128];
  __shared__ __align__(16) float bgv_l[128];

  const int t = threadIdx.x;
  const bool isB = blockIdx.x >= gA;
  const int bid = isB ? (blockIdx.x - gA) : blockIdx.x;
  const int gsz = isB ? (gridDim.x - gA) : gA;
  const int n   = isB ? n_b : n_a;
  const size_t roff = isB ? (size_t)n_a * DD : 0;
  const unsigned short* rowsp = rows_bf + roff;
  const unsigned short* meanp = mean_bf + roff;
  const int* cntp = cnt + (isB ? n_a : 0);
  float* outp = out + roff;
  const unsigned short* Wr_g  = wbf + (isB ? 16384 : 0);
  const unsigned short* Wg1_g = wbf + 32768;
  const unsigned short* Wc_g  = wbf + 49152 + (isB ? 16384 : 0);
  const float* brp = isB ? b_fwd : b_rev;
  const float* vp  = vab + (isB ? 128 : 0);

  // stage 3x 128x128 bf16 with octet-XOR swizzle (proven pattern)
  for (int oi = t; oi < 2048; oi += 512) {
    int j = oi >> 4, o = oi & 15;
    int d = j * 128 + ((o ^ (j & 15)) << 3);
    *(short8*)&Wr_l[d]  = *(const short8*)&Wr_g[oi << 3];
    *(short8*)&Wg1_l[d] = *(const short8*)&Wg1_g[oi << 3];
    *(short8*)&Wc_l[d]  = *(const short8*)&Wc_g[oi << 3];
  }
  if (t < 128) {
    float b = brp[t], g = bg[t], v = vp[t];
    br_l[t] = b; bg_l[t] = g; bgv_l[t] = g + v;
  }
  __syncthreads();

  const int wid  = t >> 6;
  const int lane = t & 63;
  const int lrow = lane & 15;
  const int lgrp = lane >> 4;
  const int nbt = (n + 127) >> 7;

  for (int tb = bid; tb < nbt; tb += gsz) {
    int m0 = tb * 128 + wid * 16;
    int m = m0 + lrow;
    bool ok = m < n;
    int cv = ok ? cntp[m] : 0;

    // x-fragments (B-operand layout == A layout): row m, octet ks*4+lgrp
    short8 am[4], ar[4];
    #pragma unroll
    for (int ks = 0; ks < 4; ++ks) {
      short8 z = {0, 0, 0, 0, 0, 0, 0, 0};
      am[ks] = z; ar[ks] = z;
      if (ok) {
        size_t off = (size_t)m * DD + ks * 32 + lgrp * 8;
        am[ks] = *(const short8*)&meanp[off];
        ar[ks] = *(const short8*)&rowsp[off];
      }
    }

    #pragma unroll
    for (int jt = 0; jt < 8; ++jt) {
      int j0 = jt * 16 + lgrp * 4;
      // t = mean @ Wr^T + br   (output dims j0..j0+3 for row m)
      f32x4 t4 = *(const f32x4*)&br_l[j0];
      #pragma unroll
      for (int ks = 0; ks < 4; ++ks) {
        short8 w = *(short8*)&Wr_l[(jt * 16 + lrow) * 128 +
                                   (((ks * 4 + lgrp) ^ lrow) << 3)];
        t4 = __builtin_amdgcn_mfma_f32_16x16x32_bf16(w, am[ks], t4, 0, 0, 0);
      }
      if (cv == 0) t4 = (f32x4){0.f, 0.f, 0.f, 0.f};

      // u = row @ Wg1^T + mean @ Wc^T + (cv ? bg+v : bg)
      f32x4 u4 = (cv > 0) ? *(const f32x4*)&bgv_l[j0]
                          : *(const f32x4*)&bg_l[j0];
      #pragma unroll
      for (int ks = 0; ks < 4; ++ks) {
        short8 w = *(short8*)&Wg1_l[(jt * 16 + lrow) * 128 +
                                    (((ks * 4 + lgrp) ^ lrow) << 3)];
        u4 = __builtin_amdgcn_mfma_f32_16x16x32_bf16(w, ar[ks], u4, 0, 0, 0);
      }
      #pragma unroll
      for (int ks = 0; ks < 4; ++ks) {
        short8 w = *(short8*)&Wc_l[(jt * 16 + lrow) * 128 +
                                   (((ks * 4 + lgrp) ^ lrow) << 3)];
        u4 = __builtin_amdgcn_mfma_f32_16x16x32_bf16(w, am[ks], u4, 0, 0, 0);
      }

      if (ok) {
        us4 rv = *(const us4*)&rowsp[(size_t)m * DD + j0];
        float4 o;
        float g0 = 1.f / (1.f + __expf(-u4[0]));
        float g1 = 1.f / (1.f + __expf(-u4[1]));
        float g2 = 1.f / (1.f + __expf(-u4[2]));
        float g3 = 1.f / (1.f + __expf(-u4[3]));
        o.x = g0 * b2f(rv[0]) + (1.f - g0) * t4[0];
        o.y = g1 * b2f(rv[1]) + (1.f - g1) * t4[1];
        o.z = g2 * b2f(rv[2]) + (1.f - g2) * t4[2];
        o.w = g3 * b2f(rv[3]) + (1.f - g3) * t4[3];
        *(float4*)&outp[(size_t)m * DD + j0] = o;
      }
    }
  }
}

extern "C" void kernel_launch(void* const* d_in, const int* in_sizes, int n_in,
                              void* d_out, int out_size, void* d_ws, size_t ws_size,
                              hipStream_t stream) {
  const float* A      = (const float*)d_in[0];
  const float* B      = (const float*)d_in[1];
  const float* W_fwd  = (const float*)d_in[2];
  const float* b_fwd  = (const float*)d_in[3];
  const float* W_rev  = (const float*)d_in[4];
  const float* b_rev  = (const float*)d_in[5];
  const float* W_gate = (const float*)d_in[6];
  const float* b_gate = (const float*)d_in[7];
  const int*   src    = (const int*)d_in[8];
  const int*   dst    = (const int*)d_in[9];

  const int n_a = in_sizes[0] / DD;
  const int n_b = in_sizes[1] / DD;
  const int E   = in_sizes[8];
  const int n_total = n_a + n_b;

  const int na_bins = (n_a + 1023) >> 10;
  const int nb_bins = (n_b + 255) >> 8;
  const int nbins   = na_bins + nb_bins;

  float* out = (float*)d_out;

  // workspace layout
  int* cnt      = (int*)d_ws;                        // [n_total]
  int* binraw   = cnt + n_total;                     // [1024]
  int* start    = binraw + 1024;                     // [n_total]
  int* cursor   = start + n_total;                   // [n_total]
  int* partials = cursor + n_total;                  // [1024]
  int* binstart = partials + 1024;                   // [1024]
  int* bincur   = binstart + 1024;                   // [1024]
  uint2* binrec = (uint2*)(bincur + 1024);           // [2E]
  int* partner  = (int*)(binrec + 2 * (size_t)E);    // [2E]
  uintptr_t wp = (uintptr_t)(partner + 2 * (size_t)E);
  wp = (wp + 63) & ~(uintptr_t)63;
  unsigned short* wbf = (unsigned short*)wp;         // [81920] bf16 weights
  float* vab = (float*)(wbf + 81920);                // [256] f32: vA | vB
  unsigned short* rows_bf = (unsigned short*)(vab + 256);  // [n_total*128]
  unsigned short* A_bf = rows_bf;
  unsigned short* B_bf = rows_bf + (size_t)n_a * DD;
  unsigned short* mean_bf = rows_bf + (size_t)n_total * DD; // [n_total*128]

  const int nch  = (n_total + SCHUNK - 1) / SCHUNK;
  const int eblk = (E + 255) / 256;
  const int nA4  = n_a * (DD / 4);
  const int nt4  = n_total * (DD / 4);

  hipMemsetAsync(cnt, 0, ((size_t)n_total + 1024) * sizeof(int), stream);

  rowconv_kernel<<<2048, 256, 0, stream>>>(A, B, rows_bf, nA4, nt4);
  wconv_kernel<<<192, 256, 0, stream>>>(W_rev, W_fwd, W_gate, wbf);
  wc_kernel<<<128, 128, 0, stream>>>(W_gate, W_rev, b_rev, wbf + 49152, vab);
  wc_kernel<<<128, 128, 0, stream>>>(W_gate, W_fwd, b_fwd, wbf + 65536, vab + 128);

  hist_kernel<<<eblk, 256, 0, stream>>>(src, dst, cnt, n_a, E);
  scan1_kernel<<<nch, 256, 0, stream>>>(cnt, n_total, partials);
  scan2_kernel<<<1, 256, 0, stream>>>(partials, nch);
  scan3_kernel<<<nch, 256, 0, stream>>>(cnt, n_total, partials, start, cursor);

  binhist_kernel<<<1024, 256, 0, stream>>>(src, dst, binraw, na_bins, nbins, E);
  binscan_kernel<<<1, 512, 0, stream>>>(binraw, nbins, binstart, bincur);
  binfill_kernel<<<(E + 4095) / 4096, 512, 0, stream>>>(
      src, dst, bincur, binrec, n_a, na_bins, nbins, E);
  binscatter_kernel<<<nbins, 256, 0, stream>>>(
      binrec, binstart, bincur, cursor, partner);

  aggregate_mean_bf16_kernel<<<(n_total + 3) / 4, 256, 0, stream>>>(
      A_bf, B_bf, partner, start, cnt, mean_bf, n_a, n_total);

  // merged post kernel: blocks [0,408) -> A range, [408,512) -> B range
  fused_post2_kernel<<<512, 512, 0, stream>>>(
      rows_bf, mean_bf, cnt, wbf, vab, b_rev, b_fwd, b_gate,
      out, n_a, n_b, 408);
}

// Round 13
// 481.796 us; speedup vs baseline: 1.3037x; 1.3037x over previous
//
#include <hip/hip_runtime.h>
#include <math.h>

#define DD 128
#define SCHUNK 2048

typedef __attribute__((ext_vector_type(8))) short short8;
typedef __attribute__((ext_vector_type(4))) float f32x4;
typedef __attribute__((ext_vector_type(4))) unsigned short us4;

__device__ __forceinline__ unsigned short f2bf(float f) {
  unsigned int u = __builtin_bit_cast(unsigned int, f);
  u = (u + 0x7FFFu + ((u >> 16) & 1u)) >> 16;   // RNE (finite inputs)
  return (unsigned short)u;
}

__device__ __forceinline__ float b2f(unsigned short u) {
  return __builtin_bit_cast(float, ((unsigned)u) << 16);
}

// ---------------------------------------------------------------------------
// Row conversion f32 -> bf16: [A | B] into one table.
// ---------------------------------------------------------------------------
__global__ __launch_bounds__(256) void rowconv_kernel(
    const float* __restrict__ A, const float* __restrict__ B,
    unsigned short* __restrict__ dst, int nA4, int ntot4)
{
  int stride = gridDim.x * 256;
  for (int i = blockIdx.x * 256 + threadIdx.x; i < ntot4; i += stride) {
    float4 v = (i < nA4) ? ((const float4*)A)[i] : ((const float4*)B)[i - nA4];
    us4 o;
    o[0] = f2bf(v.x); o[1] = f2bf(v.y); o[2] = f2bf(v.z); o[3] = f2bf(v.w);
    ((us4*)dst)[i] = o;
  }
}

// ---------------------------------------------------------------------------
// Weight conversion f32 -> bf16: [Wrev | Wfwd | Wg1] (Wg1 = W_gate[:, :128])
// ---------------------------------------------------------------------------
__global__ __launch_bounds__(256) void wconv_kernel(
    const float* __restrict__ Wrev, const float* __restrict__ Wfwd,
    const float* __restrict__ Wgate, unsigned short* __restrict__ dst)
{
  int i = blockIdx.x * 256 + threadIdx.x;   // 49152 total
  float v;
  if (i < 16384) v = Wrev[i];
  else if (i < 32768) v = Wfwd[i - 16384];
  else {
    int j = (i - 32768) >> 7, k = (i - 32768) & 127;
    v = Wgate[j * 256 + k];                 // first half of each gate row
  }
  dst[i] = f2bf(v);
}

// ---------------------------------------------------------------------------
// Wc[j][k] = sum_m Wg2[j][m]*Wr[m][k], v[j] = sum_m Wg2[j][m]*br[m]
// (Wg2 = W_gate[:, 128:]) — f32 accumulate, bf16 output. (round-12-proven)
// ---------------------------------------------------------------------------
__global__ __launch_bounds__(128) void wc_kernel(
    const float* __restrict__ Wgate, const float* __restrict__ Wr,
    const float* __restrict__ br, unsigned short* __restrict__ Wc_bf,
    float* __restrict__ v)
{
  int j = blockIdx.x, k = threadIdx.x;
  const float* g2 = Wgate + (size_t)j * 256 + 128;
  float acc = 0.f;
  for (int m = 0; m < 128; ++m) acc += g2[m] * Wr[m * 128 + k];
  Wc_bf[j * 128 + k] = f2bf(acc);
  if (k == 0) {
    float a = 0.f;
    for (int m = 0; m < 128; ++m) a += g2[m] * br[m];
    v[j] = a;
  }
}

// ---------------------------------------------------------------------------
// Phase 1: degree histogram (per-row counts)
// ---------------------------------------------------------------------------
__global__ __launch_bounds__(256) void hist_kernel(
    const int* __restrict__ src, const int* __restrict__ dst,
    int* __restrict__ cnt, int n_a, int E)
{
  int e = blockIdx.x * 256 + threadIdx.x;
  if (e >= E) return;
  atomicAdd(&cnt[src[e]], 1);
  atomicAdd(&cnt[n_a + dst[e]], 1);
}

// ---------------------------------------------------------------------------
// Phase 2: exclusive scan over row counts (3 kernels)
// ---------------------------------------------------------------------------
__global__ __launch_bounds__(256) void scan1_kernel(
    const int* __restrict__ cnt, int n, int* __restrict__ partials)
{
  __shared__ int sd[256];
  int t = threadIdx.x;
  int base = blockIdx.x * SCHUNK;
  int s = 0;
  #pragma unroll
  for (int k = 0; k < 8; ++k) {
    int i = base + t * 8 + k;
    s += (i < n) ? cnt[i] : 0;
  }
  sd[t] = s;
  __syncthreads();
  for (int off = 128; off > 0; off >>= 1) {
    if (t < off) sd[t] += sd[t + off];
    __syncthreads();
  }
  if (t == 0) partials[blockIdx.x] = sd[0];
}

__global__ __launch_bounds__(256) void scan2_kernel(int* __restrict__ partials, int nch)
{
  __shared__ int buf[256];
  int t = threadIdx.x;
  int v = (t < nch) ? partials[t] : 0;
  buf[t] = v;
  __syncthreads();
  for (int off = 1; off < 256; off <<= 1) {
    int x = (t >= off) ? buf[t - off] : 0;
    __syncthreads();
    buf[t] += x;
    __syncthreads();
  }
  if (t < nch) partials[t] = buf[t] - v;   // exclusive
}

__global__ __launch_bounds__(256) void scan3_kernel(
    const int* __restrict__ cnt, int n, const int* __restrict__ partials,
    int* __restrict__ start, int* __restrict__ cursor)
{
  __shared__ int sd[256];
  int t = threadIdx.x;
  int base = blockIdx.x * SCHUNK;
  int loc[8];
  int s = 0;
  #pragma unroll
  for (int k = 0; k < 8; ++k) {
    int i = base + t * 8 + k;
    loc[k] = (i < n) ? cnt[i] : 0;
    s += loc[k];
  }
  sd[t] = s;
  __syncthreads();
  for (int off = 1; off < 256; off <<= 1) {
    int x = (t >= off) ? sd[t - off] : 0;
    __syncthreads();
    sd[t] += x;
    __syncthreads();
  }
  int off = partials[blockIdx.x] + sd[t] - s;
  #pragma unroll
  for (int k = 0; k < 8; ++k) {
    int i = base + t * 8 + k;
    if (i < n) { start[i] = off; cursor[i] = off; }
    off += loc[k];
  }
}

// ---------------------------------------------------------------------------
// Phase 3a: bin histogram. A rows: 1024-row bins; B rows: 256-row bins.
// ---------------------------------------------------------------------------
__global__ __launch_bounds__(256) void binhist_kernel(
    const int* __restrict__ src, const int* __restrict__ dst,
    int* __restrict__ binraw, int na_bins, int nbins, int E)
{
  __shared__ int h[1024];
  int t = threadIdx.x;
  for (int i = t; i < 1024; i += 256) h[i] = 0;
  __syncthreads();
  int stride = gridDim.x * 256;
  for (int e = blockIdx.x * 256 + t; e < E; e += stride) {
    int s = src[e], d = dst[e];
    atomicAdd(&h[s >> 10], 1);
    atomicAdd(&h[na_bins + (d >> 8)], 1);
  }
  __syncthreads();
  for (int i = t; i < nbins; i += 256)
    if (h[i]) atomicAdd(&binraw[i], h[i]);
}

// ---------------------------------------------------------------------------
// Phase 3b: exclusive scan over bin counts (single block, nbins <= 512)
// ---------------------------------------------------------------------------
__global__ __launch_bounds__(512) void binscan_kernel(
    const int* __restrict__ binraw, int nbins,
    int* __restrict__ binstart, int* __restrict__ bincur)
{
  __shared__ int buf[512];
  int t = threadIdx.x;
  int v = (t < nbins) ? binraw[t] : 0;
  buf[t] = v;
  __syncthreads();
  for (int off = 1; off < 512; off <<= 1) {
    int x = (t >= off) ? buf[t - off] : 0;
    __syncthreads();
    buf[t] += x;
    __syncthreads();
  }
  if (t < nbins) {
    int excl = buf[t] - v;
    binstart[t] = excl;
    bincur[t] = excl;
  }
}

// ---------------------------------------------------------------------------
// Phase 3c: binfill — rank 8192 records per-bin in LDS, reserve dense runs,
// write (key=row, val=partner) as per-CU dense runs.
// ---------------------------------------------------------------------------
__global__ __launch_bounds__(512) void binfill_kernel(
    const int* __restrict__ src, const int* __restrict__ dst,
    int* __restrict__ bincur, uint2* __restrict__ binrec,
    int n_a, int na_bins, int nbins, int E)
{
  __shared__ int lcnt[1024];
  __shared__ int goff[1024];
  const int t = threadIdx.x;
  const int base = blockIdx.x * 4096;
  for (int i = t; i < 1024; i += 512) lcnt[i] = 0;
  __syncthreads();

  int bins[16], ranks[16];
  unsigned keys[16], vals[16];
  #pragma unroll
  for (int j = 0; j < 8; ++j) {
    int e = base + j * 512 + t;
    int i0 = 2 * j, i1 = 2 * j + 1;
    if (e < E) {
      int s = src[e], d = dst[e];
      bins[i0] = s >> 10;               keys[i0] = (unsigned)s;       vals[i0] = (unsigned)d;
      bins[i1] = na_bins + (d >> 8);    keys[i1] = (unsigned)(n_a + d); vals[i1] = (unsigned)s;
      ranks[i0] = atomicAdd(&lcnt[bins[i0]], 1);
      ranks[i1] = atomicAdd(&lcnt[bins[i1]], 1);
    } else {
      bins[i0] = -1; bins[i1] = -1;
      ranks[i0] = 0;  ranks[i1] = 0;
      keys[i0] = 0;   keys[i1] = 0;
      vals[i0] = 0;   vals[i1] = 0;
    }
  }
  __syncthreads();
  for (int b = t; b < nbins; b += 512)
    if (lcnt[b]) goff[b] = atomicAdd(&bincur[b], lcnt[b]);
  __syncthreads();
  #pragma unroll
  for (int i = 0; i < 16; ++i) {
    if (bins[i] >= 0) {
      int p = goff[bins[i]] + ranks[i];
      binrec[p] = make_uint2(keys[i], vals[i]);
    }
  }
}

// ---------------------------------------------------------------------------
// Phase 3d: fine scatter, one block per bin (exclusively-owned L2-local bin).
// ---------------------------------------------------------------------------
__global__ __launch_bounds__(256) void binscatter_kernel(
    const uint2* __restrict__ binrec, const int* __restrict__ binstart,
    const int* __restrict__ binend, int* __restrict__ cursor,
    int* __restrict__ partner)
{
  int b = blockIdx.x;
  int s0 = binstart[b], e0 = binend[b];
  for (int i = s0 + threadIdx.x; i < e0; i += 256) {
    uint2 r = binrec[i];
    int pos = atomicAdd(&cursor[r.x], 1);
    partner[pos] = (int)r.y;
  }
}

// ---------------------------------------------------------------------------
// Phase 4: one wave per row; 32 lanes x 8B cover a 256B bf16 row, half-waves
// take even/odd edges; combine with shfl_xor(32).
// ---------------------------------------------------------------------------
__global__ __launch_bounds__(256) void aggregate_mean_bf16_kernel(
    const unsigned short* __restrict__ A_bf,
    const unsigned short* __restrict__ B_bf,
    const int* __restrict__ partner, const int* __restrict__ start,
    const int* __restrict__ cnt, unsigned short* __restrict__ mean_bf,
    int n_a, int n_total)
{
  int wid = (blockIdx.x * 256 + threadIdx.x) >> 6;
  if (wid >= n_total) return;
  int lane = threadIdx.x & 63;
  int c2 = lane & 31;
  int h  = lane >> 5;
  int s0 = start[wid], c = cnt[wid];
  const unsigned short* tbl = (wid < n_a) ? B_bf : A_bf;
  float a0 = 0.f, a1 = 0.f, a2 = 0.f, a3 = 0.f;
  int k = 0;
  for (; k + 8 <= c; k += 8) {
    int p0 = partner[s0 + k + 0 + h];
    int p1 = partner[s0 + k + 2 + h];
    int p2 = partner[s0 + k + 4 + h];
    int p3 = partner[s0 + k + 6 + h];
    us4 v0 = *(const us4*)(tbl + (size_t)p0 * DD + 4 * c2);
    us4 v1 = *(const us4*)(tbl + (size_t)p1 * DD + 4 * c2);
    us4 v2 = *(const us4*)(tbl + (size_t)p2 * DD + 4 * c2);
    us4 v3 = *(const us4*)(tbl + (size_t)p3 * DD + 4 * c2);
    a0 += b2f(v0[0]) + b2f(v1[0]) + b2f(v2[0]) + b2f(v3[0]);
    a1 += b2f(v0[1]) + b2f(v1[1]) + b2f(v2[1]) + b2f(v3[1]);
    a2 += b2f(v0[2]) + b2f(v1[2]) + b2f(v2[2]) + b2f(v3[2]);
    a3 += b2f(v0[3]) + b2f(v1[3]) + b2f(v2[3]) + b2f(v3[3]);
  }
  for (; k < c; k += 2) {
    int i = k + h;
    if (i < c) {
      int p = partner[s0 + i];
      us4 v = *(const us4*)(tbl + (size_t)p * DD + 4 * c2);
      a0 += b2f(v[0]); a1 += b2f(v[1]); a2 += b2f(v[2]); a3 += b2f(v[3]);
    }
  }
  a0 += __shfl_xor(a0, 32);
  a1 += __shfl_xor(a1, 32);
  a2 += __shfl_xor(a2, 32);
  a3 += __shfl_xor(a3, 32);
  if (lane < 32) {
    float inv = (c > 0) ? (1.f / (float)c) : 0.f;
    us4 o;
    o[0] = f2bf(a0 * inv); o[1] = f2bf(a1 * inv);
    o[2] = f2bf(a2 * inv); o[3] = f2bf(a3 * inv);
    *(us4*)&mean_bf[(size_t)wid * DD + 4 * c2] = o;
  }
}

// ---------------------------------------------------------------------------
// Phase 5+6 fused v3 (MFMA) — round-11-proven body + Wc algebra (no patch):
//   t = (cnt>0) ? mean @ Wr^T + br : 0
//   u = row @ Wg1^T + mean @ Wc^T + (cnt>0 ? bg+v : bg)    [Wc=Wg2@Wr, v=Wg2@br]
//   out = sigmoid(u)*row + (1-sigmoid(u))*t
// 512 threads = 8 waves x 16 rows = 128 rows/block. Old operand order, old
// store pattern (proven). No LDS writes after staging. LDS = 96 KB + biases.
// ---------------------------------------------------------------------------
__global__ __launch_bounds__(512) void fused_post_kernel(
    const unsigned short* __restrict__ rows16,  // bf16 rows of this range
    const unsigned short* __restrict__ mean_bf, // bf16 mean of this range
    const int* __restrict__ cnt,                // range-local
    const unsigned short* __restrict__ Wr_bf,   // [128][128] bf16
    const unsigned short* __restrict__ Wg1_bf,  // [128][128] bf16
    const unsigned short* __restrict__ Wc_bf,   // [128][128] bf16
    const float* __restrict__ br, const float* __restrict__ bg,
    const float* __restrict__ vv,
    float* __restrict__ out, int n)
{
  __shared__ unsigned short Wr_l[128 * 128];   // 32 KB
  __shared__ unsigned short Wg1_l[128 * 128];  // 32 KB
  __shared__ unsigned short Wc_l[128 * 128];   // 32 KB
  __shared__ float br_l[128];
  __shared__ float bg_l[128];
  __shared__ float v_l[128];

  const int t = threadIdx.x;
  // stage 3x 128x128 bf16 (2048 16B-octets each), proven octet-XOR swizzle
  for (int oi = t; oi < 2048; oi += 512) {
    int j = oi >> 4, o = oi & 15;
    int d = j * 128 + ((o ^ (j & 15)) << 3);
    *(short8*)&Wr_l[d]  = *(const short8*)&Wr_bf[oi << 3];
    *(short8*)&Wg1_l[d] = *(const short8*)&Wg1_bf[oi << 3];
    *(short8*)&Wc_l[d]  = *(const short8*)&Wc_bf[oi << 3];
  }
  if (t < 128) { br_l[t] = br[t]; bg_l[t] = bg[t]; v_l[t] = vv[t]; }
  __syncthreads();

  const int wid  = t >> 6;
  const int lane = t & 63;
  const int lrow = lane & 15;   // A/B fragment: row/col index
  const int lgrp = lane >> 4;   // k-octet group
  const int m0 = blockIdx.x * 128 + wid * 16;
  if (m0 >= n) return;

  const int mr = m0 + lrow;
  const bool rowok = mr < n;

  // A-fragments of mean and row: direct 16B global bf16 loads (proven)
  short8 am[4], ar[4];
  #pragma unroll
  for (int ks = 0; ks < 4; ++ks) {
    short8 z = {0, 0, 0, 0, 0, 0, 0, 0};
    am[ks] = z; ar[ks] = z;
    if (rowok) {
      size_t off = (size_t)mr * DD + ks * 32 + lgrp * 8;
      am[ks] = *(const short8*)&mean_bf[off];
      ar[ks] = *(const short8*)&rows16[off];
    }
  }

  // t = mean @ Wr^T + br
  f32x4 tac[8];
  #pragma unroll
  for (int jt = 0; jt < 8; ++jt) {
    float bv = br_l[jt * 16 + lrow];
    f32x4 c = {bv, bv, bv, bv};
    #pragma unroll
    for (int ks = 0; ks < 4; ++ks) {
      int o = ks * 4 + lgrp;
      short8 b = *(short8*)&Wr_l[(jt * 16 + lrow) * 128 + ((o ^ lrow) << 3)];
      c = __builtin_amdgcn_mfma_f32_16x16x32_bf16(am[ks], b, c, 0, 0, 0);
    }
    tac[jt] = c;
  }

  // cnt per output row (C/D rows of this lane): cnt==0 -> t = 0
  const int rbase = m0 + lgrp * 4;
  int cv4[4];
  #pragma unroll
  for (int r = 0; r < 4; ++r) {
    int rr = rbase + r;
    cv4[r] = (rr < n) ? cnt[rr] : 0;
    if (cv4[r] == 0) {
      #pragma unroll
      for (int jt = 0; jt < 8; ++jt) tac[jt][r] = 0.f;
    }
  }

  // gate: u = row @ Wg1^T + mean @ Wc^T + (cv ? bg+v : bg); blend + store
  #pragma unroll
  for (int jt = 0; jt < 8; ++jt) {
    int col = jt * 16 + lrow;
    float bgc = bg_l[col];
    float bgv = bgc + v_l[col];
    f32x4 c;
    #pragma unroll
    for (int r = 0; r < 4; ++r) c[r] = (cv4[r] > 0) ? bgv : bgc;
    #pragma unroll
    for (int ks = 0; ks < 4; ++ks) {
      int o = ks * 4 + lgrp;
      short8 b = *(short8*)&Wg1_l[(jt * 16 + lrow) * 128 + ((o ^ lrow) << 3)];
      c = __builtin_amdgcn_mfma_f32_16x16x32_bf16(ar[ks], b, c, 0, 0, 0);
    }
    #pragma unroll
    for (int ks = 0; ks < 4; ++ks) {
      int o = ks * 4 + lgrp;
      short8 b = *(short8*)&Wc_l[(jt * 16 + lrow) * 128 + ((o ^ lrow) << 3)];
      c = __builtin_amdgcn_mfma_f32_16x16x32_bf16(am[ks], b, c, 0, 0, 0);
    }
    #pragma unroll
    for (int r = 0; r < 4; ++r) {
      int rr = rbase + r;
      if (rr < n) {
        float g = 1.f / (1.f + __expf(-c[r]));
        float rowf = b2f(rows16[(size_t)rr * DD + col]);
        out[(size_t)rr * DD + col] = g * rowf + (1.f - g) * tac[jt][r];
      }
    }
  }
}

extern "C" void kernel_launch(void* const* d_in, const int* in_sizes, int n_in,
                              void* d_out, int out_size, void* d_ws, size_t ws_size,
                              hipStream_t stream) {
  const float* A      = (const float*)d_in[0];
  const float* B      = (const float*)d_in[1];
  const float* W_fwd  = (const float*)d_in[2];
  const float* b_fwd  = (const float*)d_in[3];
  const float* W_rev  = (const float*)d_in[4];
  const float* b_rev  = (const float*)d_in[5];
  const float* W_gate = (const float*)d_in[6];
  const float* b_gate = (const float*)d_in[7];
  const int*   src    = (const int*)d_in[8];
  const int*   dst    = (const int*)d_in[9];

  const int n_a = in_sizes[0] / DD;
  const int n_b = in_sizes[1] / DD;
  const int E   = in_sizes[8];
  const int n_total = n_a + n_b;

  const int na_bins = (n_a + 1023) >> 10;
  const int nb_bins = (n_b + 255) >> 8;
  const int nbins   = na_bins + nb_bins;

  float* out = (float*)d_out;

  // workspace layout
  int* cnt      = (int*)d_ws;                        // [n_total]
  int* binraw   = cnt + n_total;                     // [1024]
  int* start    = binraw + 1024;                     // [n_total]
  int* cursor   = start + n_total;                   // [n_total]
  int* partials = cursor + n_total;                  // [1024]
  int* binstart = partials + 1024;                   // [1024]
  int* bincur   = binstart + 1024;                   // [1024]
  uint2* binrec = (uint2*)(bincur + 1024);           // [2E]
  int* partner  = (int*)(binrec + 2 * (size_t)E);    // [2E]
  uintptr_t wp = (uintptr_t)(partner + 2 * (size_t)E);
  wp = (wp + 63) & ~(uintptr_t)63;
  unsigned short* wbf = (unsigned short*)wp;         // [81920]: Wrev|Wfwd|Wg1|WcA|WcB
  float* vab = (float*)(wbf + 81920);                // [256] f32: vA | vB
  unsigned short* rows_bf = (unsigned short*)(vab + 256);  // [n_total*128]
  unsigned short* A_bf = rows_bf;
  unsigned short* B_bf = rows_bf + (size_t)n_a * DD;
  unsigned short* mean_bf = rows_bf + (size_t)n_total * DD; // [n_total*128]

  const int nch  = (n_total + SCHUNK - 1) / SCHUNK;
  const int eblk = (E + 255) / 256;
  const int nA4  = n_a * (DD / 4);
  const int nt4  = n_total * (DD / 4);

  hipMemsetAsync(cnt, 0, ((size_t)n_total + 1024) * sizeof(int), stream);

  rowconv_kernel<<<2048, 256, 0, stream>>>(A, B, rows_bf, nA4, nt4);
  wconv_kernel<<<192, 256, 0, stream>>>(W_rev, W_fwd, W_gate, wbf);
  wc_kernel<<<128, 128, 0, stream>>>(W_gate, W_rev, b_rev, wbf + 49152, vab);
  wc_kernel<<<128, 128, 0, stream>>>(W_gate, W_fwd, b_fwd, wbf + 65536, vab + 128);

  hist_kernel<<<eblk, 256, 0, stream>>>(src, dst, cnt, n_a, E);
  scan1_kernel<<<nch, 256, 0, stream>>>(cnt, n_total, partials);
  scan2_kernel<<<1, 256, 0, stream>>>(partials, nch);
  scan3_kernel<<<nch, 256, 0, stream>>>(cnt, n_total, partials, start, cursor);

  binhist_kernel<<<1024, 256, 0, stream>>>(src, dst, binraw, na_bins, nbins, E);
  binscan_kernel<<<1, 512, 0, stream>>>(binraw, nbins, binstart, bincur);
  binfill_kernel<<<(E + 4095) / 4096, 512, 0, stream>>>(
      src, dst, bincur, binrec, n_a, na_bins, nbins, E);
  binscatter_kernel<<<nbins, 256, 0, stream>>>(
      binrec, binstart, bincur, cursor, partner);

  aggregate_mean_bf16_kernel<<<(n_total + 3) / 4, 256, 0, stream>>>(
      A_bf, B_bf, partner, start, cnt, mean_bf, n_a, n_total);

  // A range: t = mean_a @ W_rev^T + b_rev ; gate uses Wg1 + WcA (+vA)
  fused_post_kernel<<<(n_a + 127) / 128, 512, 0, stream>>>(
      A_bf, mean_bf, cnt, wbf, wbf + 32768, wbf + 49152,
      b_rev, b_gate, vab, out, n_a);
  // B range: t = mean_b @ W_fwd^T + b_fwd ; gate uses Wg1 + WcB (+vB)
  fused_post_kernel<<<(n_b + 127) / 128, 512, 0, stream>>>(
      B_bf, mean_bf + (size_t)n_a * DD, cnt + n_a, wbf + 16384, wbf + 32768,
      wbf + 65536, b_fwd, b_gate, vab + 128,
      out + (size_t)n_a * DD, n_b);
}

// Round 14
// 334.076 us; speedup vs baseline: 1.8802x; 1.4422x over previous
//
#include <hip/hip_runtime.h>
#include <math.h>

#define DD 128

typedef __attribute__((ext_vector_type(8))) short short8;
typedef __attribute__((ext_vector_type(4))) float f32x4;
typedef __attribute__((ext_vector_type(4))) unsigned short us4;
typedef __attribute__((ext_vector_type(8))) unsigned short us8;

__device__ __forceinline__ unsigned short f2bf(float f) {
  unsigned int u = __builtin_bit_cast(unsigned int, f);
  u = (u + 0x7FFFu + ((u >> 16) & 1u)) >> 16;   // RNE (finite inputs)
  return (unsigned short)u;
}

__device__ __forceinline__ float b2f(unsigned short u) {
  return __builtin_bit_cast(float, ((unsigned)u) << 16);
}

// ---------------------------------------------------------------------------
// Row conversion f32 -> bf16: [A | B] into one table.
// ---------------------------------------------------------------------------
__global__ __launch_bounds__(256) void rowconv_kernel(
    const float* __restrict__ A, const float* __restrict__ B,
    unsigned short* __restrict__ dst, int nA4, int ntot4)
{
  int stride = gridDim.x * 256;
  for (int i = blockIdx.x * 256 + threadIdx.x; i < ntot4; i += stride) {
    float4 v = (i < nA4) ? ((const float4*)A)[i] : ((const float4*)B)[i - nA4];
    us4 o;
    o[0] = f2bf(v.x); o[1] = f2bf(v.y); o[2] = f2bf(v.z); o[3] = f2bf(v.w);
    ((us4*)dst)[i] = o;
  }
}

// ---------------------------------------------------------------------------
// Weight conversion f32 -> bf16: [Wrev | Wfwd | Wg1] (Wg1 = W_gate[:, :128])
// ---------------------------------------------------------------------------
__global__ __launch_bounds__(256) void wconv_kernel(
    const float* __restrict__ Wrev, const float* __restrict__ Wfwd,
    const float* __restrict__ Wgate, unsigned short* __restrict__ dst)
{
  int i = blockIdx.x * 256 + threadIdx.x;   // 49152 total
  float v;
  if (i < 16384) v = Wrev[i];
  else if (i < 32768) v = Wfwd[i - 16384];
  else {
    int j = (i - 32768) >> 7, k = (i - 32768) & 127;
    v = Wgate[j * 256 + k];                 // first half of each gate row
  }
  dst[i] = f2bf(v);
}

// ---------------------------------------------------------------------------
// Wc[j][k] = sum_m Wg2[j][m]*Wr[m][k], v[j] = sum_m Wg2[j][m]*br[m]
// (Wg2 = W_gate[:, 128:]) — f32 accumulate, bf16 output. (round-12/13-proven)
// ---------------------------------------------------------------------------
__global__ __launch_bounds__(128) void wc_kernel(
    const float* __restrict__ Wgate, const float* __restrict__ Wr,
    const float* __restrict__ br, unsigned short* __restrict__ Wc_bf,
    float* __restrict__ v)
{
  int j = blockIdx.x, k = threadIdx.x;
  const float* g2 = Wgate + (size_t)j * 256 + 128;
  float acc = 0.f;
  for (int m = 0; m < 128; ++m) acc += g2[m] * Wr[m * 128 + k];
  Wc_bf[j * 128 + k] = f2bf(acc);
  if (k == 0) {
    float a = 0.f;
    for (int m = 0; m < 128; ++m) a += g2[m] * br[m];
    v[j] = a;
  }
}

// ---------------------------------------------------------------------------
// Bin histogram. A rows: 1024-row bins; B rows: 256-row bins. (proven)
// ---------------------------------------------------------------------------
__global__ __launch_bounds__(256) void binhist_kernel(
    const int* __restrict__ src, const int* __restrict__ dst,
    int* __restrict__ binraw, int na_bins, int nbins, int E)
{
  __shared__ int h[1024];
  int t = threadIdx.x;
  for (int i = t; i < 1024; i += 256) h[i] = 0;
  __syncthreads();
  int stride = gridDim.x * 256;
  for (int e = blockIdx.x * 256 + t; e < E; e += stride) {
    int s = src[e], d = dst[e];
    atomicAdd(&h[s >> 10], 1);
    atomicAdd(&h[na_bins + (d >> 8)], 1);
  }
  __syncthreads();
  for (int i = t; i < nbins; i += 256)
    if (h[i]) atomicAdd(&binraw[i], h[i]);
}

// ---------------------------------------------------------------------------
// Exclusive scan over bin counts (single block, nbins <= 512). (proven)
// ---------------------------------------------------------------------------
__global__ __launch_bounds__(512) void binscan_kernel(
    const int* __restrict__ binraw, int nbins,
    int* __restrict__ binstart, int* __restrict__ bincur)
{
  __shared__ int buf[512];
  int t = threadIdx.x;
  int v = (t < nbins) ? binraw[t] : 0;
  buf[t] = v;
  __syncthreads();
  for (int off = 1; off < 512; off <<= 1) {
    int x = (t >= off) ? buf[t - off] : 0;
    __syncthreads();
    buf[t] += x;
    __syncthreads();
  }
  if (t < nbins) {
    int excl = buf[t] - v;
    binstart[t] = excl;
    bincur[t] = excl;
  }
}

// ---------------------------------------------------------------------------
// binfill — rank 8192 records per-bin in LDS, reserve dense runs, write
// (key=row, val=partner) as per-CU dense runs. (proven)
// ---------------------------------------------------------------------------
__global__ __launch_bounds__(512) void binfill_kernel(
    const int* __restrict__ src, const int* __restrict__ dst,
    int* __restrict__ bincur, uint2* __restrict__ binrec,
    int n_a, int na_bins, int nbins, int E)
{
  __shared__ int lcnt[1024];
  __shared__ int goff[1024];
  const int t = threadIdx.x;
  const int base = blockIdx.x * 4096;
  for (int i = t; i < 1024; i += 512) lcnt[i] = 0;
  __syncthreads();

  int bins[16], ranks[16];
  unsigned keys[16], vals[16];
  #pragma unroll
  for (int j = 0; j < 8; ++j) {
    int e = base + j * 512 + t;
    int i0 = 2 * j, i1 = 2 * j + 1;
    if (e < E) {
      int s = src[e], d = dst[e];
      bins[i0] = s >> 10;               keys[i0] = (unsigned)s;       vals[i0] = (unsigned)d;
      bins[i1] = na_bins + (d >> 8);    keys[i1] = (unsigned)(n_a + d); vals[i1] = (unsigned)s;
      ranks[i0] = atomicAdd(&lcnt[bins[i0]], 1);
      ranks[i1] = atomicAdd(&lcnt[bins[i1]], 1);
    } else {
      bins[i0] = -1; bins[i1] = -1;
      ranks[i0] = 0;  ranks[i1] = 0;
      keys[i0] = 0;   keys[i1] = 0;
      vals[i0] = 0;   vals[i1] = 0;
    }
  }
  __syncthreads();
  for (int b = t; b < nbins; b += 512)
    if (lcnt[b]) goff[b] = atomicAdd(&bincur[b], lcnt[b]);
  __syncthreads();
  #pragma unroll
  for (int i = 0; i < 16; ++i) {
    if (bins[i] >= 0) {
      int p = goff[bins[i]] + ranks[i];
      binrec[p] = make_uint2(keys[i], vals[i]);
    }
  }
}

// ---------------------------------------------------------------------------
// binscatter2 — one block per bin. Per-bin LDS counting sort: count per row,
// 1024-wide LDS exclusive scan, write start/cnt for the bin's rows, then
// scatter partners into the bin's exclusively-owned region. Subsumes the
// old global hist + 3 scan kernels.
// ---------------------------------------------------------------------------
__global__ __launch_bounds__(256) void binscatter2_kernel(
    const uint2* __restrict__ binrec, const int* __restrict__ binstart,
    const int* __restrict__ binend, int* __restrict__ partner,
    int* __restrict__ start, int* __restrict__ cnt,
    int n_a, int n_total, int na_bins)
{
  __shared__ int cntL[1024];
  __shared__ int curL[1024];
  __shared__ int sbuf[256];
  const int b = blockIdx.x;
  const int t = threadIdx.x;
  int row0, nrows;
  if (b < na_bins) { row0 = b << 10; nrows = min(1024, n_a - row0); }
  else { row0 = n_a + ((b - na_bins) << 8); nrows = min(256, n_total - row0); }
  const int s0 = binstart[b], e0 = binend[b];

  for (int i = t; i < 1024; i += 256) cntL[i] = 0;
  __syncthreads();
  // pass 1: per-row counts (records are L2-resident for pass 2 re-read)
  for (int i = s0 + t; i < e0; i += 256)
    atomicAdd(&cntL[binrec[i].x - (unsigned)row0], 1);
  __syncthreads();
  // exclusive scan of cntL[0..1024): 4 elems/thread + block scan
  int l0 = cntL[4 * t], l1 = cntL[4 * t + 1];
  int l2 = cntL[4 * t + 2], l3 = cntL[4 * t + 3];
  int s = l0 + l1 + l2 + l3;
  sbuf[t] = s;
  __syncthreads();
  for (int off = 1; off < 256; off <<= 1) {
    int x = (t >= off) ? sbuf[t - off] : 0;
    __syncthreads();
    sbuf[t] += x;
    __syncthreads();
  }
  int excl = sbuf[t] - s;
  curL[4 * t]     = excl;
  curL[4 * t + 1] = excl + l0;
  curL[4 * t + 2] = excl + l0 + l1;
  curL[4 * t + 3] = excl + l0 + l1 + l2;
  __syncthreads();
  // write per-row start/cnt (covers every row of this bin, incl. zero-degree)
  for (int j = t; j < nrows; j += 256) {
    start[row0 + j] = s0 + curL[j];
    cnt[row0 + j] = cntL[j];
  }
  __syncthreads();
  // pass 2: scatter partners within the exclusively-owned region
  for (int i = s0 + t; i < e0; i += 256) {
    uint2 r = binrec[i];
    int pos = atomicAdd(&curL[r.x - (unsigned)row0], 1);
    partner[s0 + pos] = (int)r.y;
  }
}

// ---------------------------------------------------------------------------
// Aggregate v3: one wave per row; 16 lanes x 16B (us8) cover a 256B bf16 row,
// 4 quads process 4 edges per wave-load batch (16 edges/iter, 4 loads deep).
// Reduce across quads with shfl_xor(16/32); lanes<16 write mean (us8).
// ---------------------------------------------------------------------------
__global__ __launch_bounds__(256) void aggregate_mean_bf16_kernel(
    const unsigned short* __restrict__ A_bf,
    const unsigned short* __restrict__ B_bf,
    const int* __restrict__ partner, const int* __restrict__ start,
    const int* __restrict__ cnt, unsigned short* __restrict__ mean_bf,
    int n_a, int n_total)
{
  int wid = (blockIdx.x * 256 + threadIdx.x) >> 6;
  if (wid >= n_total) return;
  int lane = threadIdx.x & 63;
  int q    = lane & 15;      // 16B chunk: elements 8q .. 8q+7
  int quad = lane >> 4;      // edge slot within a batch of 4
  int s0 = start[wid], c = cnt[wid];
  const unsigned short* tbl = (wid < n_a) ? B_bf : A_bf;
  float a0 = 0.f, a1 = 0.f, a2 = 0.f, a3 = 0.f;
  float a4 = 0.f, a5 = 0.f, a6 = 0.f, a7 = 0.f;
  int k = 0;
  for (; k + 16 <= c; k += 16) {       // 4 batches = 16 edges in flight
    int p0 = partner[s0 + k + 0 + quad];
    int p1 = partner[s0 + k + 4 + quad];
    int p2 = partner[s0 + k + 8 + quad];
    int p3 = partner[s0 + k + 12 + quad];
    us8 v0 = *(const us8*)(tbl + (size_t)p0 * DD + 8 * q);
    us8 v1 = *(const us8*)(tbl + (size_t)p1 * DD + 8 * q);
    us8 v2 = *(const us8*)(tbl + (size_t)p2 * DD + 8 * q);
    us8 v3 = *(const us8*)(tbl + (size_t)p3 * DD + 8 * q);
    a0 += b2f(v0[0]) + b2f(v1[0]) + b2f(v2[0]) + b2f(v3[0]);
    a1 += b2f(v0[1]) + b2f(v1[1]) + b2f(v2[1]) + b2f(v3[1]);
    a2 += b2f(v0[2]) + b2f(v1[2]) + b2f(v2[2]) + b2f(v3[2]);
    a3 += b2f(v0[3]) + b2f(v1[3]) + b2f(v2[3]) + b2f(v3[3]);
    a4 += b2f(v0[4]) + b2f(v1[4]) + b2f(v2[4]) + b2f(v3[4]);
    a5 += b2f(v0[5]) + b2f(v1[5]) + b2f(v2[5]) + b2f(v3[5]);
    a6 += b2f(v0[6]) + b2f(v1[6]) + b2f(v2[6]) + b2f(v3[6]);
    a7 += b2f(v0[7]) + b2f(v1[7]) + b2f(v2[7]) + b2f(v3[7]);
  }
  for (; k < c; k += 4) {              // tail: up to 4 edges per step
    int i = k + quad;
    if (i < c) {
      int p = partner[s0 + i];
      us8 v = *(const us8*)(tbl + (size_t)p * DD + 8 * q);
      a0 += b2f(v[0]); a1 += b2f(v[1]); a2 += b2f(v[2]); a3 += b2f(v[3]);
      a4 += b2f(v[4]); a5 += b2f(v[5]); a6 += b2f(v[6]); a7 += b2f(v[7]);
    }
  }
  a0 += __shfl_xor(a0, 16); a0 += __shfl_xor(a0, 32);
  a1 += __shfl_xor(a1, 16); a1 += __shfl_xor(a1, 32);
  a2 += __shfl_xor(a2, 16); a2 += __shfl_xor(a2, 32);
  a3 += __shfl_xor(a3, 16); a3 += __shfl_xor(a3, 32);
  a4 += __shfl_xor(a4, 16); a4 += __shfl_xor(a4, 32);
  a5 += __shfl_xor(a5, 16); a5 += __shfl_xor(a5, 32);
  a6 += __shfl_xor(a6, 16); a6 += __shfl_xor(a6, 32);
  a7 += __shfl_xor(a7, 16); a7 += __shfl_xor(a7, 32);
  if (lane < 16) {
    float inv = (c > 0) ? (1.f / (float)c) : 0.f;
    us8 o;
    o[0] = f2bf(a0 * inv); o[1] = f2bf(a1 * inv);
    o[2] = f2bf(a2 * inv); o[3] = f2bf(a3 * inv);
    o[4] = f2bf(a4 * inv); o[5] = f2bf(a5 * inv);
    o[6] = f2bf(a6 * inv); o[7] = f2bf(a7 * inv);
    *(us8*)&mean_bf[(size_t)wid * DD + 8 * q] = o;
  }
}

// ---------------------------------------------------------------------------
// Fused post (MFMA) — round-13-proven body (Wc algebra, no patch):
//   t = (cnt>0) ? mean @ Wr^T + br : 0
//   u = row @ Wg1^T + mean @ Wc^T + (cnt>0 ? bg+v : bg)
//   out = sigmoid(u)*row + (1-sigmoid(u))*t
// ---------------------------------------------------------------------------
__global__ __launch_bounds__(512) void fused_post_kernel(
    const unsigned short* __restrict__ rows16,  // bf16 rows of this range
    const unsigned short* __restrict__ mean_bf, // bf16 mean of this range
    const int* __restrict__ cnt,                // range-local
    const unsigned short* __restrict__ Wr_bf,   // [128][128] bf16
    const unsigned short* __restrict__ Wg1_bf,  // [128][128] bf16
    const unsigned short* __restrict__ Wc_bf,   // [128][128] bf16
    const float* __restrict__ br, const float* __restrict__ bg,
    const float* __restrict__ vv,
    float* __restrict__ out, int n)
{
  __shared__ unsigned short Wr_l[128 * 128];   // 32 KB
  __shared__ unsigned short Wg1_l[128 * 128];  // 32 KB
  __shared__ unsigned short Wc_l[128 * 128];   // 32 KB
  __shared__ float br_l[128];
  __shared__ float bg_l[128];
  __shared__ float v_l[128];

  const int t = threadIdx.x;
  for (int oi = t; oi < 2048; oi += 512) {
    int j = oi >> 4, o = oi & 15;
    int d = j * 128 + ((o ^ (j & 15)) << 3);
    *(short8*)&Wr_l[d]  = *(const short8*)&Wr_bf[oi << 3];
    *(short8*)&Wg1_l[d] = *(const short8*)&Wg1_bf[oi << 3];
    *(short8*)&Wc_l[d]  = *(const short8*)&Wc_bf[oi << 3];
  }
  if (t < 128) { br_l[t] = br[t]; bg_l[t] = bg[t]; v_l[t] = vv[t]; }
  __syncthreads();

  const int wid  = t >> 6;
  const int lane = t & 63;
  const int lrow = lane & 15;
  const int lgrp = lane >> 4;
  const int m0 = blockIdx.x * 128 + wid * 16;
  if (m0 >= n) return;

  const int mr = m0 + lrow;
  const bool rowok = mr < n;

  short8 am[4], ar[4];
  #pragma unroll
  for (int ks = 0; ks < 4; ++ks) {
    short8 z = {0, 0, 0, 0, 0, 0, 0, 0};
    am[ks] = z; ar[ks] = z;
    if (rowok) {
      size_t off = (size_t)mr * DD + ks * 32 + lgrp * 8;
      am[ks] = *(const short8*)&mean_bf[off];
      ar[ks] = *(const short8*)&rows16[off];
    }
  }

  // t = mean @ Wr^T + br
  f32x4 tac[8];
  #pragma unroll
  for (int jt = 0; jt < 8; ++jt) {
    float bv = br_l[jt * 16 + lrow];
    f32x4 c = {bv, bv, bv, bv};
    #pragma unroll
    for (int ks = 0; ks < 4; ++ks) {
      int o = ks * 4 + lgrp;
      short8 b = *(short8*)&Wr_l[(jt * 16 + lrow) * 128 + ((o ^ lrow) << 3)];
      c = __builtin_amdgcn_mfma_f32_16x16x32_bf16(am[ks], b, c, 0, 0, 0);
    }
    tac[jt] = c;
  }

  const int rbase = m0 + lgrp * 4;
  int cv4[4];
  #pragma unroll
  for (int r = 0; r < 4; ++r) {
    int rr = rbase + r;
    cv4[r] = (rr < n) ? cnt[rr] : 0;
    if (cv4[r] == 0) {
      #pragma unroll
      for (int jt = 0; jt < 8; ++jt) tac[jt][r] = 0.f;
    }
  }

  // gate + blend + store
  #pragma unroll
  for (int jt = 0; jt < 8; ++jt) {
    int col = jt * 16 + lrow;
    float bgc = bg_l[col];
    float bgv = bgc + v_l[col];
    f32x4 c;
    #pragma unroll
    for (int r = 0; r < 4; ++r) c[r] = (cv4[r] > 0) ? bgv : bgc;
    #pragma unroll
    for (int ks = 0; ks < 4; ++ks) {
      int o = ks * 4 + lgrp;
      short8 b = *(short8*)&Wg1_l[(jt * 16 + lrow) * 128 + ((o ^ lrow) << 3)];
      c = __builtin_amdgcn_mfma_f32_16x16x32_bf16(ar[ks], b, c, 0, 0, 0);
    }
    #pragma unroll
    for (int ks = 0; ks < 4; ++ks) {
      int o = ks * 4 + lgrp;
      short8 b = *(short8*)&Wc_l[(jt * 16 + lrow) * 128 + ((o ^ lrow) << 3)];
      c = __builtin_amdgcn_mfma_f32_16x16x32_bf16(am[ks], b, c, 0, 0, 0);
    }
    #pragma unroll
    for (int r = 0; r < 4; ++r) {
      int rr = rbase + r;
      if (rr < n) {
        float g = 1.f / (1.f + __expf(-c[r]));
        float rowf = b2f(rows16[(size_t)rr * DD + col]);
        out[(size_t)rr * DD + col] = g * rowf + (1.f - g) * tac[jt][r];
      }
    }
  }
}

extern "C" void kernel_launch(void* const* d_in, const int* in_sizes, int n_in,
                              void* d_out, int out_size, void* d_ws, size_t ws_size,
                              hipStream_t stream) {
  const float* A      = (const float*)d_in[0];
  const float* B      = (const float*)d_in[1];
  const float* W_fwd  = (const float*)d_in[2];
  const float* b_fwd  = (const float*)d_in[3];
  const float* W_rev  = (const float*)d_in[4];
  const float* b_rev  = (const float*)d_in[5];
  const float* W_gate = (const float*)d_in[6];
  const float* b_gate = (const float*)d_in[7];
  const int*   src    = (const int*)d_in[8];
  const int*   dst    = (const int*)d_in[9];

  const int n_a = in_sizes[0] / DD;
  const int n_b = in_sizes[1] / DD;
  const int E   = in_sizes[8];
  const int n_total = n_a + n_b;

  const int na_bins = (n_a + 1023) >> 10;
  const int nb_bins = (n_b + 255) >> 8;
  const int nbins   = na_bins + nb_bins;

  float* out = (float*)d_out;

  // workspace layout
  int* cnt      = (int*)d_ws;                        // [n_total]
  int* binraw   = cnt + n_total;                     // [1024]
  int* start    = binraw + 1024;                     // [n_total]
  int* binstart = start + n_total;                   // [1024]
  int* bincur   = binstart + 1024;                   // [1024]
  uint2* binrec = (uint2*)(bincur + 1024);           // [2E]
  int* partner  = (int*)(binrec + 2 * (size_t)E);    // [2E]
  uintptr_t wp = (uintptr_t)(partner + 2 * (size_t)E);
  wp = (wp + 63) & ~(uintptr_t)63;
  unsigned short* wbf = (unsigned short*)wp;         // [81920]: Wrev|Wfwd|Wg1|WcA|WcB
  float* vab = (float*)(wbf + 81920);                // [256] f32: vA | vB
  unsigned short* rows_bf = (unsigned short*)(vab + 256);  // [n_total*128]
  unsigned short* A_bf = rows_bf;
  unsigned short* B_bf = rows_bf + (size_t)n_a * DD;
  unsigned short* mean_bf = rows_bf + (size_t)n_total * DD; // [n_total*128]

  const int nA4  = n_a * (DD / 4);
  const int nt4  = n_total * (DD / 4);

  hipMemsetAsync(binraw, 0, 1024 * sizeof(int), stream);

  rowconv_kernel<<<2048, 256, 0, stream>>>(A, B, rows_bf, nA4, nt4);
  wconv_kernel<<<192, 256, 0, stream>>>(W_rev, W_fwd, W_gate, wbf);
  wc_kernel<<<128, 128, 0, stream>>>(W_gate, W_rev, b_rev, wbf + 49152, vab);
  wc_kernel<<<128, 128, 0, stream>>>(W_gate, W_fwd, b_fwd, wbf + 65536, vab + 128);

  binhist_kernel<<<1024, 256, 0, stream>>>(src, dst, binraw, na_bins, nbins, E);
  binscan_kernel<<<1, 512, 0, stream>>>(binraw, nbins, binstart, bincur);
  binfill_kernel<<<(E + 4095) / 4096, 512, 0, stream>>>(
      src, dst, bincur, binrec, n_a, na_bins, nbins, E);
  binscatter2_kernel<<<nbins, 256, 0, stream>>>(
      binrec, binstart, bincur, partner, start, cnt, n_a, n_total, na_bins);

  aggregate_mean_bf16_kernel<<<(n_total + 3) / 4, 256, 0, stream>>>(
      A_bf, B_bf, partner, start, cnt, mean_bf, n_a, n_total);

  // A range: t = mean_a @ W_rev^T + b_rev ; gate uses Wg1 + WcA (+vA)
  fused_post_kernel<<<(n_a + 127) / 128, 512, 0, stream>>>(
      A_bf, mean_bf, cnt, wbf, wbf + 32768, wbf + 49152,
      b_rev, b_gate, vab, out, n_a);
  // B range: t = mean_b @ W_fwd^T + b_fwd ; gate uses Wg1 + WcB (+vB)
  fused_post_kernel<<<(n_b + 127) / 128, 512, 0, stream>>>(
      B_bf, mean_bf + (size_t)n_a * DD, cnt + n_a, wbf + 16384, wbf + 32768,
      wbf + 65536, b_fwd, b_gate, vab + 128,
      out + (size_t)n_a * DD, n_b);
}

// Round 15
// 332.168 us; speedup vs baseline: 1.8910x; 1.0057x over previous
//
#include <hip/hip_runtime.h>
#include <math.h>

#define DD 128

typedef __attribute__((ext_vector_type(8))) short short8;
typedef __attribute__((ext_vector_type(4))) float f32x4;
typedef __attribute__((ext_vector_type(4))) unsigned short us4;
typedef __attribute__((ext_vector_type(8))) unsigned short us8;

__device__ __forceinline__ unsigned short f2bf(float f) {
  unsigned int u = __builtin_bit_cast(unsigned int, f);
  u = (u + 0x7FFFu + ((u >> 16) & 1u)) >> 16;   // RNE (finite inputs)
  return (unsigned short)u;
}

__device__ __forceinline__ float b2f(unsigned short u) {
  return __builtin_bit_cast(float, ((unsigned)u) << 16);
}

// ---------------------------------------------------------------------------
// Row conversion f32 -> bf16: [A | B] into one table.
// ---------------------------------------------------------------------------
__global__ __launch_bounds__(256) void rowconv_kernel(
    const float* __restrict__ A, const float* __restrict__ B,
    unsigned short* __restrict__ dst, int nA4, int ntot4)
{
  int stride = gridDim.x * 256;
  for (int i = blockIdx.x * 256 + threadIdx.x; i < ntot4; i += stride) {
    float4 v = (i < nA4) ? ((const float4*)A)[i] : ((const float4*)B)[i - nA4];
    us4 o;
    o[0] = f2bf(v.x); o[1] = f2bf(v.y); o[2] = f2bf(v.z); o[3] = f2bf(v.w);
    ((us4*)dst)[i] = o;
  }
}

// ---------------------------------------------------------------------------
// Weight conversion f32 -> bf16: [Wrev | Wfwd | Wg1] (Wg1 = W_gate[:, :128])
// ---------------------------------------------------------------------------
__global__ __launch_bounds__(256) void wconv_kernel(
    const float* __restrict__ Wrev, const float* __restrict__ Wfwd,
    const float* __restrict__ Wgate, unsigned short* __restrict__ dst)
{
  int i = blockIdx.x * 256 + threadIdx.x;   // 49152 total
  float v;
  if (i < 16384) v = Wrev[i];
  else if (i < 32768) v = Wfwd[i - 16384];
  else {
    int j = (i - 32768) >> 7, k = (i - 32768) & 127;
    v = Wgate[j * 256 + k];                 // first half of each gate row
  }
  dst[i] = f2bf(v);
}

// ---------------------------------------------------------------------------
// Wc[j][k] = sum_m Wg2[j][m]*Wr[m][k], v[j] = sum_m Wg2[j][m]*br[m]
// (Wg2 = W_gate[:, 128:]) — f32 accumulate, bf16 output. (proven)
// ---------------------------------------------------------------------------
__global__ __launch_bounds__(128) void wc_kernel(
    const float* __restrict__ Wgate, const float* __restrict__ Wr,
    const float* __restrict__ br, unsigned short* __restrict__ Wc_bf,
    float* __restrict__ v)
{
  int j = blockIdx.x, k = threadIdx.x;
  const float* g2 = Wgate + (size_t)j * 256 + 128;
  float acc = 0.f;
  for (int m = 0; m < 128; ++m) acc += g2[m] * Wr[m * 128 + k];
  Wc_bf[j * 128 + k] = f2bf(acc);
  if (k == 0) {
    float a = 0.f;
    for (int m = 0; m < 128; ++m) a += g2[m] * br[m];
    v[j] = a;
  }
}

// ---------------------------------------------------------------------------
// Bin histogram. A rows: 1024-row bins; B rows: 256-row bins. (proven)
// ---------------------------------------------------------------------------
__global__ __launch_bounds__(256) void binhist_kernel(
    const int* __restrict__ src, const int* __restrict__ dst,
    int* __restrict__ binraw, int na_bins, int nbins, int E)
{
  __shared__ int h[1024];
  int t = threadIdx.x;
  for (int i = t; i < 1024; i += 256) h[i] = 0;
  __syncthreads();
  int stride = gridDim.x * 256;
  for (int e = blockIdx.x * 256 + t; e < E; e += stride) {
    int s = src[e], d = dst[e];
    atomicAdd(&h[s >> 10], 1);
    atomicAdd(&h[na_bins + (d >> 8)], 1);
  }
  __syncthreads();
  for (int i = t; i < nbins; i += 256)
    if (h[i]) atomicAdd(&binraw[i], h[i]);
}

// ---------------------------------------------------------------------------
// Exclusive scan over bin counts (single block, nbins <= 512). (proven)
// ---------------------------------------------------------------------------
__global__ __launch_bounds__(512) void binscan_kernel(
    const int* __restrict__ binraw, int nbins,
    int* __restrict__ binstart, int* __restrict__ bincur)
{
  __shared__ int buf[512];
  int t = threadIdx.x;
  int v = (t < nbins) ? binraw[t] : 0;
  buf[t] = v;
  __syncthreads();
  for (int off = 1; off < 512; off <<= 1) {
    int x = (t >= off) ? buf[t - off] : 0;
    __syncthreads();
    buf[t] += x;
    __syncthreads();
  }
  if (t < nbins) {
    int excl = buf[t] - v;
    binstart[t] = excl;
    bincur[t] = excl;
  }
}

// ---------------------------------------------------------------------------
// binfill — rank 8192 records per-bin in LDS, reserve dense runs, write
// (key=row, val=partner) as per-CU dense runs. (proven)
// ---------------------------------------------------------------------------
__global__ __launch_bounds__(512) void binfill_kernel(
    const int* __restrict__ src, const int* __restrict__ dst,
    int* __restrict__ bincur, uint2* __restrict__ binrec,
    int n_a, int na_bins, int nbins, int E)
{
  __shared__ int lcnt[1024];
  __shared__ int goff[1024];
  const int t = threadIdx.x;
  const int base = blockIdx.x * 4096;
  for (int i = t; i < 1024; i += 512) lcnt[i] = 0;
  __syncthreads();

  int bins[16], ranks[16];
  unsigned keys[16], vals[16];
  #pragma unroll
  for (int j = 0; j < 8; ++j) {
    int e = base + j * 512 + t;
    int i0 = 2 * j, i1 = 2 * j + 1;
    if (e < E) {
      int s = src[e], d = dst[e];
      bins[i0] = s >> 10;               keys[i0] = (unsigned)s;       vals[i0] = (unsigned)d;
      bins[i1] = na_bins + (d >> 8);    keys[i1] = (unsigned)(n_a + d); vals[i1] = (unsigned)s;
      ranks[i0] = atomicAdd(&lcnt[bins[i0]], 1);
      ranks[i1] = atomicAdd(&lcnt[bins[i1]], 1);
    } else {
      bins[i0] = -1; bins[i1] = -1;
      ranks[i0] = 0;  ranks[i1] = 0;
      keys[i0] = 0;   keys[i1] = 0;
      vals[i0] = 0;   vals[i1] = 0;
    }
  }
  __syncthreads();
  for (int b = t; b < nbins; b += 512)
    if (lcnt[b]) goff[b] = atomicAdd(&bincur[b], lcnt[b]);
  __syncthreads();
  #pragma unroll
  for (int i = 0; i < 16; ++i) {
    if (bins[i] >= 0) {
      int p = goff[bins[i]] + ranks[i];
      binrec[p] = make_uint2(keys[i], vals[i]);
    }
  }
}

// ---------------------------------------------------------------------------
// binscatter2 — one block per bin: per-bin LDS counting sort producing
// start/cnt + partner list. (round-14-proven)
// ---------------------------------------------------------------------------
__global__ __launch_bounds__(256) void binscatter2_kernel(
    const uint2* __restrict__ binrec, const int* __restrict__ binstart,
    const int* __restrict__ binend, int* __restrict__ partner,
    int* __restrict__ start, int* __restrict__ cnt,
    int n_a, int n_total, int na_bins)
{
  __shared__ int cntL[1024];
  __shared__ int curL[1024];
  __shared__ int sbuf[256];
  const int b = blockIdx.x;
  const int t = threadIdx.x;
  int row0, nrows;
  if (b < na_bins) { row0 = b << 10; nrows = min(1024, n_a - row0); }
  else { row0 = n_a + ((b - na_bins) << 8); nrows = min(256, n_total - row0); }
  const int s0 = binstart[b], e0 = binend[b];

  for (int i = t; i < 1024; i += 256) cntL[i] = 0;
  __syncthreads();
  for (int i = s0 + t; i < e0; i += 256)
    atomicAdd(&cntL[binrec[i].x - (unsigned)row0], 1);
  __syncthreads();
  int l0 = cntL[4 * t], l1 = cntL[4 * t + 1];
  int l2 = cntL[4 * t + 2], l3 = cntL[4 * t + 3];
  int s = l0 + l1 + l2 + l3;
  sbuf[t] = s;
  __syncthreads();
  for (int off = 1; off < 256; off <<= 1) {
    int x = (t >= off) ? sbuf[t - off] : 0;
    __syncthreads();
    sbuf[t] += x;
    __syncthreads();
  }
  int excl = sbuf[t] - s;
  curL[4 * t]     = excl;
  curL[4 * t + 1] = excl + l0;
  curL[4 * t + 2] = excl + l0 + l1;
  curL[4 * t + 3] = excl + l0 + l1 + l2;
  __syncthreads();
  for (int j = t; j < nrows; j += 256) {
    start[row0 + j] = s0 + curL[j];
    cnt[row0 + j] = cntL[j];
  }
  __syncthreads();
  for (int i = s0 + t; i < e0; i += 256) {
    uint2 r = binrec[i];
    int pos = atomicAdd(&curL[r.x - (unsigned)row0], 1);
    partner[s0 + pos] = (int)r.y;
  }
}

// ---------------------------------------------------------------------------
// Aggregate v3: one wave per row; 16 lanes x 16B (us8), 4 quads x 4 batches
// = 16 edges in flight. (round-14-proven)
// ---------------------------------------------------------------------------
__global__ __launch_bounds__(256) void aggregate_mean_bf16_kernel(
    const unsigned short* __restrict__ A_bf,
    const unsigned short* __restrict__ B_bf,
    const int* __restrict__ partner, const int* __restrict__ start,
    const int* __restrict__ cnt, unsigned short* __restrict__ mean_bf,
    int n_a, int n_total)
{
  int wid = (blockIdx.x * 256 + threadIdx.x) >> 6;
  if (wid >= n_total) return;
  int lane = threadIdx.x & 63;
  int q    = lane & 15;
  int quad = lane >> 4;
  int s0 = start[wid], c = cnt[wid];
  const unsigned short* tbl = (wid < n_a) ? B_bf : A_bf;
  float a0 = 0.f, a1 = 0.f, a2 = 0.f, a3 = 0.f;
  float a4 = 0.f, a5 = 0.f, a6 = 0.f, a7 = 0.f;
  int k = 0;
  for (; k + 16 <= c; k += 16) {
    int p0 = partner[s0 + k + 0 + quad];
    int p1 = partner[s0 + k + 4 + quad];
    int p2 = partner[s0 + k + 8 + quad];
    int p3 = partner[s0 + k + 12 + quad];
    us8 v0 = *(const us8*)(tbl + (size_t)p0 * DD + 8 * q);
    us8 v1 = *(const us8*)(tbl + (size_t)p1 * DD + 8 * q);
    us8 v2 = *(const us8*)(tbl + (size_t)p2 * DD + 8 * q);
    us8 v3 = *(const us8*)(tbl + (size_t)p3 * DD + 8 * q);
    a0 += b2f(v0[0]) + b2f(v1[0]) + b2f(v2[0]) + b2f(v3[0]);
    a1 += b2f(v0[1]) + b2f(v1[1]) + b2f(v2[1]) + b2f(v3[1]);
    a2 += b2f(v0[2]) + b2f(v1[2]) + b2f(v2[2]) + b2f(v3[2]);
    a3 += b2f(v0[3]) + b2f(v1[3]) + b2f(v2[3]) + b2f(v3[3]);
    a4 += b2f(v0[4]) + b2f(v1[4]) + b2f(v2[4]) + b2f(v3[4]);
    a5 += b2f(v0[5]) + b2f(v1[5]) + b2f(v2[5]) + b2f(v3[5]);
    a6 += b2f(v0[6]) + b2f(v1[6]) + b2f(v2[6]) + b2f(v3[6]);
    a7 += b2f(v0[7]) + b2f(v1[7]) + b2f(v2[7]) + b2f(v3[7]);
  }
  for (; k < c; k += 4) {
    int i = k + quad;
    if (i < c) {
      int p = partner[s0 + i];
      us8 v = *(const us8*)(tbl + (size_t)p * DD + 8 * q);
      a0 += b2f(v[0]); a1 += b2f(v[1]); a2 += b2f(v[2]); a3 += b2f(v[3]);
      a4 += b2f(v[4]); a5 += b2f(v[5]); a6 += b2f(v[6]); a7 += b2f(v[7]);
    }
  }
  a0 += __shfl_xor(a0, 16); a0 += __shfl_xor(a0, 32);
  a1 += __shfl_xor(a1, 16); a1 += __shfl_xor(a1, 32);
  a2 += __shfl_xor(a2, 16); a2 += __shfl_xor(a2, 32);
  a3 += __shfl_xor(a3, 16); a3 += __shfl_xor(a3, 32);
  a4 += __shfl_xor(a4, 16); a4 += __shfl_xor(a4, 32);
  a5 += __shfl_xor(a5, 16); a5 += __shfl_xor(a5, 32);
  a6 += __shfl_xor(a6, 16); a6 += __shfl_xor(a6, 32);
  a7 += __shfl_xor(a7, 16); a7 += __shfl_xor(a7, 32);
  if (lane < 16) {
    float inv = (c > 0) ? (1.f / (float)c) : 0.f;
    us8 o;
    o[0] = f2bf(a0 * inv); o[1] = f2bf(a1 * inv);
    o[2] = f2bf(a2 * inv); o[3] = f2bf(a3 * inv);
    o[4] = f2bf(a4 * inv); o[5] = f2bf(a5 * inv);
    o[6] = f2bf(a6 * inv); o[7] = f2bf(a7 * inv);
    *(us8*)&mean_bf[(size_t)wid * DD + 8 * q] = o;
  }
}

// ---------------------------------------------------------------------------
// Fused post v4 (MFMA) — round-14-proven body; changes: (1) merged A+B launch
// via round-12-proven block->range mapping (non-persistent); (2) Wc read from
// GLOBAL (round-5-proven pattern, 32KB L2-resident) so LDS = 64KB + biases ->
// 2 blocks/CU (4 waves/SIMD) instead of 1 (2 waves/SIMD).
//   t = (cnt>0) ? mean @ Wr^T + br : 0
//   u = row @ Wg1^T + mean @ Wc^T + (cnt>0 ? bg+v : bg)
//   out = sigmoid(u)*row + (1-sigmoid(u))*t
// ---------------------------------------------------------------------------
__global__ __launch_bounds__(512, 4) void fused_post_kernel(
    const unsigned short* __restrict__ rows_bf,  // [n_total][128] bf16
    const unsigned short* __restrict__ mean_bf,  // [n_total][128] bf16
    const int* __restrict__ cnt,                 // [n_total]
    const unsigned short* __restrict__ wbf,      // [Wrev|Wfwd|Wg1|WcA|WcB]
    const float* __restrict__ b_rev, const float* __restrict__ b_fwd,
    const float* __restrict__ bg, const float* __restrict__ vab,
    float* __restrict__ out, int n_a, int n_b, int gA)
{
  __shared__ unsigned short Wr_l[128 * 128];   // 32 KB
  __shared__ unsigned short Wg1_l[128 * 128];  // 32 KB
  __shared__ float br_l[128];
  __shared__ float bg_l[128];
  __shared__ float v_l[128];

  const int t = threadIdx.x;
  const bool isB = (int)blockIdx.x >= gA;
  const int bid = isB ? ((int)blockIdx.x - gA) : (int)blockIdx.x;
  const int n   = isB ? n_b : n_a;
  const size_t roff = isB ? (size_t)n_a * DD : 0;
  const unsigned short* rowsp = rows_bf + roff;
  const unsigned short* meanp = mean_bf + roff;
  const int* cntp = cnt + (isB ? n_a : 0);
  float* outp = out + roff;
  const unsigned short* Wr_g  = wbf + (isB ? 16384 : 0);
  const unsigned short* Wg1_g = wbf + 32768;
  const unsigned short* Wc_g  = wbf + 49152 + (isB ? 16384 : 0);
  const float* brp = isB ? b_fwd : b_rev;
  const float* vp  = vab + (isB ? 128 : 0);

  // stage Wr + Wg1 (2048 16B-octets each), proven octet-XOR swizzle
  for (int oi = t; oi < 2048; oi += 512) {
    int j = oi >> 4, o = oi & 15;
    int d = j * 128 + ((o ^ (j & 15)) << 3);
    *(short8*)&Wr_l[d]  = *(const short8*)&Wr_g[oi << 3];
    *(short8*)&Wg1_l[d] = *(const short8*)&Wg1_g[oi << 3];
  }
  if (t < 128) { br_l[t] = brp[t]; bg_l[t] = bg[t]; v_l[t] = vp[t]; }
  __syncthreads();

  const int wid  = t >> 6;
  const int lane = t & 63;
  const int lrow = lane & 15;   // A/B fragment: row/col index
  const int lgrp = lane >> 4;   // k-octet group
  const int m0 = bid * 128 + wid * 16;
  if (m0 >= n) return;

  const int mr = m0 + lrow;
  const bool rowok = mr < n;

  // A-fragments of mean and row: direct 16B global bf16 loads (proven)
  short8 am[4], ar[4];
  #pragma unroll
  for (int ks = 0; ks < 4; ++ks) {
    short8 z = {0, 0, 0, 0, 0, 0, 0, 0};
    am[ks] = z; ar[ks] = z;
    if (rowok) {
      size_t off = (size_t)mr * DD + ks * 32 + lgrp * 8;
      am[ks] = *(const short8*)&meanp[off];
      ar[ks] = *(const short8*)&rowsp[off];
    }
  }

  // t = mean @ Wr^T + br   (Wr from LDS)
  f32x4 tac[8];
  #pragma unroll
  for (int jt = 0; jt < 8; ++jt) {
    float bv = br_l[jt * 16 + lrow];
    f32x4 c = {bv, bv, bv, bv};
    #pragma unroll
    for (int ks = 0; ks < 4; ++ks) {
      int o = ks * 4 + lgrp;
      short8 b = *(short8*)&Wr_l[(jt * 16 + lrow) * 128 + ((o ^ lrow) << 3)];
      c = __builtin_amdgcn_mfma_f32_16x16x32_bf16(am[ks], b, c, 0, 0, 0);
    }
    tac[jt] = c;
  }

  const int rbase = m0 + lgrp * 4;
  int cv4[4];
  #pragma unroll
  for (int r = 0; r < 4; ++r) {
    int rr = rbase + r;
    cv4[r] = (rr < n) ? cntp[rr] : 0;
    if (cv4[r] == 0) {
      #pragma unroll
      for (int jt = 0; jt < 8; ++jt) tac[jt][r] = 0.f;
    }
  }

  // gate: u = row @ Wg1^T (LDS) + mean @ Wc^T (GLOBAL, L2) + bias; blend+store
  #pragma unroll
  for (int jt = 0; jt < 8; ++jt) {
    int col = jt * 16 + lrow;
    float bgc = bg_l[col];
    float bgv = bgc + v_l[col];
    f32x4 c;
    #pragma unroll
    for (int r = 0; r < 4; ++r) c[r] = (cv4[r] > 0) ? bgv : bgc;
    #pragma unroll
    for (int ks = 0; ks < 4; ++ks) {
      int o = ks * 4 + lgrp;
      short8 b = *(short8*)&Wg1_l[(jt * 16 + lrow) * 128 + ((o ^ lrow) << 3)];
      c = __builtin_amdgcn_mfma_f32_16x16x32_bf16(ar[ks], b, c, 0, 0, 0);
    }
    #pragma unroll
    for (int ks = 0; ks < 4; ++ks) {
      short8 b = *(const short8*)&Wc_g[(size_t)(jt * 16 + lrow) * 128 +
                                       (ks * 4 + lgrp) * 8];
      c = __builtin_amdgcn_mfma_f32_16x16x32_bf16(am[ks], b, c, 0, 0, 0);
    }
    #pragma unroll
    for (int r = 0; r < 4; ++r) {
      int rr = rbase + r;
      if (rr < n) {
        float g = 1.f / (1.f + __expf(-c[r]));
        float rowf = b2f(rowsp[(size_t)rr * DD + col]);
        outp[(size_t)rr * DD + col] = g * rowf + (1.f - g) * tac[jt][r];
      }
    }
  }
}

extern "C" void kernel_launch(void* const* d_in, const int* in_sizes, int n_in,
                              void* d_out, int out_size, void* d_ws, size_t ws_size,
                              hipStream_t stream) {
  const float* A      = (const float*)d_in[0];
  const float* B      = (const float*)d_in[1];
  const float* W_fwd  = (const float*)d_in[2];
  const float* b_fwd  = (const float*)d_in[3];
  const float* W_rev  = (const float*)d_in[4];
  const float* b_rev  = (const float*)d_in[5];
  const float* W_gate = (const float*)d_in[6];
  const float* b_gate = (const float*)d_in[7];
  const int*   src    = (const int*)d_in[8];
  const int*   dst    = (const int*)d_in[9];

  const int n_a = in_sizes[0] / DD;
  const int n_b = in_sizes[1] / DD;
  const int E   = in_sizes[8];
  const int n_total = n_a + n_b;

  const int na_bins = (n_a + 1023) >> 10;
  const int nb_bins = (n_b + 255) >> 8;
  const int nbins   = na_bins + nb_bins;

  float* out = (float*)d_out;

  // workspace layout
  int* cnt      = (int*)d_ws;                        // [n_total]
  int* binraw   = cnt + n_total;                     // [1024]
  int* start    = binraw + 1024;                     // [n_total]
  int* binstart = start + n_total;                   // [1024]
  int* bincur   = binstart + 1024;                   // [1024]
  uint2* binrec = (uint2*)(bincur + 1024);           // [2E]
  int* partner  = (int*)(binrec + 2 * (size_t)E);    // [2E]
  uintptr_t wp = (uintptr_t)(partner + 2 * (size_t)E);
  wp = (wp + 63) & ~(uintptr_t)63;
  unsigned short* wbf = (unsigned short*)wp;         // [81920]: Wrev|Wfwd|Wg1|WcA|WcB
  float* vab = (float*)(wbf + 81920);                // [256] f32: vA | vB
  unsigned short* rows_bf = (unsigned short*)(vab + 256);  // [n_total*128]
  unsigned short* A_bf = rows_bf;
  unsigned short* B_bf = rows_bf + (size_t)n_a * DD;
  unsigned short* mean_bf = rows_bf + (size_t)n_total * DD; // [n_total*128]

  const int nA4  = n_a * (DD / 4);
  const int nt4  = n_total * (DD / 4);

  hipMemsetAsync(binraw, 0, 1024 * sizeof(int), stream);

  rowconv_kernel<<<2048, 256, 0, stream>>>(A, B, rows_bf, nA4, nt4);
  wconv_kernel<<<192, 256, 0, stream>>>(W_rev, W_fwd, W_gate, wbf);
  wc_kernel<<<128, 128, 0, stream>>>(W_gate, W_rev, b_rev, wbf + 49152, vab);
  wc_kernel<<<128, 128, 0, stream>>>(W_gate, W_fwd, b_fwd, wbf + 65536, vab + 128);

  binhist_kernel<<<1024, 256, 0, stream>>>(src, dst, binraw, na_bins, nbins, E);
  binscan_kernel<<<1, 512, 0, stream>>>(binraw, nbins, binstart, bincur);
  binfill_kernel<<<(E + 4095) / 4096, 512, 0, stream>>>(
      src, dst, bincur, binrec, n_a, na_bins, nbins, E);
  binscatter2_kernel<<<nbins, 256, 0, stream>>>(
      binrec, binstart, bincur, partner, start, cnt, n_a, n_total, na_bins);

  aggregate_mean_bf16_kernel<<<(n_total + 3) / 4, 256, 0, stream>>>(
      A_bf, B_bf, partner, start, cnt, mean_bf, n_a, n_total);

  // merged post kernel: blocks [0,gA) -> A range, [gA,gA+gB) -> B range
  const int gA = (n_a + 127) / 128;
  const int gB = (n_b + 127) / 128;
  fused_post_kernel<<<gA + gB, 512, 0, stream>>>(
      rows_bf, mean_bf, cnt, wbf, b_rev, b_fwd, b_gate, vab,
      out, n_a, n_b, gA);
}

// Round 16
// 327.468 us; speedup vs baseline: 1.9181x; 1.0144x over previous
//
#include <hip/hip_runtime.h>
#include <math.h>

#define DD 128

typedef __attribute__((ext_vector_type(8))) short short8;
typedef __attribute__((ext_vector_type(4))) float f32x4;
typedef __attribute__((ext_vector_type(4))) unsigned short us4;
typedef __attribute__((ext_vector_type(8))) unsigned short us8;

__device__ __forceinline__ unsigned short f2bf(float f) {
  unsigned int u = __builtin_bit_cast(unsigned int, f);
  u = (u + 0x7FFFu + ((u >> 16) & 1u)) >> 16;   // RNE (finite inputs)
  return (unsigned short)u;
}

__device__ __forceinline__ float b2f(unsigned short u) {
  return __builtin_bit_cast(float, ((unsigned)u) << 16);
}

// ---------------------------------------------------------------------------
// Row conversion f32 -> bf16: [A | B] into one table.
// ---------------------------------------------------------------------------
__global__ __launch_bounds__(256) void rowconv_kernel(
    const float* __restrict__ A, const float* __restrict__ B,
    unsigned short* __restrict__ dst, int nA4, int ntot4)
{
  int stride = gridDim.x * 256;
  for (int i = blockIdx.x * 256 + threadIdx.x; i < ntot4; i += stride) {
    float4 v = (i < nA4) ? ((const float4*)A)[i] : ((const float4*)B)[i - nA4];
    us4 o;
    o[0] = f2bf(v.x); o[1] = f2bf(v.y); o[2] = f2bf(v.z); o[3] = f2bf(v.w);
    ((us4*)dst)[i] = o;
  }
}

// ---------------------------------------------------------------------------
// Weight conversion f32 -> bf16: [Wrev | Wfwd | Wg1] (Wg1 = W_gate[:, :128])
// ---------------------------------------------------------------------------
__global__ __launch_bounds__(256) void wconv_kernel(
    const float* __restrict__ Wrev, const float* __restrict__ Wfwd,
    const float* __restrict__ Wgate, unsigned short* __restrict__ dst)
{
  int i = blockIdx.x * 256 + threadIdx.x;   // 49152 total
  float v;
  if (i < 16384) v = Wrev[i];
  else if (i < 32768) v = Wfwd[i - 16384];
  else {
    int j = (i - 32768) >> 7, k = (i - 32768) & 127;
    v = Wgate[j * 256 + k];                 // first half of each gate row
  }
  dst[i] = f2bf(v);
}

// ---------------------------------------------------------------------------
// Wc[j][k] = sum_m Wg2[j][m]*Wr[m][k], v[j] = sum_m Wg2[j][m]*br[m]
// (Wg2 = W_gate[:, 128:]) — f32 accumulate, bf16 output. (proven)
// ---------------------------------------------------------------------------
__global__ __launch_bounds__(128) void wc_kernel(
    const float* __restrict__ Wgate, const float* __restrict__ Wr,
    const float* __restrict__ br, unsigned short* __restrict__ Wc_bf,
    float* __restrict__ v)
{
  int j = blockIdx.x, k = threadIdx.x;
  const float* g2 = Wgate + (size_t)j * 256 + 128;
  float acc = 0.f;
  for (int m = 0; m < 128; ++m) acc += g2[m] * Wr[m * 128 + k];
  Wc_bf[j * 128 + k] = f2bf(acc);
  if (k == 0) {
    float a = 0.f;
    for (int m = 0; m < 128; ++m) a += g2[m] * br[m];
    v[j] = a;
  }
}

// ---------------------------------------------------------------------------
// Bin histogram. A rows: 1024-row bins; B rows: 256-row bins. (proven)
// ---------------------------------------------------------------------------
__global__ __launch_bounds__(256) void binhist_kernel(
    const int* __restrict__ src, const int* __restrict__ dst,
    int* __restrict__ binraw, int na_bins, int nbins, int E)
{
  __shared__ int h[1024];
  int t = threadIdx.x;
  for (int i = t; i < 1024; i += 256) h[i] = 0;
  __syncthreads();
  int stride = gridDim.x * 256;
  for (int e = blockIdx.x * 256 + t; e < E; e += stride) {
    int s = src[e], d = dst[e];
    atomicAdd(&h[s >> 10], 1);
    atomicAdd(&h[na_bins + (d >> 8)], 1);
  }
  __syncthreads();
  for (int i = t; i < nbins; i += 256)
    if (h[i]) atomicAdd(&binraw[i], h[i]);
}

// ---------------------------------------------------------------------------
// Exclusive scan over bin counts (single block, nbins <= 512). (proven)
// ---------------------------------------------------------------------------
__global__ __launch_bounds__(512) void binscan_kernel(
    const int* __restrict__ binraw, int nbins,
    int* __restrict__ binstart, int* __restrict__ bincur)
{
  __shared__ int buf[512];
  int t = threadIdx.x;
  int v = (t < nbins) ? binraw[t] : 0;
  buf[t] = v;
  __syncthreads();
  for (int off = 1; off < 512; off <<= 1) {
    int x = (t >= off) ? buf[t - off] : 0;
    __syncthreads();
    buf[t] += x;
    __syncthreads();
  }
  if (t < nbins) {
    int excl = buf[t] - v;
    binstart[t] = excl;
    bincur[t] = excl;
  }
}

// ---------------------------------------------------------------------------
// binfill — rank 8192 records per-bin in LDS, reserve dense runs, write
// (key=row, val=partner) as per-CU dense runs. (proven)
// ---------------------------------------------------------------------------
__global__ __launch_bounds__(512) void binfill_kernel(
    const int* __restrict__ src, const int* __restrict__ dst,
    int* __restrict__ bincur, uint2* __restrict__ binrec,
    int n_a, int na_bins, int nbins, int E)
{
  __shared__ int lcnt[1024];
  __shared__ int goff[1024];
  const int t = threadIdx.x;
  const int base = blockIdx.x * 4096;
  for (int i = t; i < 1024; i += 512) lcnt[i] = 0;
  __syncthreads();

  int bins[16], ranks[16];
  unsigned keys[16], vals[16];
  #pragma unroll
  for (int j = 0; j < 8; ++j) {
    int e = base + j * 512 + t;
    int i0 = 2 * j, i1 = 2 * j + 1;
    if (e < E) {
      int s = src[e], d = dst[e];
      bins[i0] = s >> 10;               keys[i0] = (unsigned)s;       vals[i0] = (unsigned)d;
      bins[i1] = na_bins + (d >> 8);    keys[i1] = (unsigned)(n_a + d); vals[i1] = (unsigned)s;
      ranks[i0] = atomicAdd(&lcnt[bins[i0]], 1);
      ranks[i1] = atomicAdd(&lcnt[bins[i1]], 1);
    } else {
      bins[i0] = -1; bins[i1] = -1;
      ranks[i0] = 0;  ranks[i1] = 0;
      keys[i0] = 0;   keys[i1] = 0;
      vals[i0] = 0;   vals[i1] = 0;
    }
  }
  __syncthreads();
  for (int b = t; b < nbins; b += 512)
    if (lcnt[b]) goff[b] = atomicAdd(&bincur[b], lcnt[b]);
  __syncthreads();
  #pragma unroll
  for (int i = 0; i < 16; ++i) {
    if (bins[i] >= 0) {
      int p = goff[bins[i]] + ranks[i];
      binrec[p] = make_uint2(keys[i], vals[i]);
    }
  }
}

// ---------------------------------------------------------------------------
// binscatter2 — one block per bin: per-bin LDS counting sort producing
// start/cnt + partner list. (round-14-proven)
// ---------------------------------------------------------------------------
__global__ __launch_bounds__(256) void binscatter2_kernel(
    const uint2* __restrict__ binrec, const int* __restrict__ binstart,
    const int* __restrict__ binend, int* __restrict__ partner,
    int* __restrict__ start, int* __restrict__ cnt,
    int n_a, int n_total, int na_bins)
{
  __shared__ int cntL[1024];
  __shared__ int curL[1024];
  __shared__ int sbuf[256];
  const int b = blockIdx.x;
  const int t = threadIdx.x;
  int row0, nrows;
  if (b < na_bins) { row0 = b << 10; nrows = min(1024, n_a - row0); }
  else { row0 = n_a + ((b - na_bins) << 8); nrows = min(256, n_total - row0); }
  const int s0 = binstart[b], e0 = binend[b];

  for (int i = t; i < 1024; i += 256) cntL[i] = 0;
  __syncthreads();
  for (int i = s0 + t; i < e0; i += 256)
    atomicAdd(&cntL[binrec[i].x - (unsigned)row0], 1);
  __syncthreads();
  int l0 = cntL[4 * t], l1 = cntL[4 * t + 1];
  int l2 = cntL[4 * t + 2], l3 = cntL[4 * t + 3];
  int s = l0 + l1 + l2 + l3;
  sbuf[t] = s;
  __syncthreads();
  for (int off = 1; off < 256; off <<= 1) {
    int x = (t >= off) ? sbuf[t - off] : 0;
    __syncthreads();
    sbuf[t] += x;
    __syncthreads();
  }
  int excl = sbuf[t] - s;
  curL[4 * t]     = excl;
  curL[4 * t + 1] = excl + l0;
  curL[4 * t + 2] = excl + l0 + l1;
  curL[4 * t + 3] = excl + l0 + l1 + l2;
  __syncthreads();
  for (int j = t; j < nrows; j += 256) {
    start[row0 + j] = s0 + curL[j];
    cnt[row0 + j] = cntL[j];
  }
  __syncthreads();
  for (int i = s0 + t; i < e0; i += 256) {
    uint2 r = binrec[i];
    int pos = atomicAdd(&curL[r.x - (unsigned)row0], 1);
    partner[s0 + pos] = (int)r.y;
  }
}

// ---------------------------------------------------------------------------
// Aggregate v3: one wave per row; 16 lanes x 16B (us8), 4 quads x 4 batches
// = 16 edges in flight. (round-14-proven)
// ---------------------------------------------------------------------------
__global__ __launch_bounds__(256) void aggregate_mean_bf16_kernel(
    const unsigned short* __restrict__ A_bf,
    const unsigned short* __restrict__ B_bf,
    const int* __restrict__ partner, const int* __restrict__ start,
    const int* __restrict__ cnt, unsigned short* __restrict__ mean_bf,
    int n_a, int n_total)
{
  int wid = (blockIdx.x * 256 + threadIdx.x) >> 6;
  if (wid >= n_total) return;
  int lane = threadIdx.x & 63;
  int q    = lane & 15;
  int quad = lane >> 4;
  int s0 = start[wid], c = cnt[wid];
  const unsigned short* tbl = (wid < n_a) ? B_bf : A_bf;
  float a0 = 0.f, a1 = 0.f, a2 = 0.f, a3 = 0.f;
  float a4 = 0.f, a5 = 0.f, a6 = 0.f, a7 = 0.f;
  int k = 0;
  for (; k + 16 <= c; k += 16) {
    int p0 = partner[s0 + k + 0 + quad];
    int p1 = partner[s0 + k + 4 + quad];
    int p2 = partner[s0 + k + 8 + quad];
    int p3 = partner[s0 + k + 12 + quad];
    us8 v0 = *(const us8*)(tbl + (size_t)p0 * DD + 8 * q);
    us8 v1 = *(const us8*)(tbl + (size_t)p1 * DD + 8 * q);
    us8 v2 = *(const us8*)(tbl + (size_t)p2 * DD + 8 * q);
    us8 v3 = *(const us8*)(tbl + (size_t)p3 * DD + 8 * q);
    a0 += b2f(v0[0]) + b2f(v1[0]) + b2f(v2[0]) + b2f(v3[0]);
    a1 += b2f(v0[1]) + b2f(v1[1]) + b2f(v2[1]) + b2f(v3[1]);
    a2 += b2f(v0[2]) + b2f(v1[2]) + b2f(v2[2]) + b2f(v3[2]);
    a3 += b2f(v0[3]) + b2f(v1[3]) + b2f(v2[3]) + b2f(v3[3]);
    a4 += b2f(v0[4]) + b2f(v1[4]) + b2f(v2[4]) + b2f(v3[4]);
    a5 += b2f(v0[5]) + b2f(v1[5]) + b2f(v2[5]) + b2f(v3[5]);
    a6 += b2f(v0[6]) + b2f(v1[6]) + b2f(v2[6]) + b2f(v3[6]);
    a7 += b2f(v0[7]) + b2f(v1[7]) + b2f(v2[7]) + b2f(v3[7]);
  }
  for (; k < c; k += 4) {
    int i = k + quad;
    if (i < c) {
      int p = partner[s0 + i];
      us8 v = *(const us8*)(tbl + (size_t)p * DD + 8 * q);
      a0 += b2f(v[0]); a1 += b2f(v[1]); a2 += b2f(v[2]); a3 += b2f(v[3]);
      a4 += b2f(v[4]); a5 += b2f(v[5]); a6 += b2f(v[6]); a7 += b2f(v[7]);
    }
  }
  a0 += __shfl_xor(a0, 16); a0 += __shfl_xor(a0, 32);
  a1 += __shfl_xor(a1, 16); a1 += __shfl_xor(a1, 32);
  a2 += __shfl_xor(a2, 16); a2 += __shfl_xor(a2, 32);
  a3 += __shfl_xor(a3, 16); a3 += __shfl_xor(a3, 32);
  a4 += __shfl_xor(a4, 16); a4 += __shfl_xor(a4, 32);
  a5 += __shfl_xor(a5, 16); a5 += __shfl_xor(a5, 32);
  a6 += __shfl_xor(a6, 16); a6 += __shfl_xor(a6, 32);
  a7 += __shfl_xor(a7, 16); a7 += __shfl_xor(a7, 32);
  if (lane < 16) {
    float inv = (c > 0) ? (1.f / (float)c) : 0.f;
    us8 o;
    o[0] = f2bf(a0 * inv); o[1] = f2bf(a1 * inv);
    o[2] = f2bf(a2 * inv); o[3] = f2bf(a3 * inv);
    o[4] = f2bf(a4 * inv); o[5] = f2bf(a5 * inv);
    o[6] = f2bf(a6 * inv); o[7] = f2bf(a7 * inv);
    *(us8*)&mean_bf[(size_t)wid * DD + 8 * q] = o;
  }
}

// ---------------------------------------------------------------------------
// Fused post v5 (MFMA) — round-15 memory structure (non-persistent merged,
// 1 tile/block, Wr+Wg1 in LDS @64KB -> 2 blocks/CU, Wc from global) +
// round-12-proven SWAPPED operand order mfma(W_frag, x_frag):
//   D[j][m]: lane owns row m=lrow, 4 consecutive j per reg -> per-lane cv,
//   f32x4 bias, us4 row re-load, float4 stores (vector epilogue).
//   t = (cnt>0) ? mean @ Wr^T + br : 0
//   u = row @ Wg1^T + mean @ Wc^T + (cnt>0 ? bg+v : bg)
//   out = sigmoid(u)*row + (1-sigmoid(u))*t
// ---------------------------------------------------------------------------
__global__ __launch_bounds__(512, 4) void fused_post_kernel(
    const unsigned short* __restrict__ rows_bf,  // [n_total][128] bf16
    const unsigned short* __restrict__ mean_bf,  // [n_total][128] bf16
    const int* __restrict__ cnt,                 // [n_total]
    const unsigned short* __restrict__ wbf,      // [Wrev|Wfwd|Wg1|WcA|WcB]
    const float* __restrict__ b_rev, const float* __restrict__ b_fwd,
    const float* __restrict__ bg, const float* __restrict__ vab,
    float* __restrict__ out, int n_a, int n_b, int gA)
{
  __shared__ unsigned short Wr_l[128 * 128];   // 32 KB
  __shared__ unsigned short Wg1_l[128 * 128];  // 32 KB
  __shared__ __align__(16) float br_l[128];
  __shared__ __align__(16) float bg_l[128];
  __shared__ __align__(16) float bgv_l[128];

  const int t = threadIdx.x;
  const bool isB = (int)blockIdx.x >= gA;
  const int bid = isB ? ((int)blockIdx.x - gA) : (int)blockIdx.x;
  const int n   = isB ? n_b : n_a;
  const size_t roff = isB ? (size_t)n_a * DD : 0;
  const unsigned short* rowsp = rows_bf + roff;
  const unsigned short* meanp = mean_bf + roff;
  const int* cntp = cnt + (isB ? n_a : 0);
  float* outp = out + roff;
  const unsigned short* Wr_g  = wbf + (isB ? 16384 : 0);
  const unsigned short* Wg1_g = wbf + 32768;
  const unsigned short* Wc_g  = wbf + 49152 + (isB ? 16384 : 0);
  const float* brp = isB ? b_fwd : b_rev;
  const float* vp  = vab + (isB ? 128 : 0);

  // stage Wr + Wg1 (2048 16B-octets each), proven octet-XOR swizzle
  for (int oi = t; oi < 2048; oi += 512) {
    int j = oi >> 4, o = oi & 15;
    int d = j * 128 + ((o ^ (j & 15)) << 3);
    *(short8*)&Wr_l[d]  = *(const short8*)&Wr_g[oi << 3];
    *(short8*)&Wg1_l[d] = *(const short8*)&Wg1_g[oi << 3];
  }
  if (t < 128) {
    float b = brp[t], g = bg[t], v = vp[t];
    br_l[t] = b; bg_l[t] = g; bgv_l[t] = g + v;
  }
  __syncthreads();

  const int wid  = t >> 6;
  const int lane = t & 63;
  const int lrow = lane & 15;   // row m owned by this lane
  const int lgrp = lane >> 4;   // k-octet group / j-quad selector
  const int m0 = bid * 128 + wid * 16;
  if (m0 >= n) return;

  const int m = m0 + lrow;
  const bool ok = m < n;
  const int cv = ok ? cntp[m] : 0;

  // x-fragments (B-operand layout == A layout: row m, octet ks*4+lgrp)
  short8 am[4], ar[4];
  #pragma unroll
  for (int ks = 0; ks < 4; ++ks) {
    short8 z = {0, 0, 0, 0, 0, 0, 0, 0};
    am[ks] = z; ar[ks] = z;
    if (ok) {
      size_t off = (size_t)m * DD + ks * 32 + lgrp * 8;
      am[ks] = *(const short8*)&meanp[off];
      ar[ks] = *(const short8*)&rowsp[off];
    }
  }

  #pragma unroll
  for (int jt = 0; jt < 8; ++jt) {
    int j0 = jt * 16 + lgrp * 4;
    // t = mean @ Wr^T + br   (output dims j0..j0+3 for row m)
    f32x4 t4 = *(const f32x4*)&br_l[j0];
    #pragma unroll
    for (int ks = 0; ks < 4; ++ks) {
      short8 w = *(short8*)&Wr_l[(jt * 16 + lrow) * 128 +
                                 (((ks * 4 + lgrp) ^ lrow) << 3)];
      t4 = __builtin_amdgcn_mfma_f32_16x16x32_bf16(w, am[ks], t4, 0, 0, 0);
    }
    if (cv == 0) t4 = (f32x4){0.f, 0.f, 0.f, 0.f};

    // u = row @ Wg1^T (LDS) + mean @ Wc^T (GLOBAL, L2) + (cv ? bg+v : bg)
    f32x4 u4 = (cv > 0) ? *(const f32x4*)&bgv_l[j0]
                        : *(const f32x4*)&bg_l[j0];
    #pragma unroll
    for (int ks = 0; ks < 4; ++ks) {
      short8 w = *(short8*)&Wg1_l[(jt * 16 + lrow) * 128 +
                                  (((ks * 4 + lgrp) ^ lrow) << 3)];
      u4 = __builtin_amdgcn_mfma_f32_16x16x32_bf16(w, ar[ks], u4, 0, 0, 0);
    }
    #pragma unroll
    for (int ks = 0; ks < 4; ++ks) {
      short8 w = *(const short8*)&Wc_g[(size_t)(jt * 16 + lrow) * 128 +
                                       (ks * 4 + lgrp) * 8];
      u4 = __builtin_amdgcn_mfma_f32_16x16x32_bf16(w, am[ks], u4, 0, 0, 0);
    }

    if (ok) {
      us4 rv = *(const us4*)&rowsp[(size_t)m * DD + j0];
      float4 o;
      float g0 = 1.f / (1.f + __expf(-u4[0]));
      float g1 = 1.f / (1.f + __expf(-u4[1]));
      float g2 = 1.f / (1.f + __expf(-u4[2]));
      float g3 = 1.f / (1.f + __expf(-u4[3]));
      o.x = g0 * b2f(rv[0]) + (1.f - g0) * t4[0];
      o.y = g1 * b2f(rv[1]) + (1.f - g1) * t4[1];
      o.z = g2 * b2f(rv[2]) + (1.f - g2) * t4[2];
      o.w = g3 * b2f(rv[3]) + (1.f - g3) * t4[3];
      *(float4*)&outp[(size_t)m * DD + j0] = o;
    }
  }
}

extern "C" void kernel_launch(void* const* d_in, const int* in_sizes, int n_in,
                              void* d_out, int out_size, void* d_ws, size_t ws_size,
                              hipStream_t stream) {
  const float* A      = (const float*)d_in[0];
  const float* B      = (const float*)d_in[1];
  const float* W_fwd  = (const float*)d_in[2];
  const float* b_fwd  = (const float*)d_in[3];
  const float* W_rev  = (const float*)d_in[4];
  const float* b_rev  = (const float*)d_in[5];
  const float* W_gate = (const float*)d_in[6];
  const float* b_gate = (const float*)d_in[7];
  const int*   src    = (const int*)d_in[8];
  const int*   dst    = (const int*)d_in[9];

  const int n_a = in_sizes[0] / DD;
  const int n_b = in_sizes[1] / DD;
  const int E   = in_sizes[8];
  const int n_total = n_a + n_b;

  const int na_bins = (n_a + 1023) >> 10;
  const int nb_bins = (n_b + 255) >> 8;
  const int nbins   = na_bins + nb_bins;

  float* out = (float*)d_out;

  // workspace layout
  int* cnt      = (int*)d_ws;                        // [n_total]
  int* binraw   = cnt + n_total;                     // [1024]
  int* start    = binraw + 1024;                     // [n_total]
  int* binstart = start + n_total;                   // [1024]
  int* bincur   = binstart + 1024;                   // [1024]
  uint2* binrec = (uint2*)(bincur + 1024);           // [2E]
  int* partner  = (int*)(binrec + 2 * (size_t)E);    // [2E]
  uintptr_t wp = (uintptr_t)(partner + 2 * (size_t)E);
  wp = (wp + 63) & ~(uintptr_t)63;
  unsigned short* wbf = (unsigned short*)wp;         // [81920]: Wrev|Wfwd|Wg1|WcA|WcB
  float* vab = (float*)(wbf + 81920);                // [256] f32: vA | vB
  unsigned short* rows_bf = (unsigned short*)(vab + 256);  // [n_total*128]
  unsigned short* A_bf = rows_bf;
  unsigned short* B_bf = rows_bf + (size_t)n_a * DD;
  unsigned short* mean_bf = rows_bf + (size_t)n_total * DD; // [n_total*128]

  const int nA4  = n_a * (DD / 4);
  const int nt4  = n_total * (DD / 4);

  hipMemsetAsync(binraw, 0, 1024 * sizeof(int), stream);

  rowconv_kernel<<<2048, 256, 0, stream>>>(A, B, rows_bf, nA4, nt4);
  wconv_kernel<<<192, 256, 0, stream>>>(W_rev, W_fwd, W_gate, wbf);
  wc_kernel<<<128, 128, 0, stream>>>(W_gate, W_rev, b_rev, wbf + 49152, vab);
  wc_kernel<<<128, 128, 0, stream>>>(W_gate, W_fwd, b_fwd, wbf + 65536, vab + 128);

  binhist_kernel<<<1024, 256, 0, stream>>>(src, dst, binraw, na_bins, nbins, E);
  binscan_kernel<<<1, 512, 0, stream>>>(binraw, nbins, binstart, bincur);
  binfill_kernel<<<(E + 4095) / 4096, 512, 0, stream>>>(
      src, dst, bincur, binrec, n_a, na_bins, nbins, E);
  binscatter2_kernel<<<nbins, 256, 0, stream>>>(
      binrec, binstart, bincur, partner, start, cnt, n_a, n_total, na_bins);

  aggregate_mean_bf16_kernel<<<(n_total + 3) / 4, 256, 0, stream>>>(
      A_bf, B_bf, partner, start, cnt, mean_bf, n_a, n_total);

  // merged post kernel: blocks [0,gA) -> A range, [gA,gA+gB) -> B range
  const int gA = (n_a + 127) / 128;
  const int gB = (n_b + 127) / 128;
  fused_post_kernel<<<gA + gB, 512, 0, stream>>>(
      rows_bf, mean_bf, cnt, wbf, b_rev, b_fwd, b_gate, vab,
      out, n_a, n_b, gA);
}

// Round 17
// 302.323 us; speedup vs baseline: 2.0777x; 1.0832x over previous
//
#include <hip/hip_runtime.h>
#include <math.h>

#define DD 128

typedef __attribute__((ext_vector_type(8))) short short8;
typedef __attribute__((ext_vector_type(4))) float f32x4;
typedef __attribute__((ext_vector_type(4))) unsigned short us4;
typedef __attribute__((ext_vector_type(8))) unsigned short us8;

__device__ __forceinline__ unsigned short f2bf(float f) {
  unsigned int u = __builtin_bit_cast(unsigned int, f);
  u = (u + 0x7FFFu + ((u >> 16) & 1u)) >> 16;   // RNE (finite inputs)
  return (unsigned short)u;
}

__device__ __forceinline__ float b2f(unsigned short u) {
  return __builtin_bit_cast(float, ((unsigned)u) << 16);
}

// ---------------------------------------------------------------------------
// Row conversion f32 -> bf16: [A | B] into one table.
// ---------------------------------------------------------------------------
__global__ __launch_bounds__(256) void rowconv_kernel(
    const float* __restrict__ A, const float* __restrict__ B,
    unsigned short* __restrict__ dst, int nA4, int ntot4)
{
  int stride = gridDim.x * 256;
  for (int i = blockIdx.x * 256 + threadIdx.x; i < ntot4; i += stride) {
    float4 v = (i < nA4) ? ((const float4*)A)[i] : ((const float4*)B)[i - nA4];
    us4 o;
    o[0] = f2bf(v.x); o[1] = f2bf(v.y); o[2] = f2bf(v.z); o[3] = f2bf(v.w);
    ((us4*)dst)[i] = o;
  }
}

// ---------------------------------------------------------------------------
// Weight conversion f32 -> bf16: [Wrev | Wfwd | Wg1] (Wg1 = W_gate[:, :128])
// ---------------------------------------------------------------------------
__global__ __launch_bounds__(256) void wconv_kernel(
    const float* __restrict__ Wrev, const float* __restrict__ Wfwd,
    const float* __restrict__ Wgate, unsigned short* __restrict__ dst)
{
  int i = blockIdx.x * 256 + threadIdx.x;   // 49152 total
  float v;
  if (i < 16384) v = Wrev[i];
  else if (i < 32768) v = Wfwd[i - 16384];
  else {
    int j = (i - 32768) >> 7, k = (i - 32768) & 127;
    v = Wgate[j * 256 + k];                 // first half of each gate row
  }
  dst[i] = f2bf(v);
}

// ---------------------------------------------------------------------------
// Wc[j][k] = sum_m Wg2[j][m]*Wr[m][k], v[j] = sum_m Wg2[j][m]*br[m]
// (Wg2 = W_gate[:, 128:]) — f32 accumulate, bf16 output. (proven)
// ---------------------------------------------------------------------------
__global__ __launch_bounds__(128) void wc_kernel(
    const float* __restrict__ Wgate, const float* __restrict__ Wr,
    const float* __restrict__ br, unsigned short* __restrict__ Wc_bf,
    float* __restrict__ v)
{
  int j = blockIdx.x, k = threadIdx.x;
  const float* g2 = Wgate + (size_t)j * 256 + 128;
  float acc = 0.f;
  for (int m = 0; m < 128; ++m) acc += g2[m] * Wr[m * 128 + k];
  Wc_bf[j * 128 + k] = f2bf(acc);
  if (k == 0) {
    float a = 0.f;
    for (int m = 0; m < 128; ++m) a += g2[m] * br[m];
    v[j] = a;
  }
}

// ---------------------------------------------------------------------------
// Bin histogram. A rows: 1024-row bins; B rows: 256-row bins. (proven)
// ---------------------------------------------------------------------------
__global__ __launch_bounds__(256) void binhist_kernel(
    const int* __restrict__ src, const int* __restrict__ dst,
    int* __restrict__ binraw, int na_bins, int nbins, int E)
{
  __shared__ int h[1024];
  int t = threadIdx.x;
  for (int i = t; i < 1024; i += 256) h[i] = 0;
  __syncthreads();
  int stride = gridDim.x * 256;
  for (int e = blockIdx.x * 256 + t; e < E; e += stride) {
    int s = src[e], d = dst[e];
    atomicAdd(&h[s >> 10], 1);
    atomicAdd(&h[na_bins + (d >> 8)], 1);
  }
  __syncthreads();
  for (int i = t; i < nbins; i += 256)
    if (h[i]) atomicAdd(&binraw[i], h[i]);
}

// ---------------------------------------------------------------------------
// Exclusive scan over bin counts (single block, nbins <= 512). (proven)
// ---------------------------------------------------------------------------
__global__ __launch_bounds__(512) void binscan_kernel(
    const int* __restrict__ binraw, int nbins,
    int* __restrict__ binstart, int* __restrict__ bincur)
{
  __shared__ int buf[512];
  int t = threadIdx.x;
  int v = (t < nbins) ? binraw[t] : 0;
  buf[t] = v;
  __syncthreads();
  for (int off = 1; off < 512; off <<= 1) {
    int x = (t >= off) ? buf[t - off] : 0;
    __syncthreads();
    buf[t] += x;
    __syncthreads();
  }
  if (t < nbins) {
    int excl = buf[t] - v;
    binstart[t] = excl;
    bincur[t] = excl;
  }
}

// ---------------------------------------------------------------------------
// binfill — rank 8192 records per-bin in LDS, reserve dense runs, write
// (key=row, val=partner) as per-CU dense runs. (proven)
// ---------------------------------------------------------------------------
__global__ __launch_bounds__(512) void binfill_kernel(
    const int* __restrict__ src, const int* __restrict__ dst,
    int* __restrict__ bincur, uint2* __restrict__ binrec,
    int n_a, int na_bins, int nbins, int E)
{
  __shared__ int lcnt[1024];
  __shared__ int goff[1024];
  const int t = threadIdx.x;
  const int base = blockIdx.x * 4096;
  for (int i = t; i < 1024; i += 512) lcnt[i] = 0;
  __syncthreads();

  int bins[16], ranks[16];
  unsigned keys[16], vals[16];
  #pragma unroll
  for (int j = 0; j < 8; ++j) {
    int e = base + j * 512 + t;
    int i0 = 2 * j, i1 = 2 * j + 1;
    if (e < E) {
      int s = src[e], d = dst[e];
      bins[i0] = s >> 10;               keys[i0] = (unsigned)s;       vals[i0] = (unsigned)d;
      bins[i1] = na_bins + (d >> 8);    keys[i1] = (unsigned)(n_a + d); vals[i1] = (unsigned)s;
      ranks[i0] = atomicAdd(&lcnt[bins[i0]], 1);
      ranks[i1] = atomicAdd(&lcnt[bins[i1]], 1);
    } else {
      bins[i0] = -1; bins[i1] = -1;
      ranks[i0] = 0;  ranks[i1] = 0;
      keys[i0] = 0;   keys[i1] = 0;
      vals[i0] = 0;   vals[i1] = 0;
    }
  }
  __syncthreads();
  for (int b = t; b < nbins; b += 512)
    if (lcnt[b]) goff[b] = atomicAdd(&bincur[b], lcnt[b]);
  __syncthreads();
  #pragma unroll
  for (int i = 0; i < 16; ++i) {
    if (bins[i] >= 0) {
      int p = goff[bins[i]] + ranks[i];
      binrec[p] = make_uint2(keys[i], vals[i]);
    }
  }
}

// ---------------------------------------------------------------------------
// binscatter2 — one block per bin: per-bin LDS counting sort producing
// start/cnt + partner list. (round-14-proven)
// ---------------------------------------------------------------------------
__global__ __launch_bounds__(256) void binscatter2_kernel(
    const uint2* __restrict__ binrec, const int* __restrict__ binstart,
    const int* __restrict__ binend, int* __restrict__ partner,
    int* __restrict__ start, int* __restrict__ cnt,
    int n_a, int n_total, int na_bins)
{
  __shared__ int cntL[1024];
  __shared__ int curL[1024];
  __shared__ int sbuf[256];
  const int b = blockIdx.x;
  const int t = threadIdx.x;
  int row0, nrows;
  if (b < na_bins) { row0 = b << 10; nrows = min(1024, n_a - row0); }
  else { row0 = n_a + ((b - na_bins) << 8); nrows = min(256, n_total - row0); }
  const int s0 = binstart[b], e0 = binend[b];

  for (int i = t; i < 1024; i += 256) cntL[i] = 0;
  __syncthreads();
  for (int i = s0 + t; i < e0; i += 256)
    atomicAdd(&cntL[binrec[i].x - (unsigned)row0], 1);
  __syncthreads();
  int l0 = cntL[4 * t], l1 = cntL[4 * t + 1];
  int l2 = cntL[4 * t + 2], l3 = cntL[4 * t + 3];
  int s = l0 + l1 + l2 + l3;
  sbuf[t] = s;
  __syncthreads();
  for (int off = 1; off < 256; off <<= 1) {
    int x = (t >= off) ? sbuf[t - off] : 0;
    __syncthreads();
    sbuf[t] += x;
    __syncthreads();
  }
  int excl = sbuf[t] - s;
  curL[4 * t]     = excl;
  curL[4 * t + 1] = excl + l0;
  curL[4 * t + 2] = excl + l0 + l1;
  curL[4 * t + 3] = excl + l0 + l1 + l2;
  __syncthreads();
  for (int j = t; j < nrows; j += 256) {
    start[row0 + j] = s0 + curL[j];
    cnt[row0 + j] = cntL[j];
  }
  __syncthreads();
  for (int i = s0 + t; i < e0; i += 256) {
    uint2 r = binrec[i];
    int pos = atomicAdd(&curL[r.x - (unsigned)row0], 1);
    partner[s0 + pos] = (int)r.y;
  }
}

// ---------------------------------------------------------------------------
// Aggregate v3: one wave per row; 16 lanes x 16B (us8), 4 quads x 4 batches
// = 16 edges in flight. (round-14-proven)
// ---------------------------------------------------------------------------
__global__ __launch_bounds__(256) void aggregate_mean_bf16_kernel(
    const unsigned short* __restrict__ A_bf,
    const unsigned short* __restrict__ B_bf,
    const int* __restrict__ partner, const int* __restrict__ start,
    const int* __restrict__ cnt, unsigned short* __restrict__ mean_bf,
    int n_a, int n_total)
{
  int wid = (blockIdx.x * 256 + threadIdx.x) >> 6;
  if (wid >= n_total) return;
  int lane = threadIdx.x & 63;
  int q    = lane & 15;
  int quad = lane >> 4;
  int s0 = start[wid], c = cnt[wid];
  const unsigned short* tbl = (wid < n_a) ? B_bf : A_bf;
  float a0 = 0.f, a1 = 0.f, a2 = 0.f, a3 = 0.f;
  float a4 = 0.f, a5 = 0.f, a6 = 0.f, a7 = 0.f;
  int k = 0;
  for (; k + 16 <= c; k += 16) {
    int p0 = partner[s0 + k + 0 + quad];
    int p1 = partner[s0 + k + 4 + quad];
    int p2 = partner[s0 + k + 8 + quad];
    int p3 = partner[s0 + k + 12 + quad];
    us8 v0 = *(const us8*)(tbl + (size_t)p0 * DD + 8 * q);
    us8 v1 = *(const us8*)(tbl + (size_t)p1 * DD + 8 * q);
    us8 v2 = *(const us8*)(tbl + (size_t)p2 * DD + 8 * q);
    us8 v3 = *(const us8*)(tbl + (size_t)p3 * DD + 8 * q);
    a0 += b2f(v0[0]) + b2f(v1[0]) + b2f(v2[0]) + b2f(v3[0]);
    a1 += b2f(v0[1]) + b2f(v1[1]) + b2f(v2[1]) + b2f(v3[1]);
    a2 += b2f(v0[2]) + b2f(v1[2]) + b2f(v2[2]) + b2f(v3[2]);
    a3 += b2f(v0[3]) + b2f(v1[3]) + b2f(v2[3]) + b2f(v3[3]);
    a4 += b2f(v0[4]) + b2f(v1[4]) + b2f(v2[4]) + b2f(v3[4]);
    a5 += b2f(v0[5]) + b2f(v1[5]) + b2f(v2[5]) + b2f(v3[5]);
    a6 += b2f(v0[6]) + b2f(v1[6]) + b2f(v2[6]) + b2f(v3[6]);
    a7 += b2f(v0[7]) + b2f(v1[7]) + b2f(v2[7]) + b2f(v3[7]);
  }
  for (; k < c; k += 4) {
    int i = k + quad;
    if (i < c) {
      int p = partner[s0 + i];
      us8 v = *(const us8*)(tbl + (size_t)p * DD + 8 * q);
      a0 += b2f(v[0]); a1 += b2f(v[1]); a2 += b2f(v[2]); a3 += b2f(v[3]);
      a4 += b2f(v[4]); a5 += b2f(v[5]); a6 += b2f(v[6]); a7 += b2f(v[7]);
    }
  }
  a0 += __shfl_xor(a0, 16); a0 += __shfl_xor(a0, 32);
  a1 += __shfl_xor(a1, 16); a1 += __shfl_xor(a1, 32);
  a2 += __shfl_xor(a2, 16); a2 += __shfl_xor(a2, 32);
  a3 += __shfl_xor(a3, 16); a3 += __shfl_xor(a3, 32);
  a4 += __shfl_xor(a4, 16); a4 += __shfl_xor(a4, 32);
  a5 += __shfl_xor(a5, 16); a5 += __shfl_xor(a5, 32);
  a6 += __shfl_xor(a6, 16); a6 += __shfl_xor(a6, 32);
  a7 += __shfl_xor(a7, 16); a7 += __shfl_xor(a7, 32);
  if (lane < 16) {
    float inv = (c > 0) ? (1.f / (float)c) : 0.f;
    us8 o;
    o[0] = f2bf(a0 * inv); o[1] = f2bf(a1 * inv);
    o[2] = f2bf(a2 * inv); o[3] = f2bf(a3 * inv);
    o[4] = f2bf(a4 * inv); o[5] = f2bf(a5 * inv);
    o[6] = f2bf(a6 * inv); o[7] = f2bf(a7 * inv);
    *(us8*)&mean_bf[(size_t)wid * DD + 8 * q] = o;
  }
}

// ---------------------------------------------------------------------------
// Fused post v6 (MFMA) — round-16 structure + 2 contiguous tiles per wave:
// each Wr/Wg1 LDS read and each Wc global load feeds TWO independent MFMAs
// (2x ILP, half B-operand traffic per FLOP, 2x staging amortization).
// Swapped operands (round-12-proven): D[j][m], lane owns row m, vector
// epilogue. No LDS writes after staging. 256 rows/block.
//   t = (cnt>0) ? mean @ Wr^T + br : 0
//   u = row @ Wg1^T + mean @ Wc^T + (cnt>0 ? bg+v : bg)
//   out = sigmoid(u)*row + (1-sigmoid(u))*t
// ---------------------------------------------------------------------------
__global__ __launch_bounds__(512, 4) void fused_post_kernel(
    const unsigned short* __restrict__ rows_bf,  // [n_total][128] bf16
    const unsigned short* __restrict__ mean_bf,  // [n_total][128] bf16
    const int* __restrict__ cnt,                 // [n_total]
    const unsigned short* __restrict__ wbf,      // [Wrev|Wfwd|Wg1|WcA|WcB]
    const float* __restrict__ b_rev, const float* __restrict__ b_fwd,
    const float* __restrict__ bg, const float* __restrict__ vab,
    float* __restrict__ out, int n_a, int n_b, int gA)
{
  __shared__ unsigned short Wr_l[128 * 128];   // 32 KB
  __shared__ unsigned short Wg1_l[128 * 128];  // 32 KB
  __shared__ __align__(16) float br_l[128];
  __shared__ __align__(16) float bg_l[128];
  __shared__ __align__(16) float bgv_l[128];

  const int t = threadIdx.x;
  const bool isB = (int)blockIdx.x >= gA;
  const int bid = isB ? ((int)blockIdx.x - gA) : (int)blockIdx.x;
  const int n   = isB ? n_b : n_a;
  const size_t roff = isB ? (size_t)n_a * DD : 0;
  const unsigned short* rowsp = rows_bf + roff;
  const unsigned short* meanp = mean_bf + roff;
  const int* cntp = cnt + (isB ? n_a : 0);
  float* outp = out + roff;
  const unsigned short* Wr_g  = wbf + (isB ? 16384 : 0);
  const unsigned short* Wg1_g = wbf + 32768;
  const unsigned short* Wc_g  = wbf + 49152 + (isB ? 16384 : 0);
  const float* brp = isB ? b_fwd : b_rev;
  const float* vp  = vab + (isB ? 128 : 0);

  // stage Wr + Wg1 (2048 16B-octets each), proven octet-XOR swizzle
  for (int oi = t; oi < 2048; oi += 512) {
    int j = oi >> 4, o = oi & 15;
    int d = j * 128 + ((o ^ (j & 15)) << 3);
    *(short8*)&Wr_l[d]  = *(const short8*)&Wr_g[oi << 3];
    *(short8*)&Wg1_l[d] = *(const short8*)&Wg1_g[oi << 3];
  }
  if (t < 128) {
    float b = brp[t], g = bg[t], v = vp[t];
    br_l[t] = b; bg_l[t] = g; bgv_l[t] = g + v;
  }
  __syncthreads();

  const int wid  = t >> 6;
  const int lane = t & 63;
  const int lrow = lane & 15;   // row within tile owned by this lane
  const int lgrp = lane >> 4;   // k-octet group / j-quad selector
  const int m0 = bid * 256 + wid * 32;
  if (m0 >= n) return;

  const int mA = m0 + lrow;          // tile 0 row
  const int mB = m0 + 16 + lrow;     // tile 1 row
  const bool okA = mA < n, okB = mB < n;
  const int cvA = okA ? cntp[mA] : 0;
  const int cvB = okB ? cntp[mB] : 0;

  // x-fragments for both tiles (B-operand layout: row m, octet ks*4+lgrp)
  short8 amA[4], arA[4], amB[4], arB[4];
  #pragma unroll
  for (int ks = 0; ks < 4; ++ks) {
    short8 z = {0, 0, 0, 0, 0, 0, 0, 0};
    amA[ks] = z; arA[ks] = z; amB[ks] = z; arB[ks] = z;
    size_t ofs = ks * 32 + lgrp * 8;
    if (okA) {
      amA[ks] = *(const short8*)&meanp[(size_t)mA * DD + ofs];
      arA[ks] = *(const short8*)&rowsp[(size_t)mA * DD + ofs];
    }
    if (okB) {
      amB[ks] = *(const short8*)&meanp[(size_t)mB * DD + ofs];
      arB[ks] = *(const short8*)&rowsp[(size_t)mB * DD + ofs];
    }
  }

  #pragma unroll
  for (int jt = 0; jt < 8; ++jt) {
    int j0 = jt * 16 + lgrp * 4;
    // t = mean @ Wr^T + br  — shared Wr read feeds both tiles
    f32x4 br4 = *(const f32x4*)&br_l[j0];
    f32x4 tA = br4, tB = br4;
    #pragma unroll
    for (int ks = 0; ks < 4; ++ks) {
      short8 w = *(short8*)&Wr_l[(jt * 16 + lrow) * 128 +
                                 (((ks * 4 + lgrp) ^ lrow) << 3)];
      tA = __builtin_amdgcn_mfma_f32_16x16x32_bf16(w, amA[ks], tA, 0, 0, 0);
      tB = __builtin_amdgcn_mfma_f32_16x16x32_bf16(w, amB[ks], tB, 0, 0, 0);
    }
    if (cvA == 0) tA = (f32x4){0.f, 0.f, 0.f, 0.f};
    if (cvB == 0) tB = (f32x4){0.f, 0.f, 0.f, 0.f};

    // u = row @ Wg1^T (LDS) + mean @ Wc^T (GLOBAL, L2) + (cv ? bg+v : bg)
    f32x4 uA = (cvA > 0) ? *(const f32x4*)&bgv_l[j0] : *(const f32x4*)&bg_l[j0];
    f32x4 uB = (cvB > 0) ? *(const f32x4*)&bgv_l[j0] : *(const f32x4*)&bg_l[j0];
    #pragma unroll
    for (int ks = 0; ks < 4; ++ks) {
      short8 w = *(short8*)&Wg1_l[(jt * 16 + lrow) * 128 +
                                  (((ks * 4 + lgrp) ^ lrow) << 3)];
      uA = __builtin_amdgcn_mfma_f32_16x16x32_bf16(w, arA[ks], uA, 0, 0, 0);
      uB = __builtin_amdgcn_mfma_f32_16x16x32_bf16(w, arB[ks], uB, 0, 0, 0);
    }
    #pragma unroll
    for (int ks = 0; ks < 4; ++ks) {
      short8 w = *(const short8*)&Wc_g[(size_t)(jt * 16 + lrow) * 128 +
                                       (ks * 4 + lgrp) * 8];
      uA = __builtin_amdgcn_mfma_f32_16x16x32_bf16(w, amA[ks], uA, 0, 0, 0);
      uB = __builtin_amdgcn_mfma_f32_16x16x32_bf16(w, amB[ks], uB, 0, 0, 0);
    }

    if (okA) {
      us4 rv = *(const us4*)&rowsp[(size_t)mA * DD + j0];
      float4 o;
      float g0 = 1.f / (1.f + __expf(-uA[0]));
      float g1 = 1.f / (1.f + __expf(-uA[1]));
      float g2 = 1.f / (1.f + __expf(-uA[2]));
      float g3 = 1.f / (1.f + __expf(-uA[3]));
      o.x = g0 * b2f(rv[0]) + (1.f - g0) * tA[0];
      o.y = g1 * b2f(rv[1]) + (1.f - g1) * tA[1];
      o.z = g2 * b2f(rv[2]) + (1.f - g2) * tA[2];
      o.w = g3 * b2f(rv[3]) + (1.f - g3) * tA[3];
      *(float4*)&outp[(size_t)mA * DD + j0] = o;
    }
    if (okB) {
      us4 rv = *(const us4*)&rowsp[(size_t)mB * DD + j0];
      float4 o;
      float g0 = 1.f / (1.f + __expf(-uB[0]));
      float g1 = 1.f / (1.f + __expf(-uB[1]));
      float g2 = 1.f / (1.f + __expf(-uB[2]));
      float g3 = 1.f / (1.f + __expf(-uB[3]));
      o.x = g0 * b2f(rv[0]) + (1.f - g0) * tB[0];
      o.y = g1 * b2f(rv[1]) + (1.f - g1) * tB[1];
      o.z = g2 * b2f(rv[2]) + (1.f - g2) * tB[2];
      o.w = g3 * b2f(rv[3]) + (1.f - g3) * tB[3];
      *(float4*)&outp[(size_t)mB * DD + j0] = o;
    }
  }
}

extern "C" void kernel_launch(void* const* d_in, const int* in_sizes, int n_in,
                              void* d_out, int out_size, void* d_ws, size_t ws_size,
                              hipStream_t stream) {
  const float* A      = (const float*)d_in[0];
  const float* B      = (const float*)d_in[1];
  const float* W_fwd  = (const float*)d_in[2];
  const float* b_fwd  = (const float*)d_in[3];
  const float* W_rev  = (const float*)d_in[4];
  const float* b_rev  = (const float*)d_in[5];
  const float* W_gate = (const float*)d_in[6];
  const float* b_gate = (const float*)d_in[7];
  const int*   src    = (const int*)d_in[8];
  const int*   dst    = (const int*)d_in[9];

  const int n_a = in_sizes[0] / DD;
  const int n_b = in_sizes[1] / DD;
  const int E   = in_sizes[8];
  const int n_total = n_a + n_b;

  const int na_bins = (n_a + 1023) >> 10;
  const int nb_bins = (n_b + 255) >> 8;
  const int nbins   = na_bins + nb_bins;

  float* out = (float*)d_out;

  // workspace layout
  int* cnt      = (int*)d_ws;                        // [n_total]
  int* binraw   = cnt + n_total;                     // [1024]
  int* start    = binraw + 1024;                     // [n_total]
  int* binstart = start + n_total;                   // [1024]
  int* bincur   = binstart + 1024;                   // [1024]
  uint2* binrec = (uint2*)(bincur + 1024);           // [2E]
  int* partner  = (int*)(binrec + 2 * (size_t)E);    // [2E]
  uintptr_t wp = (uintptr_t)(partner + 2 * (size_t)E);
  wp = (wp + 63) & ~(uintptr_t)63;
  unsigned short* wbf = (unsigned short*)wp;         // [81920]: Wrev|Wfwd|Wg1|WcA|WcB
  float* vab = (float*)(wbf + 81920);                // [256] f32: vA | vB
  unsigned short* rows_bf = (unsigned short*)(vab + 256);  // [n_total*128]
  unsigned short* A_bf = rows_bf;
  unsigned short* B_bf = rows_bf + (size_t)n_a * DD;
  unsigned short* mean_bf = rows_bf + (size_t)n_total * DD; // [n_total*128]

  const int nA4  = n_a * (DD / 4);
  const int nt4  = n_total * (DD / 4);

  hipMemsetAsync(binraw, 0, 1024 * sizeof(int), stream);

  rowconv_kernel<<<2048, 256, 0, stream>>>(A, B, rows_bf, nA4, nt4);
  wconv_kernel<<<192, 256, 0, stream>>>(W_rev, W_fwd, W_gate, wbf);
  wc_kernel<<<128, 128, 0, stream>>>(W_gate, W_rev, b_rev, wbf + 49152, vab);
  wc_kernel<<<128, 128, 0, stream>>>(W_gate, W_fwd, b_fwd, wbf + 65536, vab + 128);

  binhist_kernel<<<1024, 256, 0, stream>>>(src, dst, binraw, na_bins, nbins, E);
  binscan_kernel<<<1, 512, 0, stream>>>(binraw, nbins, binstart, bincur);
  binfill_kernel<<<(E + 4095) / 4096, 512, 0, stream>>>(
      src, dst, bincur, binrec, n_a, na_bins, nbins, E);
  binscatter2_kernel<<<nbins, 256, 0, stream>>>(
      binrec, binstart, bincur, partner, start, cnt, n_a, n_total, na_bins);

  aggregate_mean_bf16_kernel<<<(n_total + 3) / 4, 256, 0, stream>>>(
      A_bf, B_bf, partner, start, cnt, mean_bf, n_a, n_total);

  // merged post kernel: blocks [0,gA) -> A range (256 rows each), then B
  const int gA = (n_a + 255) / 256;
  const int gB = (n_b + 255) / 256;
  fused_post_kernel<<<gA + gB, 512, 0, stream>>>(
      rows_bf, mean_bf, cnt, wbf, b_rev, b_fwd, b_gate, vab,
      out, n_a, n_b, gA);
}

// Round 18
// 300.364 us; speedup vs baseline: 2.0912x; 1.0065x over previous
//
#include <hip/hip_runtime.h>
#include <math.h>

#define DD 128

typedef __attribute__((ext_vector_type(8))) short short8;
typedef __attribute__((ext_vector_type(4))) float f32x4;
typedef __attribute__((ext_vector_type(4))) unsigned short us4;
typedef __attribute__((ext_vector_type(8))) unsigned short us8;

__device__ __forceinline__ unsigned short f2bf(float f) {
  unsigned int u = __builtin_bit_cast(unsigned int, f);
  u = (u + 0x7FFFu + ((u >> 16) & 1u)) >> 16;   // RNE (finite inputs)
  return (unsigned short)u;
}

__device__ __forceinline__ float b2f(unsigned short u) {
  return __builtin_bit_cast(float, ((unsigned)u) << 16);
}

// ---------------------------------------------------------------------------
// Row conversion f32 -> bf16: [A | B] into one table.
// ---------------------------------------------------------------------------
__global__ __launch_bounds__(256) void rowconv_kernel(
    const float* __restrict__ A, const float* __restrict__ B,
    unsigned short* __restrict__ dst, int nA4, int ntot4)
{
  int stride = gridDim.x * 256;
  for (int i = blockIdx.x * 256 + threadIdx.x; i < ntot4; i += stride) {
    float4 v = (i < nA4) ? ((const float4*)A)[i] : ((const float4*)B)[i - nA4];
    us4 o;
    o[0] = f2bf(v.x); o[1] = f2bf(v.y); o[2] = f2bf(v.z); o[3] = f2bf(v.w);
    ((us4*)dst)[i] = o;
  }
}

// ---------------------------------------------------------------------------
// Weight conversion f32 -> bf16: [Wrev | Wfwd | Wg1] (Wg1 = W_gate[:, :128])
// ---------------------------------------------------------------------------
__global__ __launch_bounds__(256) void wconv_kernel(
    const float* __restrict__ Wrev, const float* __restrict__ Wfwd,
    const float* __restrict__ Wgate, unsigned short* __restrict__ dst)
{
  int i = blockIdx.x * 256 + threadIdx.x;   // 49152 total
  float v;
  if (i < 16384) v = Wrev[i];
  else if (i < 32768) v = Wfwd[i - 16384];
  else {
    int j = (i - 32768) >> 7, k = (i - 32768) & 127;
    v = Wgate[j * 256 + k];                 // first half of each gate row
  }
  dst[i] = f2bf(v);
}

// ---------------------------------------------------------------------------
// Wc[j][k] = sum_m Wg2[j][m]*Wr[m][k], v[j] = sum_m Wg2[j][m]*br[m]
// (Wg2 = W_gate[:, 128:]) — f32 accumulate, bf16 output. (proven)
// ---------------------------------------------------------------------------
__global__ __launch_bounds__(128) void wc_kernel(
    const float* __restrict__ Wgate, const float* __restrict__ Wr,
    const float* __restrict__ br, unsigned short* __restrict__ Wc_bf,
    float* __restrict__ v)
{
  int j = blockIdx.x, k = threadIdx.x;
  const float* g2 = Wgate + (size_t)j * 256 + 128;
  float acc = 0.f;
  for (int m = 0; m < 128; ++m) acc += g2[m] * Wr[m * 128 + k];
  Wc_bf[j * 128 + k] = f2bf(acc);
  if (k == 0) {
    float a = 0.f;
    for (int m = 0; m < 128; ++m) a += g2[m] * br[m];
    v[j] = a;
  }
}

// ---------------------------------------------------------------------------
// Bin histogram. A rows: 1024-row bins; B rows: 256-row bins. (proven)
// ---------------------------------------------------------------------------
__global__ __launch_bounds__(256) void binhist_kernel(
    const int* __restrict__ src, const int* __restrict__ dst,
    int* __restrict__ binraw, int na_bins, int nbins, int E)
{
  __shared__ int h[1024];
  int t = threadIdx.x;
  for (int i = t; i < 1024; i += 256) h[i] = 0;
  __syncthreads();
  int stride = gridDim.x * 256;
  for (int e = blockIdx.x * 256 + t; e < E; e += stride) {
    int s = src[e], d = dst[e];
    atomicAdd(&h[s >> 10], 1);
    atomicAdd(&h[na_bins + (d >> 8)], 1);
  }
  __syncthreads();
  for (int i = t; i < nbins; i += 256)
    if (h[i]) atomicAdd(&binraw[i], h[i]);
}

// ---------------------------------------------------------------------------
// Exclusive scan over bin counts (single block, nbins <= 512). (proven)
// ---------------------------------------------------------------------------
__global__ __launch_bounds__(512) void binscan_kernel(
    const int* __restrict__ binraw, int nbins,
    int* __restrict__ binstart, int* __restrict__ bincur)
{
  __shared__ int buf[512];
  int t = threadIdx.x;
  int v = (t < nbins) ? binraw[t] : 0;
  buf[t] = v;
  __syncthreads();
  for (int off = 1; off < 512; off <<= 1) {
    int x = (t >= off) ? buf[t - off] : 0;
    __syncthreads();
    buf[t] += x;
    __syncthreads();
  }
  if (t < nbins) {
    int excl = buf[t] - v;
    binstart[t] = excl;
    bincur[t] = excl;
  }
}

// ---------------------------------------------------------------------------
// binfill — rank 8192 records per-bin in LDS, reserve dense runs, write
// (key=row, val=partner) as per-CU dense runs. (proven)
// ---------------------------------------------------------------------------
__global__ __launch_bounds__(512) void binfill_kernel(
    const int* __restrict__ src, const int* __restrict__ dst,
    int* __restrict__ bincur, uint2* __restrict__ binrec,
    int n_a, int na_bins, int nbins, int E)
{
  __shared__ int lcnt[1024];
  __shared__ int goff[1024];
  const int t = threadIdx.x;
  const int base = blockIdx.x * 4096;
  for (int i = t; i < 1024; i += 512) lcnt[i] = 0;
  __syncthreads();

  int bins[16], ranks[16];
  unsigned keys[16], vals[16];
  #pragma unroll
  for (int j = 0; j < 8; ++j) {
    int e = base + j * 512 + t;
    int i0 = 2 * j, i1 = 2 * j + 1;
    if (e < E) {
      int s = src[e], d = dst[e];
      bins[i0] = s >> 10;               keys[i0] = (unsigned)s;       vals[i0] = (unsigned)d;
      bins[i1] = na_bins + (d >> 8);    keys[i1] = (unsigned)(n_a + d); vals[i1] = (unsigned)s;
      ranks[i0] = atomicAdd(&lcnt[bins[i0]], 1);
      ranks[i1] = atomicAdd(&lcnt[bins[i1]], 1);
    } else {
      bins[i0] = -1; bins[i1] = -1;
      ranks[i0] = 0;  ranks[i1] = 0;
      keys[i0] = 0;   keys[i1] = 0;
      vals[i0] = 0;   vals[i1] = 0;
    }
  }
  __syncthreads();
  for (int b = t; b < nbins; b += 512)
    if (lcnt[b]) goff[b] = atomicAdd(&bincur[b], lcnt[b]);
  __syncthreads();
  #pragma unroll
  for (int i = 0; i < 16; ++i) {
    if (bins[i] >= 0) {
      int p = goff[bins[i]] + ranks[i];
      binrec[p] = make_uint2(keys[i], vals[i]);
    }
  }
}

// ---------------------------------------------------------------------------
// binscatter2 — one block per bin: per-bin LDS counting sort producing
// start/cnt + partner list. (round-14-proven)
// ---------------------------------------------------------------------------
__global__ __launch_bounds__(256) void binscatter2_kernel(
    const uint2* __restrict__ binrec, const int* __restrict__ binstart,
    const int* __restrict__ binend, int* __restrict__ partner,
    int* __restrict__ start, int* __restrict__ cnt,
    int n_a, int n_total, int na_bins)
{
  __shared__ int cntL[1024];
  __shared__ int curL[1024];
  __shared__ int sbuf[256];
  const int b = blockIdx.x;
  const int t = threadIdx.x;
  int row0, nrows;
  if (b < na_bins) { row0 = b << 10; nrows = min(1024, n_a - row0); }
  else { row0 = n_a + ((b - na_bins) << 8); nrows = min(256, n_total - row0); }
  const int s0 = binstart[b], e0 = binend[b];

  for (int i = t; i < 1024; i += 256) cntL[i] = 0;
  __syncthreads();
  for (int i = s0 + t; i < e0; i += 256)
    atomicAdd(&cntL[binrec[i].x - (unsigned)row0], 1);
  __syncthreads();
  int l0 = cntL[4 * t], l1 = cntL[4 * t + 1];
  int l2 = cntL[4 * t + 2], l3 = cntL[4 * t + 3];
  int s = l0 + l1 + l2 + l3;
  sbuf[t] = s;
  __syncthreads();
  for (int off = 1; off < 256; off <<= 1) {
    int x = (t >= off) ? sbuf[t - off] : 0;
    __syncthreads();
    sbuf[t] += x;
    __syncthreads();
  }
  int excl = sbuf[t] - s;
  curL[4 * t]     = excl;
  curL[4 * t + 1] = excl + l0;
  curL[4 * t + 2] = excl + l0 + l1;
  curL[4 * t + 3] = excl + l0 + l1 + l2;
  __syncthreads();
  for (int j = t; j < nrows; j += 256) {
    start[row0 + j] = s0 + curL[j];
    cnt[row0 + j] = cntL[j];
  }
  __syncthreads();
  for (int i = s0 + t; i < e0; i += 256) {
    uint2 r = binrec[i];
    int pos = atomicAdd(&curL[r.x - (unsigned)row0], 1);
    partner[s0 + pos] = (int)r.y;
  }
}

// ---------------------------------------------------------------------------
// Aggregate v3: one wave per row; 16 lanes x 16B (us8), 4 quads x 4 batches
// = 16 edges in flight. (round-14-proven)
// ---------------------------------------------------------------------------
__global__ __launch_bounds__(256) void aggregate_mean_bf16_kernel(
    const unsigned short* __restrict__ A_bf,
    const unsigned short* __restrict__ B_bf,
    const int* __restrict__ partner, const int* __restrict__ start,
    const int* __restrict__ cnt, unsigned short* __restrict__ mean_bf,
    int n_a, int n_total)
{
  int wid = (blockIdx.x * 256 + threadIdx.x) >> 6;
  if (wid >= n_total) return;
  int lane = threadIdx.x & 63;
  int q    = lane & 15;
  int quad = lane >> 4;
  int s0 = start[wid], c = cnt[wid];
  const unsigned short* tbl = (wid < n_a) ? B_bf : A_bf;
  float a0 = 0.f, a1 = 0.f, a2 = 0.f, a3 = 0.f;
  float a4 = 0.f, a5 = 0.f, a6 = 0.f, a7 = 0.f;
  int k = 0;
  for (; k + 16 <= c; k += 16) {
    int p0 = partner[s0 + k + 0 + quad];
    int p1 = partner[s0 + k + 4 + quad];
    int p2 = partner[s0 + k + 8 + quad];
    int p3 = partner[s0 + k + 12 + quad];
    us8 v0 = *(const us8*)(tbl + (size_t)p0 * DD + 8 * q);
    us8 v1 = *(const us8*)(tbl + (size_t)p1 * DD + 8 * q);
    us8 v2 = *(const us8*)(tbl + (size_t)p2 * DD + 8 * q);
    us8 v3 = *(const us8*)(tbl + (size_t)p3 * DD + 8 * q);
    a0 += b2f(v0[0]) + b2f(v1[0]) + b2f(v2[0]) + b2f(v3[0]);
    a1 += b2f(v0[1]) + b2f(v1[1]) + b2f(v2[1]) + b2f(v3[1]);
    a2 += b2f(v0[2]) + b2f(v1[2]) + b2f(v2[2]) + b2f(v3[2]);
    a3 += b2f(v0[3]) + b2f(v1[3]) + b2f(v2[3]) + b2f(v3[3]);
    a4 += b2f(v0[4]) + b2f(v1[4]) + b2f(v2[4]) + b2f(v3[4]);
    a5 += b2f(v0[5]) + b2f(v1[5]) + b2f(v2[5]) + b2f(v3[5]);
    a6 += b2f(v0[6]) + b2f(v1[6]) + b2f(v2[6]) + b2f(v3[6]);
    a7 += b2f(v0[7]) + b2f(v1[7]) + b2f(v2[7]) + b2f(v3[7]);
  }
  for (; k < c; k += 4) {
    int i = k + quad;
    if (i < c) {
      int p = partner[s0 + i];
      us8 v = *(const us8*)(tbl + (size_t)p * DD + 8 * q);
      a0 += b2f(v[0]); a1 += b2f(v[1]); a2 += b2f(v[2]); a3 += b2f(v[3]);
      a4 += b2f(v[4]); a5 += b2f(v[5]); a6 += b2f(v[6]); a7 += b2f(v[7]);
    }
  }
  a0 += __shfl_xor(a0, 16); a0 += __shfl_xor(a0, 32);
  a1 += __shfl_xor(a1, 16); a1 += __shfl_xor(a1, 32);
  a2 += __shfl_xor(a2, 16); a2 += __shfl_xor(a2, 32);
  a3 += __shfl_xor(a3, 16); a3 += __shfl_xor(a3, 32);
  a4 += __shfl_xor(a4, 16); a4 += __shfl_xor(a4, 32);
  a5 += __shfl_xor(a5, 16); a5 += __shfl_xor(a5, 32);
  a6 += __shfl_xor(a6, 16); a6 += __shfl_xor(a6, 32);
  a7 += __shfl_xor(a7, 16); a7 += __shfl_xor(a7, 32);
  if (lane < 16) {
    float inv = (c > 0) ? (1.f / (float)c) : 0.f;
    us8 o;
    o[0] = f2bf(a0 * inv); o[1] = f2bf(a1 * inv);
    o[2] = f2bf(a2 * inv); o[3] = f2bf(a3 * inv);
    o[4] = f2bf(a4 * inv); o[5] = f2bf(a5 * inv);
    o[6] = f2bf(a6 * inv); o[7] = f2bf(a7 * inv);
    *(us8*)&mean_bf[(size_t)wid * DD + 8 * q] = o;
  }
}

// ---------------------------------------------------------------------------
// Fused post v7 (MFMA) — round-17 structure (2 row-tiles/wave, swapped
// operands, vector epilogue) + jt-PAIRING: process j-tiles in pairs so each
// GEMM phase has 4 independent accumulator chains (2 tiles x 2 j-tiles).
// Same loads/stores/swizzles/MFMA count — pure ILP reorganization.
//   t = (cnt>0) ? mean @ Wr^T + br : 0
//   u = row @ Wg1^T + mean @ Wc^T + (cnt>0 ? bg+v : bg)
//   out = sigmoid(u)*row + (1-sigmoid(u))*t
// ---------------------------------------------------------------------------
__global__ __launch_bounds__(512, 4) void fused_post_kernel(
    const unsigned short* __restrict__ rows_bf,  // [n_total][128] bf16
    const unsigned short* __restrict__ mean_bf,  // [n_total][128] bf16
    const int* __restrict__ cnt,                 // [n_total]
    const unsigned short* __restrict__ wbf,      // [Wrev|Wfwd|Wg1|WcA|WcB]
    const float* __restrict__ b_rev, const float* __restrict__ b_fwd,
    const float* __restrict__ bg, const float* __restrict__ vab,
    float* __restrict__ out, int n_a, int n_b, int gA)
{
  __shared__ unsigned short Wr_l[128 * 128];   // 32 KB
  __shared__ unsigned short Wg1_l[128 * 128];  // 32 KB
  __shared__ __align__(16) float br_l[128];
  __shared__ __align__(16) float bg_l[128];
  __shared__ __align__(16) float bgv_l[128];

  const int t = threadIdx.x;
  const bool isB = (int)blockIdx.x >= gA;
  const int bid = isB ? ((int)blockIdx.x - gA) : (int)blockIdx.x;
  const int n   = isB ? n_b : n_a;
  const size_t roff = isB ? (size_t)n_a * DD : 0;
  const unsigned short* rowsp = rows_bf + roff;
  const unsigned short* meanp = mean_bf + roff;
  const int* cntp = cnt + (isB ? n_a : 0);
  float* outp = out + roff;
  const unsigned short* Wr_g  = wbf + (isB ? 16384 : 0);
  const unsigned short* Wg1_g = wbf + 32768;
  const unsigned short* Wc_g  = wbf + 49152 + (isB ? 16384 : 0);
  const float* brp = isB ? b_fwd : b_rev;
  const float* vp  = vab + (isB ? 128 : 0);

  // stage Wr + Wg1 (2048 16B-octets each), proven octet-XOR swizzle
  for (int oi = t; oi < 2048; oi += 512) {
    int j = oi >> 4, o = oi & 15;
    int d = j * 128 + ((o ^ (j & 15)) << 3);
    *(short8*)&Wr_l[d]  = *(const short8*)&Wr_g[oi << 3];
    *(short8*)&Wg1_l[d] = *(const short8*)&Wg1_g[oi << 3];
  }
  if (t < 128) {
    float b = brp[t], g = bg[t], v = vp[t];
    br_l[t] = b; bg_l[t] = g; bgv_l[t] = g + v;
  }
  __syncthreads();

  const int wid  = t >> 6;
  const int lane = t & 63;
  const int lrow = lane & 15;   // row within tile owned by this lane
  const int lgrp = lane >> 4;   // k-octet group / j-quad selector
  const int m0 = bid * 256 + wid * 32;
  if (m0 >= n) return;

  const int mA = m0 + lrow;          // tile 0 row
  const int mB = m0 + 16 + lrow;     // tile 1 row
  const bool okA = mA < n, okB = mB < n;
  const int cvA = okA ? cntp[mA] : 0;
  const int cvB = okB ? cntp[mB] : 0;

  // x-fragments for both tiles (B-operand layout: row m, octet ks*4+lgrp)
  short8 amA[4], arA[4], amB[4], arB[4];
  #pragma unroll
  for (int ks = 0; ks < 4; ++ks) {
    short8 z = {0, 0, 0, 0, 0, 0, 0, 0};
    amA[ks] = z; arA[ks] = z; amB[ks] = z; arB[ks] = z;
    size_t ofs = ks * 32 + lgrp * 8;
    if (okA) {
      amA[ks] = *(const short8*)&meanp[(size_t)mA * DD + ofs];
      arA[ks] = *(const short8*)&rowsp[(size_t)mA * DD + ofs];
    }
    if (okB) {
      amB[ks] = *(const short8*)&meanp[(size_t)mB * DD + ofs];
      arB[ks] = *(const short8*)&rowsp[(size_t)mB * DD + ofs];
    }
  }

  #pragma unroll
  for (int jt = 0; jt < 8; jt += 2) {
    const int r0 = (jt * 16 + lrow) * 128;        // Wr/Wg1 LDS row base, jt
    const int r1 = ((jt + 1) * 16 + lrow) * 128;  // ... jt+1
    const int j0 = jt * 16 + lgrp * 4;
    const int j1 = j0 + 16;

    // t = mean @ Wr^T + br  — 4 independent chains (2 tiles x 2 j-tiles)
    f32x4 tA0 = *(const f32x4*)&br_l[j0], tB0 = tA0;
    f32x4 tA1 = *(const f32x4*)&br_l[j1], tB1 = tA1;
    #pragma unroll
    for (int ks = 0; ks < 4; ++ks) {
      int so = ((ks * 4 + lgrp) ^ lrow) << 3;
      short8 w0 = *(short8*)&Wr_l[r0 + so];
      short8 w1 = *(short8*)&Wr_l[r1 + so];
      tA0 = __builtin_amdgcn_mfma_f32_16x16x32_bf16(w0, amA[ks], tA0, 0, 0, 0);
      tB0 = __builtin_amdgcn_mfma_f32_16x16x32_bf16(w0, amB[ks], tB0, 0, 0, 0);
      tA1 = __builtin_amdgcn_mfma_f32_16x16x32_bf16(w1, amA[ks], tA1, 0, 0, 0);
      tB1 = __builtin_amdgcn_mfma_f32_16x16x32_bf16(w1, amB[ks], tB1, 0, 0, 0);
    }
    if (cvA == 0) { tA0 = (f32x4){0.f,0.f,0.f,0.f}; tA1 = tA0; }
    if (cvB == 0) { tB0 = (f32x4){0.f,0.f,0.f,0.f}; tB1 = tB0; }

    // u = row @ Wg1^T (LDS) + mean @ Wc^T (GLOBAL, L2) + (cv ? bg+v : bg)
    f32x4 uA0 = (cvA > 0) ? *(const f32x4*)&bgv_l[j0] : *(const f32x4*)&bg_l[j0];
    f32x4 uB0 = (cvB > 0) ? *(const f32x4*)&bgv_l[j0] : *(const f32x4*)&bg_l[j0];
    f32x4 uA1 = (cvA > 0) ? *(const f32x4*)&bgv_l[j1] : *(const f32x4*)&bg_l[j1];
    f32x4 uB1 = (cvB > 0) ? *(const f32x4*)&bgv_l[j1] : *(const f32x4*)&bg_l[j1];
    #pragma unroll
    for (int ks = 0; ks < 4; ++ks) {
      int so = ((ks * 4 + lgrp) ^ lrow) << 3;
      short8 w0 = *(short8*)&Wg1_l[r0 + so];
      short8 w1 = *(short8*)&Wg1_l[r1 + so];
      uA0 = __builtin_amdgcn_mfma_f32_16x16x32_bf16(w0, arA[ks], uA0, 0, 0, 0);
      uB0 = __builtin_amdgcn_mfma_f32_16x16x32_bf16(w0, arB[ks], uB0, 0, 0, 0);
      uA1 = __builtin_amdgcn_mfma_f32_16x16x32_bf16(w1, arA[ks], uA1, 0, 0, 0);
      uB1 = __builtin_amdgcn_mfma_f32_16x16x32_bf16(w1, arB[ks], uB1, 0, 0, 0);
    }
    #pragma unroll
    for (int ks = 0; ks < 4; ++ks) {
      size_t go = (size_t)(ks * 4 + lgrp) * 8;
      short8 w0 = *(const short8*)&Wc_g[(size_t)(jt * 16 + lrow) * 128 + go];
      short8 w1 = *(const short8*)&Wc_g[(size_t)((jt + 1) * 16 + lrow) * 128 + go];
      uA0 = __builtin_amdgcn_mfma_f32_16x16x32_bf16(w0, amA[ks], uA0, 0, 0, 0);
      uB0 = __builtin_amdgcn_mfma_f32_16x16x32_bf16(w0, amB[ks], uB0, 0, 0, 0);
      uA1 = __builtin_amdgcn_mfma_f32_16x16x32_bf16(w1, amA[ks], uA1, 0, 0, 0);
      uB1 = __builtin_amdgcn_mfma_f32_16x16x32_bf16(w1, amB[ks], uB1, 0, 0, 0);
    }

    // epilogue: 4 (tile, j-tile) combos, vector loads/stores
    #pragma unroll
    for (int half = 0; half < 2; ++half) {
      int jj = (half == 0) ? j0 : j1;
      f32x4 uA = (half == 0) ? uA0 : uA1;
      f32x4 uB = (half == 0) ? uB0 : uB1;
      f32x4 tA = (half == 0) ? tA0 : tA1;
      f32x4 tB = (half == 0) ? tB0 : tB1;
      if (okA) {
        us4 rv = *(const us4*)&rowsp[(size_t)mA * DD + jj];
        float4 o;
        float g0 = 1.f / (1.f + __expf(-uA[0]));
        float g1 = 1.f / (1.f + __expf(-uA[1]));
        float g2 = 1.f / (1.f + __expf(-uA[2]));
        float g3 = 1.f / (1.f + __expf(-uA[3]));
        o.x = g0 * b2f(rv[0]) + (1.f - g0) * tA[0];
        o.y = g1 * b2f(rv[1]) + (1.f - g1) * tA[1];
        o.z = g2 * b2f(rv[2]) + (1.f - g2) * tA[2];
        o.w = g3 * b2f(rv[3]) + (1.f - g3) * tA[3];
        *(float4*)&outp[(size_t)mA * DD + jj] = o;
      }
      if (okB) {
        us4 rv = *(const us4*)&rowsp[(size_t)mB * DD + jj];
        float4 o;
        float g0 = 1.f / (1.f + __expf(-uB[0]));
        float g1 = 1.f / (1.f + __expf(-uB[1]));
        float g2 = 1.f / (1.f + __expf(-uB[2]));
        float g3 = 1.f / (1.f + __expf(-uB[3]));
        o.x = g0 * b2f(rv[0]) + (1.f - g0) * tB[0];
        o.y = g1 * b2f(rv[1]) + (1.f - g1) * tB[1];
        o.z = g2 * b2f(rv[2]) + (1.f - g2) * tB[2];
        o.w = g3 * b2f(rv[3]) + (1.f - g3) * tB[3];
        *(float4*)&outp[(size_t)mB * DD + jj] = o;
      }
    }
  }
}

extern "C" void kernel_launch(void* const* d_in, const int* in_sizes, int n_in,
                              void* d_out, int out_size, void* d_ws, size_t ws_size,
                              hipStream_t stream) {
  const float* A      = (const float*)d_in[0];
  const float* B      = (const float*)d_in[1];
  const float* W_fwd  = (const float*)d_in[2];
  const float* b_fwd  = (const float*)d_in[3];
  const float* W_rev  = (const float*)d_in[4];
  const float* b_rev  = (const float*)d_in[5];
  const float* W_gate = (const float*)d_in[6];
  const float* b_gate = (const float*)d_in[7];
  const int*   src    = (const int*)d_in[8];
  const int*   dst    = (const int*)d_in[9];

  const int n_a = in_sizes[0] / DD;
  const int n_b = in_sizes[1] / DD;
  const int E   = in_sizes[8];
  const int n_total = n_a + n_b;

  const int na_bins = (n_a + 1023) >> 10;
  const int nb_bins = (n_b + 255) >> 8;
  const int nbins   = na_bins + nb_bins;

  float* out = (float*)d_out;

  // workspace layout
  int* cnt      = (int*)d_ws;                        // [n_total]
  int* binraw   = cnt + n_total;                     // [1024]
  int* start    = binraw + 1024;                     // [n_total]
  int* binstart = start + n_total;                   // [1024]
  int* bincur   = binstart + 1024;                   // [1024]
  uint2* binrec = (uint2*)(bincur + 1024);           // [2E]
  int* partner  = (int*)(binrec + 2 * (size_t)E);    // [2E]
  uintptr_t wp = (uintptr_t)(partner + 2 * (size_t)E);
  wp = (wp + 63) & ~(uintptr_t)63;
  unsigned short* wbf = (unsigned short*)wp;         // [81920]: Wrev|Wfwd|Wg1|WcA|WcB
  float* vab = (float*)(wbf + 81920);                // [256] f32: vA | vB
  unsigned short* rows_bf = (unsigned short*)(vab + 256);  // [n_total*128]
  unsigned short* A_bf = rows_bf;
  unsigned short* B_bf = rows_bf + (size_t)n_a * DD;
  unsigned short* mean_bf = rows_bf + (size_t)n_total * DD; // [n_total*128]

  const int nA4  = n_a * (DD / 4);
  const int nt4  = n_total * (DD / 4);

  hipMemsetAsync(binraw, 0, 1024 * sizeof(int), stream);

  rowconv_kernel<<<2048, 256, 0, stream>>>(A, B, rows_bf, nA4, nt4);
  wconv_kernel<<<192, 256, 0, stream>>>(W_rev, W_fwd, W_gate, wbf);
  wc_kernel<<<128, 128, 0, stream>>>(W_gate, W_rev, b_rev, wbf + 49152, vab);
  wc_kernel<<<128, 128, 0, stream>>>(W_gate, W_fwd, b_fwd, wbf + 65536, vab + 128);

  binhist_kernel<<<1024, 256, 0, stream>>>(src, dst, binraw, na_bins, nbins, E);
  binscan_kernel<<<1, 512, 0, stream>>>(binraw, nbins, binstart, bincur);
  binfill_kernel<<<(E + 4095) / 4096, 512, 0, stream>>>(
      src, dst, bincur, binrec, n_a, na_bins, nbins, E);
  binscatter2_kernel<<<nbins, 256, 0, stream>>>(
      binrec, binstart, bincur, partner, start, cnt, n_a, n_total, na_bins);

  aggregate_mean_bf16_kernel<<<(n_total + 3) / 4, 256, 0, stream>>>(
      A_bf, B_bf, partner, start, cnt, mean_bf, n_a, n_total);

  // merged post kernel: blocks [0,gA) -> A range (256 rows each), then B
  const int gA = (n_a + 255) / 256;
  const int gB = (n_b + 255) / 256;
  fused_post_kernel<<<gA + gB, 512, 0, stream>>>(
      rows_bf, mean_bf, cnt, wbf, b_rev, b_fwd, b_gate, vab,
      out, n_a, n_b, gA);
}

// Round 19
// 298.783 us; speedup vs baseline: 2.1023x; 1.0053x over previous
//
#include <hip/hip_runtime.h>
#include <math.h>

#define DD 128

typedef __attribute__((ext_vector_type(8))) short short8;
typedef __attribute__((ext_vector_type(4))) float f32x4;
typedef __attribute__((ext_vector_type(4))) unsigned short us4;
typedef __attribute__((ext_vector_type(8))) unsigned short us8;

__device__ __forceinline__ unsigned short f2bf(float f) {
  unsigned int u = __builtin_bit_cast(unsigned int, f);
  u = (u + 0x7FFFu + ((u >> 16) & 1u)) >> 16;   // RNE (finite inputs)
  return (unsigned short)u;
}

__device__ __forceinline__ float b2f(unsigned short u) {
  return __builtin_bit_cast(float, ((unsigned)u) << 16);
}

// ---------------------------------------------------------------------------
// Row conversion f32 -> bf16: [A | B] into one table.
// ---------------------------------------------------------------------------
__global__ __launch_bounds__(256) void rowconv_kernel(
    const float* __restrict__ A, const float* __restrict__ B,
    unsigned short* __restrict__ dst, int nA4, int ntot4)
{
  int stride = gridDim.x * 256;
  for (int i = blockIdx.x * 256 + threadIdx.x; i < ntot4; i += stride) {
    float4 v = (i < nA4) ? ((const float4*)A)[i] : ((const float4*)B)[i - nA4];
    us4 o;
    o[0] = f2bf(v.x); o[1] = f2bf(v.y); o[2] = f2bf(v.z); o[3] = f2bf(v.w);
    ((us4*)dst)[i] = o;
  }
}

// ---------------------------------------------------------------------------
// Weight conversion f32 -> bf16: [Wrev | Wfwd | Wg1] (Wg1 = W_gate[:, :128])
// ---------------------------------------------------------------------------
__global__ __launch_bounds__(256) void wconv_kernel(
    const float* __restrict__ Wrev, const float* __restrict__ Wfwd,
    const float* __restrict__ Wgate, unsigned short* __restrict__ dst)
{
  int i = blockIdx.x * 256 + threadIdx.x;   // 49152 total
  float v;
  if (i < 16384) v = Wrev[i];
  else if (i < 32768) v = Wfwd[i - 16384];
  else {
    int j = (i - 32768) >> 7, k = (i - 32768) & 127;
    v = Wgate[j * 256 + k];                 // first half of each gate row
  }
  dst[i] = f2bf(v);
}

// ---------------------------------------------------------------------------
// Wc[j][k] = sum_m Wg2[j][m]*Wr[m][k], v[j] = sum_m Wg2[j][m]*br[m]
// (Wg2 = W_gate[:, 128:]) — f32 accumulate, bf16 output. (proven)
// ---------------------------------------------------------------------------
__global__ __launch_bounds__(128) void wc_kernel(
    const float* __restrict__ Wgate, const float* __restrict__ Wr,
    const float* __restrict__ br, unsigned short* __restrict__ Wc_bf,
    float* __restrict__ v)
{
  int j = blockIdx.x, k = threadIdx.x;
  const float* g2 = Wgate + (size_t)j * 256 + 128;
  float acc = 0.f;
  for (int m = 0; m < 128; ++m) acc += g2[m] * Wr[m * 128 + k];
  Wc_bf[j * 128 + k] = f2bf(acc);
  if (k == 0) {
    float a = 0.f;
    for (int m = 0; m < 128; ++m) a += g2[m] * br[m];
    v[j] = a;
  }
}

// ---------------------------------------------------------------------------
// Bin histogram. A rows: 1024-row bins; B rows: 256-row bins. (proven)
// ---------------------------------------------------------------------------
__global__ __launch_bounds__(256) void binhist_kernel(
    const int* __restrict__ src, const int* __restrict__ dst,
    int* __restrict__ binraw, int na_bins, int nbins, int E)
{
  __shared__ int h[1024];
  int t = threadIdx.x;
  for (int i = t; i < 1024; i += 256) h[i] = 0;
  __syncthreads();
  int stride = gridDim.x * 256;
  for (int e = blockIdx.x * 256 + t; e < E; e += stride) {
    int s = src[e], d = dst[e];
    atomicAdd(&h[s >> 10], 1);
    atomicAdd(&h[na_bins + (d >> 8)], 1);
  }
  __syncthreads();
  for (int i = t; i < nbins; i += 256)
    if (h[i]) atomicAdd(&binraw[i], h[i]);
}

// ---------------------------------------------------------------------------
// Exclusive scan over bin counts (single block, nbins <= 512). (proven)
// ---------------------------------------------------------------------------
__global__ __launch_bounds__(512) void binscan_kernel(
    const int* __restrict__ binraw, int nbins,
    int* __restrict__ binstart, int* __restrict__ bincur)
{
  __shared__ int buf[512];
  int t = threadIdx.x;
  int v = (t < nbins) ? binraw[t] : 0;
  buf[t] = v;
  __syncthreads();
  for (int off = 1; off < 512; off <<= 1) {
    int x = (t >= off) ? buf[t - off] : 0;
    __syncthreads();
    buf[t] += x;
    __syncthreads();
  }
  if (t < nbins) {
    int excl = buf[t] - v;
    binstart[t] = excl;
    bincur[t] = excl;
  }
}

// ---------------------------------------------------------------------------
// binfill — rank 8192 records per-bin in LDS, reserve dense runs, write
// (key=row, val=partner) as per-CU dense runs. (proven)
// ---------------------------------------------------------------------------
__global__ __launch_bounds__(512) void binfill_kernel(
    const int* __restrict__ src, const int* __restrict__ dst,
    int* __restrict__ bincur, uint2* __restrict__ binrec,
    int n_a, int na_bins, int nbins, int E)
{
  __shared__ int lcnt[1024];
  __shared__ int goff[1024];
  const int t = threadIdx.x;
  const int base = blockIdx.x * 4096;
  for (int i = t; i < 1024; i += 512) lcnt[i] = 0;
  __syncthreads();

  int bins[16], ranks[16];
  unsigned keys[16], vals[16];
  #pragma unroll
  for (int j = 0; j < 8; ++j) {
    int e = base + j * 512 + t;
    int i0 = 2 * j, i1 = 2 * j + 1;
    if (e < E) {
      int s = src[e], d = dst[e];
      bins[i0] = s >> 10;               keys[i0] = (unsigned)s;       vals[i0] = (unsigned)d;
      bins[i1] = na_bins + (d >> 8);    keys[i1] = (unsigned)(n_a + d); vals[i1] = (unsigned)s;
      ranks[i0] = atomicAdd(&lcnt[bins[i0]], 1);
      ranks[i1] = atomicAdd(&lcnt[bins[i1]], 1);
    } else {
      bins[i0] = -1; bins[i1] = -1;
      ranks[i0] = 0;  ranks[i1] = 0;
      keys[i0] = 0;   keys[i1] = 0;
      vals[i0] = 0;   vals[i1] = 0;
    }
  }
  __syncthreads();
  for (int b = t; b < nbins; b += 512)
    if (lcnt[b]) goff[b] = atomicAdd(&bincur[b], lcnt[b]);
  __syncthreads();
  #pragma unroll
  for (int i = 0; i < 16; ++i) {
    if (bins[i] >= 0) {
      int p = goff[bins[i]] + ranks[i];
      binrec[p] = make_uint2(keys[i], vals[i]);
    }
  }
}

// ---------------------------------------------------------------------------
// binscatter2 — one block per bin: per-bin LDS counting sort producing
// start/cnt + partner list. (round-14-proven)
// ---------------------------------------------------------------------------
__global__ __launch_bounds__(256) void binscatter2_kernel(
    const uint2* __restrict__ binrec, const int* __restrict__ binstart,
    const int* __restrict__ binend, int* __restrict__ partner,
    int* __restrict__ start, int* __restrict__ cnt,
    int n_a, int n_total, int na_bins)
{
  __shared__ int cntL[1024];
  __shared__ int curL[1024];
  __shared__ int sbuf[256];
  const int b = blockIdx.x;
  const int t = threadIdx.x;
  int row0, nrows;
  if (b < na_bins) { row0 = b << 10; nrows = min(1024, n_a - row0); }
  else { row0 = n_a + ((b - na_bins) << 8); nrows = min(256, n_total - row0); }
  const int s0 = binstart[b], e0 = binend[b];

  for (int i = t; i < 1024; i += 256) cntL[i] = 0;
  __syncthreads();
  for (int i = s0 + t; i < e0; i += 256)
    atomicAdd(&cntL[binrec[i].x - (unsigned)row0], 1);
  __syncthreads();
  int l0 = cntL[4 * t], l1 = cntL[4 * t + 1];
  int l2 = cntL[4 * t + 2], l3 = cntL[4 * t + 3];
  int s = l0 + l1 + l2 + l3;
  sbuf[t] = s;
  __syncthreads();
  for (int off = 1; off < 256; off <<= 1) {
    int x = (t >= off) ? sbuf[t - off] : 0;
    __syncthreads();
    sbuf[t] += x;
    __syncthreads();
  }
  int excl = sbuf[t] - s;
  curL[4 * t]     = excl;
  curL[4 * t + 1] = excl + l0;
  curL[4 * t + 2] = excl + l0 + l1;
  curL[4 * t + 3] = excl + l0 + l1 + l2;
  __syncthreads();
  for (int j = t; j < nrows; j += 256) {
    start[row0 + j] = s0 + curL[j];
    cnt[row0 + j] = cntL[j];
  }
  __syncthreads();
  for (int i = s0 + t; i < e0; i += 256) {
    uint2 r = binrec[i];
    int pos = atomicAdd(&curL[r.x - (unsigned)row0], 1);
    partner[s0 + pos] = (int)r.y;
  }
}

// ---------------------------------------------------------------------------
// Aggregate v3: one wave per row; 16 lanes x 16B (us8), 4 quads x 4 batches
// = 16 edges in flight. (round-14-proven)
// ---------------------------------------------------------------------------
__global__ __launch_bounds__(256) void aggregate_mean_bf16_kernel(
    const unsigned short* __restrict__ A_bf,
    const unsigned short* __restrict__ B_bf,
    const int* __restrict__ partner, const int* __restrict__ start,
    const int* __restrict__ cnt, unsigned short* __restrict__ mean_bf,
    int n_a, int n_total)
{
  int wid = (blockIdx.x * 256 + threadIdx.x) >> 6;
  if (wid >= n_total) return;
  int lane = threadIdx.x & 63;
  int q    = lane & 15;
  int quad = lane >> 4;
  int s0 = start[wid], c = cnt[wid];
  const unsigned short* tbl = (wid < n_a) ? B_bf : A_bf;
  float a0 = 0.f, a1 = 0.f, a2 = 0.f, a3 = 0.f;
  float a4 = 0.f, a5 = 0.f, a6 = 0.f, a7 = 0.f;
  int k = 0;
  for (; k + 16 <= c; k += 16) {
    int p0 = partner[s0 + k + 0 + quad];
    int p1 = partner[s0 + k + 4 + quad];
    int p2 = partner[s0 + k + 8 + quad];
    int p3 = partner[s0 + k + 12 + quad];
    us8 v0 = *(const us8*)(tbl + (size_t)p0 * DD + 8 * q);
    us8 v1 = *(const us8*)(tbl + (size_t)p1 * DD + 8 * q);
    us8 v2 = *(const us8*)(tbl + (size_t)p2 * DD + 8 * q);
    us8 v3 = *(const us8*)(tbl + (size_t)p3 * DD + 8 * q);
    a0 += b2f(v0[0]) + b2f(v1[0]) + b2f(v2[0]) + b2f(v3[0]);
    a1 += b2f(v0[1]) + b2f(v1[1]) + b2f(v2[1]) + b2f(v3[1]);
    a2 += b2f(v0[2]) + b2f(v1[2]) + b2f(v2[2]) + b2f(v3[2]);
    a3 += b2f(v0[3]) + b2f(v1[3]) + b2f(v2[3]) + b2f(v3[3]);
    a4 += b2f(v0[4]) + b2f(v1[4]) + b2f(v2[4]) + b2f(v3[4]);
    a5 += b2f(v0[5]) + b2f(v1[5]) + b2f(v2[5]) + b2f(v3[5]);
    a6 += b2f(v0[6]) + b2f(v1[6]) + b2f(v2[6]) + b2f(v3[6]);
    a7 += b2f(v0[7]) + b2f(v1[7]) + b2f(v2[7]) + b2f(v3[7]);
  }
  for (; k < c; k += 4) {
    int i = k + quad;
    if (i < c) {
      int p = partner[s0 + i];
      us8 v = *(const us8*)(tbl + (size_t)p * DD + 8 * q);
      a0 += b2f(v[0]); a1 += b2f(v[1]); a2 += b2f(v[2]); a3 += b2f(v[3]);
      a4 += b2f(v[4]); a5 += b2f(v[5]); a6 += b2f(v[6]); a7 += b2f(v[7]);
    }
  }
  a0 += __shfl_xor(a0, 16); a0 += __shfl_xor(a0, 32);
  a1 += __shfl_xor(a1, 16); a1 += __shfl_xor(a1, 32);
  a2 += __shfl_xor(a2, 16); a2 += __shfl_xor(a2, 32);
  a3 += __shfl_xor(a3, 16); a3 += __shfl_xor(a3, 32);
  a4 += __shfl_xor(a4, 16); a4 += __shfl_xor(a4, 32);
  a5 += __shfl_xor(a5, 16); a5 += __shfl_xor(a5, 32);
  a6 += __shfl_xor(a6, 16); a6 += __shfl_xor(a6, 32);
  a7 += __shfl_xor(a7, 16); a7 += __shfl_xor(a7, 32);
  if (lane < 16) {
    float inv = (c > 0) ? (1.f / (float)c) : 0.f;
    us8 o;
    o[0] = f2bf(a0 * inv); o[1] = f2bf(a1 * inv);
    o[2] = f2bf(a2 * inv); o[3] = f2bf(a3 * inv);
    o[4] = f2bf(a4 * inv); o[5] = f2bf(a5 * inv);
    o[6] = f2bf(a6 * inv); o[7] = f2bf(a7 * inv);
    *(us8*)&mean_bf[(size_t)wid * DD + 8 * q] = o;
  }
}

// ---------------------------------------------------------------------------
// Fused post v8 (MFMA) — round-18 body, but 1024-thread blocks with ALL
// THREE weights (Wr, Wg1, Wc) in LDS (96 KB, 1 block/CU = 16 waves/CU, same
// occupancy as 2x512@64KB) — removes the L2-latency-exposed Wc global loads
// from the dependency chain. 512 rows/block; 2 row-tiles/wave; jt-pairing
// (4 independent chains); swapped operands; vector epilogue.
//   t = (cnt>0) ? mean @ Wr^T + br : 0
//   u = row @ Wg1^T + mean @ Wc^T + (cnt>0 ? bg+v : bg)
//   out = sigmoid(u)*row + (1-sigmoid(u))*t
// ---------------------------------------------------------------------------
__global__ __launch_bounds__(1024, 1) void fused_post_kernel(
    const unsigned short* __restrict__ rows_bf,  // [n_total][128] bf16
    const unsigned short* __restrict__ mean_bf,  // [n_total][128] bf16
    const int* __restrict__ cnt,                 // [n_total]
    const unsigned short* __restrict__ wbf,      // [Wrev|Wfwd|Wg1|WcA|WcB]
    const float* __restrict__ b_rev, const float* __restrict__ b_fwd,
    const float* __restrict__ bg, const float* __restrict__ vab,
    float* __restrict__ out, int n_a, int n_b, int gA)
{
  __shared__ unsigned short Wr_l[128 * 128];   // 32 KB
  __shared__ unsigned short Wg1_l[128 * 128];  // 32 KB
  __shared__ unsigned short Wc_l[128 * 128];   // 32 KB
  __shared__ __align__(16) float br_l[128];
  __shared__ __align__(16) float bg_l[128];
  __shared__ __align__(16) float bgv_l[128];

  const int t = threadIdx.x;
  const bool isB = (int)blockIdx.x >= gA;
  const int bid = isB ? ((int)blockIdx.x - gA) : (int)blockIdx.x;
  const int n   = isB ? n_b : n_a;
  const size_t roff = isB ? (size_t)n_a * DD : 0;
  const unsigned short* rowsp = rows_bf + roff;
  const unsigned short* meanp = mean_bf + roff;
  const int* cntp = cnt + (isB ? n_a : 0);
  float* outp = out + roff;
  const unsigned short* Wr_g  = wbf + (isB ? 16384 : 0);
  const unsigned short* Wg1_g = wbf + 32768;
  const unsigned short* Wc_g  = wbf + 49152 + (isB ? 16384 : 0);
  const float* brp = isB ? b_fwd : b_rev;
  const float* vp  = vab + (isB ? 128 : 0);

  // stage Wr + Wg1 + Wc (2048 16B-octets each), proven octet-XOR swizzle
  for (int oi = t; oi < 2048; oi += 1024) {
    int j = oi >> 4, o = oi & 15;
    int d = j * 128 + ((o ^ (j & 15)) << 3);
    *(short8*)&Wr_l[d]  = *(const short8*)&Wr_g[oi << 3];
    *(short8*)&Wg1_l[d] = *(const short8*)&Wg1_g[oi << 3];
    *(short8*)&Wc_l[d]  = *(const short8*)&Wc_g[oi << 3];
  }
  if (t < 128) {
    float b = brp[t], g = bg[t], v = vp[t];
    br_l[t] = b; bg_l[t] = g; bgv_l[t] = g + v;
  }
  __syncthreads();

  const int wid  = t >> 6;      // 0..15
  const int lane = t & 63;
  const int lrow = lane & 15;   // row within tile owned by this lane
  const int lgrp = lane >> 4;   // k-octet group / j-quad selector
  const int m0 = bid * 512 + wid * 32;
  if (m0 >= n) return;

  const int mA = m0 + lrow;          // tile 0 row
  const int mB = m0 + 16 + lrow;     // tile 1 row
  const bool okA = mA < n, okB = mB < n;
  const int cvA = okA ? cntp[mA] : 0;
  const int cvB = okB ? cntp[mB] : 0;

  // x-fragments for both tiles (B-operand layout: row m, octet ks*4+lgrp)
  short8 amA[4], arA[4], amB[4], arB[4];
  #pragma unroll
  for (int ks = 0; ks < 4; ++ks) {
    short8 z = {0, 0, 0, 0, 0, 0, 0, 0};
    amA[ks] = z; arA[ks] = z; amB[ks] = z; arB[ks] = z;
    size_t ofs = ks * 32 + lgrp * 8;
    if (okA) {
      amA[ks] = *(const short8*)&meanp[(size_t)mA * DD + ofs];
      arA[ks] = *(const short8*)&rowsp[(size_t)mA * DD + ofs];
    }
    if (okB) {
      amB[ks] = *(const short8*)&meanp[(size_t)mB * DD + ofs];
      arB[ks] = *(const short8*)&rowsp[(size_t)mB * DD + ofs];
    }
  }

  #pragma unroll
  for (int jt = 0; jt < 8; jt += 2) {
    const int r0 = (jt * 16 + lrow) * 128;        // LDS row base, jt
    const int r1 = ((jt + 1) * 16 + lrow) * 128;  // ... jt+1
    const int j0 = jt * 16 + lgrp * 4;
    const int j1 = j0 + 16;

    // t = mean @ Wr^T + br  — 4 independent chains (2 tiles x 2 j-tiles)
    f32x4 tA0 = *(const f32x4*)&br_l[j0], tB0 = tA0;
    f32x4 tA1 = *(const f32x4*)&br_l[j1], tB1 = tA1;
    #pragma unroll
    for (int ks = 0; ks < 4; ++ks) {
      int so = ((ks * 4 + lgrp) ^ lrow) << 3;
      short8 w0 = *(short8*)&Wr_l[r0 + so];
      short8 w1 = *(short8*)&Wr_l[r1 + so];
      tA0 = __builtin_amdgcn_mfma_f32_16x16x32_bf16(w0, amA[ks], tA0, 0, 0, 0);
      tB0 = __builtin_amdgcn_mfma_f32_16x16x32_bf16(w0, amB[ks], tB0, 0, 0, 0);
      tA1 = __builtin_amdgcn_mfma_f32_16x16x32_bf16(w1, amA[ks], tA1, 0, 0, 0);
      tB1 = __builtin_amdgcn_mfma_f32_16x16x32_bf16(w1, amB[ks], tB1, 0, 0, 0);
    }
    if (cvA == 0) { tA0 = (f32x4){0.f,0.f,0.f,0.f}; tA1 = tA0; }
    if (cvB == 0) { tB0 = (f32x4){0.f,0.f,0.f,0.f}; tB1 = tB0; }

    // u = row @ Wg1^T + mean @ Wc^T + (cv ? bg+v : bg)  — all LDS
    f32x4 uA0 = (cvA > 0) ? *(const f32x4*)&bgv_l[j0] : *(const f32x4*)&bg_l[j0];
    f32x4 uB0 = (cvB > 0) ? *(const f32x4*)&bgv_l[j0] : *(const f32x4*)&bg_l[j0];
    f32x4 uA1 = (cvA > 0) ? *(const f32x4*)&bgv_l[j1] : *(const f32x4*)&bg_l[j1];
    f32x4 uB1 = (cvB > 0) ? *(const f32x4*)&bgv_l[j1] : *(const f32x4*)&bg_l[j1];
    #pragma unroll
    for (int ks = 0; ks < 4; ++ks) {
      int so = ((ks * 4 + lgrp) ^ lrow) << 3;
      short8 w0 = *(short8*)&Wg1_l[r0 + so];
      short8 w1 = *(short8*)&Wg1_l[r1 + so];
      uA0 = __builtin_amdgcn_mfma_f32_16x16x32_bf16(w0, arA[ks], uA0, 0, 0, 0);
      uB0 = __builtin_amdgcn_mfma_f32_16x16x32_bf16(w0, arB[ks], uB0, 0, 0, 0);
      uA1 = __builtin_amdgcn_mfma_f32_16x16x32_bf16(w1, arA[ks], uA1, 0, 0, 0);
      uB1 = __builtin_amdgcn_mfma_f32_16x16x32_bf16(w1, arB[ks], uB1, 0, 0, 0);
    }
    #pragma unroll
    for (int ks = 0; ks < 4; ++ks) {
      int so = ((ks * 4 + lgrp) ^ lrow) << 3;
      short8 w0 = *(short8*)&Wc_l[r0 + so];
      short8 w1 = *(short8*)&Wc_l[r1 + so];
      uA0 = __builtin_amdgcn_mfma_f32_16x16x32_bf16(w0, amA[ks], uA0, 0, 0, 0);
      uB0 = __builtin_amdgcn_mfma_f32_16x16x32_bf16(w0, amB[ks], uB0, 0, 0, 0);
      uA1 = __builtin_amdgcn_mfma_f32_16x16x32_bf16(w1, amA[ks], uA1, 0, 0, 0);
      uB1 = __builtin_amdgcn_mfma_f32_16x16x32_bf16(w1, amB[ks], uB1, 0, 0, 0);
    }

    // epilogue: 4 (tile, j-tile) combos, vector loads/stores
    #pragma unroll
    for (int half = 0; half < 2; ++half) {
      int jj = (half == 0) ? j0 : j1;
      f32x4 uA = (half == 0) ? uA0 : uA1;
      f32x4 uB = (half == 0) ? uB0 : uB1;
      f32x4 tA = (half == 0) ? tA0 : tA1;
      f32x4 tB = (half == 0) ? tB0 : tB1;
      if (okA) {
        us4 rv = *(const us4*)&rowsp[(size_t)mA * DD + jj];
        float4 o;
        float g0 = 1.f / (1.f + __expf(-uA[0]));
        float g1 = 1.f / (1.f + __expf(-uA[1]));
        float g2 = 1.f / (1.f + __expf(-uA[2]));
        float g3 = 1.f / (1.f + __expf(-uA[3]));
        o.x = g0 * b2f(rv[0]) + (1.f - g0) * tA[0];
        o.y = g1 * b2f(rv[1]) + (1.f - g1) * tA[1];
        o.z = g2 * b2f(rv[2]) + (1.f - g2) * tA[2];
        o.w = g3 * b2f(rv[3]) + (1.f - g3) * tA[3];
        *(float4*)&outp[(size_t)mA * DD + jj] = o;
      }
      if (okB) {
        us4 rv = *(const us4*)&rowsp[(size_t)mB * DD + jj];
        float4 o;
        float g0 = 1.f / (1.f + __expf(-uB[0]));
        float g1 = 1.f / (1.f + __expf(-uB[1]));
        float g2 = 1.f / (1.f + __expf(-uB[2]));
        float g3 = 1.f / (1.f + __expf(-uB[3]));
        o.x = g0 * b2f(rv[0]) + (1.f - g0) * tB[0];
        o.y = g1 * b2f(rv[1]) + (1.f - g1) * tB[1];
        o.z = g2 * b2f(rv[2]) + (1.f - g2) * tB[2];
        o.w = g3 * b2f(rv[3]) + (1.f - g3) * tB[3];
        *(float4*)&outp[(size_t)mB * DD + jj] = o;
      }
    }
  }
}

extern "C" void kernel_launch(void* const* d_in, const int* in_sizes, int n_in,
                              void* d_out, int out_size, void* d_ws, size_t ws_size,
                              hipStream_t stream) {
  const float* A      = (const float*)d_in[0];
  const float* B      = (const float*)d_in[1];
  const float* W_fwd  = (const float*)d_in[2];
  const float* b_fwd  = (const float*)d_in[3];
  const float* W_rev  = (const float*)d_in[4];
  const float* b_rev  = (const float*)d_in[5];
  const float* W_gate = (const float*)d_in[6];
  const float* b_gate = (const float*)d_in[7];
  const int*   src    = (const int*)d_in[8];
  const int*   dst    = (const int*)d_in[9];

  const int n_a = in_sizes[0] / DD;
  const int n_b = in_sizes[1] / DD;
  const int E   = in_sizes[8];
  const int n_total = n_a + n_b;

  const int na_bins = (n_a + 1023) >> 10;
  const int nb_bins = (n_b + 255) >> 8;
  const int nbins   = na_bins + nb_bins;

  float* out = (float*)d_out;

  // workspace layout
  int* cnt      = (int*)d_ws;                        // [n_total]
  int* binraw   = cnt + n_total;                     // [1024]
  int* start    = binraw + 1024;                     // [n_total]
  int* binstart = start + n_total;                   // [1024]
  int* bincur   = binstart + 1024;                   // [1024]
  uint2* binrec = (uint2*)(bincur + 1024);           // [2E]
  int* partner  = (int*)(binrec + 2 * (size_t)E);    // [2E]
  uintptr_t wp = (uintptr_t)(partner + 2 * (size_t)E);
  wp = (wp + 63) & ~(uintptr_t)63;
  unsigned short* wbf = (unsigned short*)wp;         // [81920]: Wrev|Wfwd|Wg1|WcA|WcB
  float* vab = (float*)(wbf + 81920);                // [256] f32: vA | vB
  unsigned short* rows_bf = (unsigned short*)(vab + 256);  // [n_total*128]
  unsigned short* A_bf = rows_bf;
  unsigned short* B_bf = rows_bf + (size_t)n_a * DD;
  unsigned short* mean_bf = rows_bf + (size_t)n_total * DD; // [n_total*128]

  const int nA4  = n_a * (DD / 4);
  const int nt4  = n_total * (DD / 4);

  hipMemsetAsync(binraw, 0, 1024 * sizeof(int), stream);

  rowconv_kernel<<<2048, 256, 0, stream>>>(A, B, rows_bf, nA4, nt4);
  wconv_kernel<<<192, 256, 0, stream>>>(W_rev, W_fwd, W_gate, wbf);
  wc_kernel<<<128, 128, 0, stream>>>(W_gate, W_rev, b_rev, wbf + 49152, vab);
  wc_kernel<<<128, 128, 0, stream>>>(W_gate, W_fwd, b_fwd, wbf + 65536, vab + 128);

  binhist_kernel<<<1024, 256, 0, stream>>>(src, dst, binraw, na_bins, nbins, E);
  binscan_kernel<<<1, 512, 0, stream>>>(binraw, nbins, binstart, bincur);
  binfill_kernel<<<(E + 4095) / 4096, 512, 0, stream>>>(
      src, dst, bincur, binrec, n_a, na_bins, nbins, E);
  binscatter2_kernel<<<nbins, 256, 0, stream>>>(
      binrec, binstart, bincur, partner, start, cnt, n_a, n_total, na_bins);

  aggregate_mean_bf16_kernel<<<(n_total + 3) / 4, 256, 0, stream>>>(
      A_bf, B_bf, partner, start, cnt, mean_bf, n_a, n_total);

  // merged post kernel: blocks [0,gA) -> A range (512 rows each), then B
  const int gA = (n_a + 511) / 512;
  const int gB = (n_b + 511) / 512;
  fused_post_kernel<<<gA + gB, 1024, 0, stream>>>(
      rows_bf, mean_bf, cnt, wbf, b_rev, b_fwd, b_gate, vab,
      out, n_a, n_b, gA);
}

// Round 20
// 292.053 us; speedup vs baseline: 2.1507x; 1.0230x over previous
//
#include <hip/hip_runtime.h>
#include <math.h>

#define DD 128

typedef __attribute__((ext_vector_type(8))) short short8;
typedef __attribute__((ext_vector_type(4))) float f32x4;
typedef __attribute__((ext_vector_type(4))) unsigned short us4;
typedef __attribute__((ext_vector_type(8))) unsigned short us8;

__device__ __forceinline__ unsigned short f2bf(float f) {
  unsigned int u = __builtin_bit_cast(unsigned int, f);
  u = (u + 0x7FFFu + ((u >> 16) & 1u)) >> 16;   // RNE (finite inputs)
  return (unsigned short)u;
}

__device__ __forceinline__ float b2f(unsigned short u) {
  return __builtin_bit_cast(float, ((unsigned)u) << 16);
}

__device__ __forceinline__ float blo(unsigned u) {        // element 0 of a u32
  return __builtin_bit_cast(float, u << 16);
}
__device__ __forceinline__ float bhi(unsigned u) {        // element 1 of a u32
  return __builtin_bit_cast(float, u & 0xFFFF0000u);
}

// ---------------------------------------------------------------------------
// Row conversion f32 -> bf16: [A | B] into one table.
// ---------------------------------------------------------------------------
__global__ __launch_bounds__(256) void rowconv_kernel(
    const float* __restrict__ A, const float* __restrict__ B,
    unsigned short* __restrict__ dst, int nA4, int ntot4)
{
  int stride = gridDim.x * 256;
  for (int i = blockIdx.x * 256 + threadIdx.x; i < ntot4; i += stride) {
    float4 v = (i < nA4) ? ((const float4*)A)[i] : ((const float4*)B)[i - nA4];
    us4 o;
    o[0] = f2bf(v.x); o[1] = f2bf(v.y); o[2] = f2bf(v.z); o[3] = f2bf(v.w);
    ((us4*)dst)[i] = o;
  }
}

// ---------------------------------------------------------------------------
// Weight conversion f32 -> bf16: [Wrev | Wfwd | Wg1] (Wg1 = W_gate[:, :128])
// ---------------------------------------------------------------------------
__global__ __launch_bounds__(256) void wconv_kernel(
    const float* __restrict__ Wrev, const float* __restrict__ Wfwd,
    const float* __restrict__ Wgate, unsigned short* __restrict__ dst)
{
  int i = blockIdx.x * 256 + threadIdx.x;   // 49152 total
  float v;
  if (i < 16384) v = Wrev[i];
  else if (i < 32768) v = Wfwd[i - 16384];
  else {
    int j = (i - 32768) >> 7, k = (i - 32768) & 127;
    v = Wgate[j * 256 + k];                 // first half of each gate row
  }
  dst[i] = f2bf(v);
}

// ---------------------------------------------------------------------------
// Merged Wc kernel (both ranges in one launch):
// half=0: Wc=Wg2@Wrev, v=Wg2@b_rev ; half=1: Wc=Wg2@Wfwd, v=Wg2@b_fwd
// ---------------------------------------------------------------------------
__global__ __launch_bounds__(128) void wc2_kernel(
    const float* __restrict__ Wgate,
    const float* __restrict__ Wrev, const float* __restrict__ Wfwd,
    const float* __restrict__ b_rev, const float* __restrict__ b_fwd,
    unsigned short* __restrict__ Wc_out,   // [2][128*128]
    float* __restrict__ vab)               // [2][128]
{
  int half = blockIdx.x >> 7;
  int j = blockIdx.x & 127, k = threadIdx.x;
  const float* Wr = half ? Wfwd : Wrev;
  const float* br = half ? b_fwd : b_rev;
  unsigned short* Wc = Wc_out + half * 16384;
  const float* g2 = Wgate + (size_t)j * 256 + 128;
  float acc = 0.f;
  for (int m = 0; m < 128; ++m) acc += g2[m] * Wr[m * 128 + k];
  Wc[j * 128 + k] = f2bf(acc);
  if (k == 0) {
    float a = 0.f;
    for (int m = 0; m < 128; ++m) a += g2[m] * br[m];
    vab[half * 128 + j] = a;
  }
}

// ---------------------------------------------------------------------------
// Bin histogram. A rows: 1024-row bins; B rows: 256-row bins. (proven)
// ---------------------------------------------------------------------------
__global__ __launch_bounds__(256) void binhist_kernel(
    const int* __restrict__ src, const int* __restrict__ dst,
    int* __restrict__ binraw, int na_bins, int nbins, int E)
{
  __shared__ int h[1024];
  int t = threadIdx.x;
  for (int i = t; i < 1024; i += 256) h[i] = 0;
  __syncthreads();
  int stride = gridDim.x * 256;
  for (int e = blockIdx.x * 256 + t; e < E; e += stride) {
    int s = src[e], d = dst[e];
    atomicAdd(&h[s >> 10], 1);
    atomicAdd(&h[na_bins + (d >> 8)], 1);
  }
  __syncthreads();
  for (int i = t; i < nbins; i += 256)
    if (h[i]) atomicAdd(&binraw[i], h[i]);
}

// ---------------------------------------------------------------------------
// Exclusive scan over bin counts (single block, nbins <= 512). (proven)
// ---------------------------------------------------------------------------
__global__ __launch_bounds__(512) void binscan_kernel(
    const int* __restrict__ binraw, int nbins,
    int* __restrict__ binstart, int* __restrict__ bincur)
{
  __shared__ int buf[512];
  int t = threadIdx.x;
  int v = (t < nbins) ? binraw[t] : 0;
  buf[t] = v;
  __syncthreads();
  for (int off = 1; off < 512; off <<= 1) {
    int x = (t >= off) ? buf[t - off] : 0;
    __syncthreads();
    buf[t] += x;
    __syncthreads();
  }
  if (t < nbins) {
    int excl = buf[t] - v;
    binstart[t] = excl;
    bincur[t] = excl;
  }
}

// ---------------------------------------------------------------------------
// binfill — rank 8192 records per-bin in LDS, reserve dense runs, write
// (key=row, val=partner) as per-CU dense runs. (proven)
// ---------------------------------------------------------------------------
__global__ __launch_bounds__(512) void binfill_kernel(
    const int* __restrict__ src, const int* __restrict__ dst,
    int* __restrict__ bincur, uint2* __restrict__ binrec,
    int n_a, int na_bins, int nbins, int E)
{
  __shared__ int lcnt[1024];
  __shared__ int goff[1024];
  const int t = threadIdx.x;
  const int base = blockIdx.x * 4096;
  for (int i = t; i < 1024; i += 512) lcnt[i] = 0;
  __syncthreads();

  int bins[16], ranks[16];
  unsigned keys[16], vals[16];
  #pragma unroll
  for (int j = 0; j < 8; ++j) {
    int e = base + j * 512 + t;
    int i0 = 2 * j, i1 = 2 * j + 1;
    if (e < E) {
      int s = src[e], d = dst[e];
      bins[i0] = s >> 10;               keys[i0] = (unsigned)s;       vals[i0] = (unsigned)d;
      bins[i1] = na_bins + (d >> 8);    keys[i1] = (unsigned)(n_a + d); vals[i1] = (unsigned)s;
      ranks[i0] = atomicAdd(&lcnt[bins[i0]], 1);
      ranks[i1] = atomicAdd(&lcnt[bins[i1]], 1);
    } else {
      bins[i0] = -1; bins[i1] = -1;
      ranks[i0] = 0;  ranks[i1] = 0;
      keys[i0] = 0;   keys[i1] = 0;
      vals[i0] = 0;   vals[i1] = 0;
    }
  }
  __syncthreads();
  for (int b = t; b < nbins; b += 512)
    if (lcnt[b]) goff[b] = atomicAdd(&bincur[b], lcnt[b]);
  __syncthreads();
  #pragma unroll
  for (int i = 0; i < 16; ++i) {
    if (bins[i] >= 0) {
      int p = goff[bins[i]] + ranks[i];
      binrec[p] = make_uint2(keys[i], vals[i]);
    }
  }
}

// ---------------------------------------------------------------------------
// binscatter2 — one block per bin: per-bin LDS counting sort producing
// start/cnt + partner list. (round-14-proven)
// ---------------------------------------------------------------------------
__global__ __launch_bounds__(256) void binscatter2_kernel(
    const uint2* __restrict__ binrec, const int* __restrict__ binstart,
    const int* __restrict__ binend, int* __restrict__ partner,
    int* __restrict__ start, int* __restrict__ cnt,
    int n_a, int n_total, int na_bins)
{
  __shared__ int cntL[1024];
  __shared__ int curL[1024];
  __shared__ int sbuf[256];
  const int b = blockIdx.x;
  const int t = threadIdx.x;
  int row0, nrows;
  if (b < na_bins) { row0 = b << 10; nrows = min(1024, n_a - row0); }
  else { row0 = n_a + ((b - na_bins) << 8); nrows = min(256, n_total - row0); }
  const int s0 = binstart[b], e0 = binend[b];

  for (int i = t; i < 1024; i += 256) cntL[i] = 0;
  __syncthreads();
  for (int i = s0 + t; i < e0; i += 256)
    atomicAdd(&cntL[binrec[i].x - (unsigned)row0], 1);
  __syncthreads();
  int l0 = cntL[4 * t], l1 = cntL[4 * t + 1];
  int l2 = cntL[4 * t + 2], l3 = cntL[4 * t + 3];
  int s = l0 + l1 + l2 + l3;
  sbuf[t] = s;
  __syncthreads();
  for (int off = 1; off < 256; off <<= 1) {
    int x = (t >= off) ? sbuf[t - off] : 0;
    __syncthreads();
    sbuf[t] += x;
    __syncthreads();
  }
  int excl = sbuf[t] - s;
  curL[4 * t]     = excl;
  curL[4 * t + 1] = excl + l0;
  curL[4 * t + 2] = excl + l0 + l1;
  curL[4 * t + 3] = excl + l0 + l1 + l2;
  __syncthreads();
  for (int j = t; j < nrows; j += 256) {
    start[row0 + j] = s0 + curL[j];
    cnt[row0 + j] = cntL[j];
  }
  __syncthreads();
  for (int i = s0 + t; i < e0; i += 256) {
    uint2 r = binrec[i];
    int pos = atomicAdd(&curL[r.x - (unsigned)row0], 1);
    partner[s0 + pos] = (int)r.y;
  }
}

// ---------------------------------------------------------------------------
// Aggregate v4: one wave per row; 16 lanes x 16B, 4 quads x 4 batches = 16
// edges in flight. 32-bit offset addressing ((p<<8)|laneoff -> single
// v_lshl_or + saddr load) and uint4 unpack (u<<16 / u&0xFFFF0000).
// ---------------------------------------------------------------------------
__global__ __launch_bounds__(256) void aggregate_mean_bf16_kernel(
    const unsigned short* __restrict__ A_bf,
    const unsigned short* __restrict__ B_bf,
    const int* __restrict__ partner, const int* __restrict__ start,
    const int* __restrict__ cnt, unsigned short* __restrict__ mean_bf,
    int n_a, int n_total)
{
  int wid = (blockIdx.x * 256 + threadIdx.x) >> 6;
  if (wid >= n_total) return;
  int lane = threadIdx.x & 63;
  int q    = lane & 15;
  int quad = lane >> 4;
  int s0 = start[wid], c = cnt[wid];
  const char* base = (const char*)((wid < n_a) ? B_bf : A_bf);
  const unsigned loff = (unsigned)q << 4;      // 16B chunk within the row
  float a0 = 0.f, a1 = 0.f, a2 = 0.f, a3 = 0.f;
  float a4 = 0.f, a5 = 0.f, a6 = 0.f, a7 = 0.f;
  int k = 0;
  for (; k + 16 <= c; k += 16) {
    unsigned o0 = ((unsigned)partner[s0 + k + 0 + quad] << 8) | loff;
    unsigned o1 = ((unsigned)partner[s0 + k + 4 + quad] << 8) | loff;
    unsigned o2 = ((unsigned)partner[s0 + k + 8 + quad] << 8) | loff;
    unsigned o3 = ((unsigned)partner[s0 + k + 12 + quad] << 8) | loff;
    uint4 v0 = *(const uint4*)(base + o0);
    uint4 v1 = *(const uint4*)(base + o1);
    uint4 v2 = *(const uint4*)(base + o2);
    uint4 v3 = *(const uint4*)(base + o3);
    a0 += blo(v0.x) + blo(v1.x) + blo(v2.x) + blo(v3.x);
    a1 += bhi(v0.x) + bhi(v1.x) + bhi(v2.x) + bhi(v3.x);
    a2 += blo(v0.y) + blo(v1.y) + blo(v2.y) + blo(v3.y);
    a3 += bhi(v0.y) + bhi(v1.y) + bhi(v2.y) + bhi(v3.y);
    a4 += blo(v0.z) + blo(v1.z) + blo(v2.z) + blo(v3.z);
    a5 += bhi(v0.z) + bhi(v1.z) + bhi(v2.z) + bhi(v3.z);
    a6 += blo(v0.w) + blo(v1.w) + blo(v2.w) + blo(v3.w);
    a7 += bhi(v0.w) + bhi(v1.w) + bhi(v2.w) + bhi(v3.w);
  }
  for (; k < c; k += 4) {
    int i = k + quad;
    if (i < c) {
      unsigned o = ((unsigned)partner[s0 + i] << 8) | loff;
      uint4 v = *(const uint4*)(base + o);
      a0 += blo(v.x); a1 += bhi(v.x);
      a2 += blo(v.y); a3 += bhi(v.y);
      a4 += blo(v.z); a5 += bhi(v.z);
      a6 += blo(v.w); a7 += bhi(v.w);
    }
  }
  a0 += __shfl_xor(a0, 16); a0 += __shfl_xor(a0, 32);
  a1 += __shfl_xor(a1, 16); a1 += __shfl_xor(a1, 32);
  a2 += __shfl_xor(a2, 16); a2 += __shfl_xor(a2, 32);
  a3 += __shfl_xor(a3, 16); a3 += __shfl_xor(a3, 32);
  a4 += __shfl_xor(a4, 16); a4 += __shfl_xor(a4, 32);
  a5 += __shfl_xor(a5, 16); a5 += __shfl_xor(a5, 32);
  a6 += __shfl_xor(a6, 16); a6 += __shfl_xor(a6, 32);
  a7 += __shfl_xor(a7, 16); a7 += __shfl_xor(a7, 32);
  if (lane < 16) {
    float inv = (c > 0) ? (1.f / (float)c) : 0.f;
    us8 o;
    o[0] = f2bf(a0 * inv); o[1] = f2bf(a1 * inv);
    o[2] = f2bf(a2 * inv); o[3] = f2bf(a3 * inv);
    o[4] = f2bf(a4 * inv); o[5] = f2bf(a5 * inv);
    o[6] = f2bf(a6 * inv); o[7] = f2bf(a7 * inv);
    *(us8*)&mean_bf[(size_t)wid * DD + 8 * q] = o;
  }
}

// ---------------------------------------------------------------------------
// Fused post v8 (MFMA) — round-19-proven: 1024 threads, Wr+Wg1+Wc all in LDS
// (96 KB, 1 block/CU = 16 waves/CU), 512 rows/block, 2 row-tiles/wave,
// jt-pairing (4 independent chains), swapped operands, vector epilogue.
//   t = (cnt>0) ? mean @ Wr^T + br : 0
//   u = row @ Wg1^T + mean @ Wc^T + (cnt>0 ? bg+v : bg)
//   out = sigmoid(u)*row + (1-sigmoid(u))*t
// ---------------------------------------------------------------------------
__global__ __launch_bounds__(1024, 1) void fused_post_kernel(
    const unsigned short* __restrict__ rows_bf,  // [n_total][128] bf16
    const unsigned short* __restrict__ mean_bf,  // [n_total][128] bf16
    const int* __restrict__ cnt,                 // [n_total]
    const unsigned short* __restrict__ wbf,      // [Wrev|Wfwd|Wg1|WcA|WcB]
    const float* __restrict__ b_rev, const float* __restrict__ b_fwd,
    const float* __restrict__ bg, const float* __restrict__ vab,
    float* __restrict__ out, int n_a, int n_b, int gA)
{
  __shared__ unsigned short Wr_l[128 * 128];   // 32 KB
  __shared__ unsigned short Wg1_l[128 * 128];  // 32 KB
  __shared__ unsigned short Wc_l[128 * 128];   // 32 KB
  __shared__ __align__(16) float br_l[128];
  __shared__ __align__(16) float bg_l[128];
  __shared__ __align__(16) float bgv_l[128];

  const int t = threadIdx.x;
  const bool isB = (int)blockIdx.x >= gA;
  const int bid = isB ? ((int)blockIdx.x - gA) : (int)blockIdx.x;
  const int n   = isB ? n_b : n_a;
  const size_t roff = isB ? (size_t)n_a * DD : 0;
  const unsigned short* rowsp = rows_bf + roff;
  const unsigned short* meanp = mean_bf + roff;
  const int* cntp = cnt + (isB ? n_a : 0);
  float* outp = out + roff;
  const unsigned short* Wr_g  = wbf + (isB ? 16384 : 0);
  const unsigned short* Wg1_g = wbf + 32768;
  const unsigned short* Wc_g  = wbf + 49152 + (isB ? 16384 : 0);
  const float* brp = isB ? b_fwd : b_rev;
  const float* vp  = vab + (isB ? 128 : 0);

  // stage Wr + Wg1 + Wc (2048 16B-octets each), proven octet-XOR swizzle
  for (int oi = t; oi < 2048; oi += 1024) {
    int j = oi >> 4, o = oi & 15;
    int d = j * 128 + ((o ^ (j & 15)) << 3);
    *(short8*)&Wr_l[d]  = *(const short8*)&Wr_g[oi << 3];
    *(short8*)&Wg1_l[d] = *(const short8*)&Wg1_g[oi << 3];
    *(short8*)&Wc_l[d]  = *(const short8*)&Wc_g[oi << 3];
  }
  if (t < 128) {
    float b = brp[t], g = bg[t], v = vp[t];
    br_l[t] = b; bg_l[t] = g; bgv_l[t] = g + v;
  }
  __syncthreads();

  const int wid  = t >> 6;      // 0..15
  const int lane = t & 63;
  const int lrow = lane & 15;   // row within tile owned by this lane
  const int lgrp = lane >> 4;   // k-octet group / j-quad selector
  const int m0 = bid * 512 + wid * 32;
  if (m0 >= n) return;

  const int mA = m0 + lrow;          // tile 0 row
  const int mB = m0 + 16 + lrow;     // tile 1 row
  const bool okA = mA < n, okB = mB < n;
  const int cvA = okA ? cntp[mA] : 0;
  const int cvB = okB ? cntp[mB] : 0;

  // x-fragments for both tiles (B-operand layout: row m, octet ks*4+lgrp)
  short8 amA[4], arA[4], amB[4], arB[4];
  #pragma unroll
  for (int ks = 0; ks < 4; ++ks) {
    short8 z = {0, 0, 0, 0, 0, 0, 0, 0};
    amA[ks] = z; arA[ks] = z; amB[ks] = z; arB[ks] = z;
    size_t ofs = ks * 32 + lgrp * 8;
    if (okA) {
      amA[ks] = *(const short8*)&meanp[(size_t)mA * DD + ofs];
      arA[ks] = *(const short8*)&rowsp[(size_t)mA * DD + ofs];
    }
    if (okB) {
      amB[ks] = *(const short8*)&meanp[(size_t)mB * DD + ofs];
      arB[ks] = *(const short8*)&rowsp[(size_t)mB * DD + ofs];
    }
  }

  #pragma unroll
  for (int jt = 0; jt < 8; jt += 2) {
    const int r0 = (jt * 16 + lrow) * 128;        // LDS row base, jt
    const int r1 = ((jt + 1) * 16 + lrow) * 128;  // ... jt+1
    const int j0 = jt * 16 + lgrp * 4;
    const int j1 = j0 + 16;

    // t = mean @ Wr^T + br  — 4 independent chains (2 tiles x 2 j-tiles)
    f32x4 tA0 = *(const f32x4*)&br_l[j0], tB0 = tA0;
    f32x4 tA1 = *(const f32x4*)&br_l[j1], tB1 = tA1;
    #pragma unroll
    for (int ks = 0; ks < 4; ++ks) {
      int so = ((ks * 4 + lgrp) ^ lrow) << 3;
      short8 w0 = *(short8*)&Wr_l[r0 + so];
      short8 w1 = *(short8*)&Wr_l[r1 + so];
      tA0 = __builtin_amdgcn_mfma_f32_16x16x32_bf16(w0, amA[ks], tA0, 0, 0, 0);
      tB0 = __builtin_amdgcn_mfma_f32_16x16x32_bf16(w0, amB[ks], tB0, 0, 0, 0);
      tA1 = __builtin_amdgcn_mfma_f32_16x16x32_bf16(w1, amA[ks], tA1, 0, 0, 0);
      tB1 = __builtin_amdgcn_mfma_f32_16x16x32_bf16(w1, amB[ks], tB1, 0, 0, 0);
    }
    if (cvA == 0) { tA0 = (f32x4){0.f,0.f,0.f,0.f}; tA1 = tA0; }
    if (cvB == 0) { tB0 = (f32x4){0.f,0.f,0.f,0.f}; tB1 = tB0; }

    // u = row @ Wg1^T + mean @ Wc^T + (cv ? bg+v : bg)  — all LDS
    f32x4 uA0 = (cvA > 0) ? *(const f32x4*)&bgv_l[j0] : *(const f32x4*)&bg_l[j0];
    f32x4 uB0 = (cvB > 0) ? *(const f32x4*)&bgv_l[j0] : *(const f32x4*)&bg_l[j0];
    f32x4 uA1 = (cvA > 0) ? *(const f32x4*)&bgv_l[j1] : *(const f32x4*)&bg_l[j1];
    f32x4 uB1 = (cvB > 0) ? *(const f32x4*)&bgv_l[j1] : *(const f32x4*)&bg_l[j1];
    #pragma unroll
    for (int ks = 0; ks < 4; ++ks) {
      int so = ((ks * 4 + lgrp) ^ lrow) << 3;
      short8 w0 = *(short8*)&Wg1_l[r0 + so];
      short8 w1 = *(short8*)&Wg1_l[r1 + so];
      uA0 = __builtin_amdgcn_mfma_f32_16x16x32_bf16(w0, arA[ks], uA0, 0, 0, 0);
      uB0 = __builtin_amdgcn_mfma_f32_16x16x32_bf16(w0, arB[ks], uB0, 0, 0, 0);
      uA1 = __builtin_amdgcn_mfma_f32_16x16x32_bf16(w1, arA[ks], uA1, 0, 0, 0);
      uB1 = __builtin_amdgcn_mfma_f32_16x16x32_bf16(w1, arB[ks], uB1, 0, 0, 0);
    }
    #pragma unroll
    for (int ks = 0; ks < 4; ++ks) {
      int so = ((ks * 4 + lgrp) ^ lrow) << 3;
      short8 w0 = *(short8*)&Wc_l[r0 + so];
      short8 w1 = *(short8*)&Wc_l[r1 + so];
      uA0 = __builtin_amdgcn_mfma_f32_16x16x32_bf16(w0, amA[ks], uA0, 0, 0, 0);
      uB0 = __builtin_amdgcn_mfma_f32_16x16x32_bf16(w0, amB[ks], uB0, 0, 0, 0);
      uA1 = __builtin_amdgcn_mfma_f32_16x16x32_bf16(w1, amA[ks], uA1, 0, 0, 0);
      uB1 = __builtin_amdgcn_mfma_f32_16x16x32_bf16(w1, amB[ks], uB1, 0, 0, 0);
    }

    // epilogue: 4 (tile, j-tile) combos, vector loads/stores
    #pragma unroll
    for (int half = 0; half < 2; ++half) {
      int jj = (half == 0) ? j0 : j1;
      f32x4 uA = (half == 0) ? uA0 : uA1;
      f32x4 uB = (half == 0) ? uB0 : uB1;
      f32x4 tA = (half == 0) ? tA0 : tA1;
      f32x4 tB = (half == 0) ? tB0 : tB1;
      if (okA) {
        us4 rv = *(const us4*)&rowsp[(size_t)mA * DD + jj];
        float4 o;
        float g0 = 1.f / (1.f + __expf(-uA[0]));
        float g1 = 1.f / (1.f + __expf(-uA[1]));
        float g2 = 1.f / (1.f + __expf(-uA[2]));
        float g3 = 1.f / (1.f + __expf(-uA[3]));
        o.x = g0 * b2f(rv[0]) + (1.f - g0) * tA[0];
        o.y = g1 * b2f(rv[1]) + (1.f - g1) * tA[1];
        o.z = g2 * b2f(rv[2]) + (1.f - g2) * tA[2];
        o.w = g3 * b2f(rv[3]) + (1.f - g3) * tA[3];
        *(float4*)&outp[(size_t)mA * DD + jj] = o;
      }
      if (okB) {
        us4 rv = *(const us4*)&rowsp[(size_t)mB * DD + jj];
        float4 o;
        float g0 = 1.f / (1.f + __expf(-uB[0]));
        float g1 = 1.f / (1.f + __expf(-uB[1]));
        float g2 = 1.f / (1.f + __expf(-uB[2]));
        float g3 = 1.f / (1.f + __expf(-uB[3]));
        o.x = g0 * b2f(rv[0]) + (1.f - g0) * tB[0];
        o.y = g1 * b2f(rv[1]) + (1.f - g1) * tB[1];
        o.z = g2 * b2f(rv[2]) + (1.f - g2) * tB[2];
        o.w = g3 * b2f(rv[3]) + (1.f - g3) * tB[3];
        *(float4*)&outp[(size_t)mB * DD + jj] = o;
      }
    }
  }
}

extern "C" void kernel_launch(void* const* d_in, const int* in_sizes, int n_in,
                              void* d_out, int out_size, void* d_ws, size_t ws_size,
                              hipStream_t stream) {
  const float* A      = (const float*)d_in[0];
  const float* B      = (const float*)d_in[1];
  const float* W_fwd  = (const float*)d_in[2];
  const float* b_fwd  = (const float*)d_in[3];
  const float* W_rev  = (const float*)d_in[4];
  const float* b_rev  = (const float*)d_in[5];
  const float* W_gate = (const float*)d_in[6];
  const float* b_gate = (const float*)d_in[7];
  const int*   src    = (const int*)d_in[8];
  const int*   dst    = (const int*)d_in[9];

  const int n_a = in_sizes[0] / DD;
  const int n_b = in_sizes[1] / DD;
  const int E   = in_sizes[8];
  const int n_total = n_a + n_b;

  const int na_bins = (n_a + 1023) >> 10;
  const int nb_bins = (n_b + 255) >> 8;
  const int nbins   = na_bins + nb_bins;

  float* out = (float*)d_out;

  // workspace layout
  int* cnt      = (int*)d_ws;                        // [n_total]
  int* binraw   = cnt + n_total;                     // [1024]
  int* start    = binraw + 1024;                     // [n_total]
  int* binstart = start + n_total;                   // [1024]
  int* bincur   = binstart + 1024;                   // [1024]
  uint2* binrec = (uint2*)(bincur + 1024);           // [2E]
  int* partner  = (int*)(binrec + 2 * (size_t)E);    // [2E]
  uintptr_t wp = (uintptr_t)(partner + 2 * (size_t)E);
  wp = (wp + 63) & ~(uintptr_t)63;
  unsigned short* wbf = (unsigned short*)wp;         // [81920]: Wrev|Wfwd|Wg1|WcA|WcB
  float* vab = (float*)(wbf + 81920);                // [256] f32: vA | vB
  unsigned short* rows_bf = (unsigned short*)(vab + 256);  // [n_total*128]
  unsigned short* A_bf = rows_bf;
  unsigned short* B_bf = rows_bf + (size_t)n_a * DD;
  unsigned short* mean_bf = rows_bf + (size_t)n_total * DD; // [n_total*128]

  const int nA4  = n_a * (DD / 4);
  const int nt4  = n_total * (DD / 4);

  hipMemsetAsync(binraw, 0, 1024 * sizeof(int), stream);

  rowconv_kernel<<<2048, 256, 0, stream>>>(A, B, rows_bf, nA4, nt4);
  wconv_kernel<<<192, 256, 0, stream>>>(W_rev, W_fwd, W_gate, wbf);
  wc2_kernel<<<256, 128, 0, stream>>>(W_gate, W_rev, W_fwd, b_rev, b_fwd,
                                      wbf + 49152, vab);

  binhist_kernel<<<1024, 256, 0, stream>>>(src, dst, binraw, na_bins, nbins, E);
  binscan_kernel<<<1, 512, 0, stream>>>(binraw, nbins, binstart, bincur);
  binfill_kernel<<<(E + 4095) / 4096, 512, 0, stream>>>(
      src, dst, bincur, binrec, n_a, na_bins, nbins, E);
  binscatter2_kernel<<<nbins, 256, 0, stream>>>(
      binrec, binstart, bincur, partner, start, cnt, n_a, n_total, na_bins);

  aggregate_mean_bf16_kernel<<<(n_total + 3) / 4, 256, 0, stream>>>(
      A_bf, B_bf, partner, start, cnt, mean_bf, n_a, n_total);

  // merged post kernel: blocks [0,gA) -> A range (512 rows each), then B
  const int gA = (n_a + 511) / 512;
  const int gB = (n_b + 511) / 512;
  fused_post_kernel<<<gA + gB, 1024, 0, stream>>>(
      rows_bf, mean_bf, cnt, wbf, b_rev, b_fwd, b_gate, vab,
      out, n_a, n_b, gA);
}